// Round 1
// baseline (2721.548 us; speedup 1.0000x reference)
//
#include <hip/hip_runtime.h>
#include <stdint.h>

// ---------------- problem constants ----------------
#define NNODE   150000
#define EDGES   4000000
#define NSEED   500
#define NSAMP   15000              // int(150000 * 0.1)
#define MOUT    12150000           // 3E + N : decoder output length
#define SORT_TILE 2048
#define NT      5933               // ceil(MOUT / SORT_TILE)
#define MP      (NT * SORT_TILE)   // 12,150,784 padded sort size
#define SENTK   0xFFFFFFFFFFFFFFFFULL
#define SPAN    150000ULL
#define MULTK   51616ULL           // ((2^32 % 150000)^2) % 150000

// out layout (float32): [rows E][cols E][enc E][dec_rows M][dec_cols M][dec_vals M]
#define OUT_DR  12000000
#define OUT_DC  24150000
#define OUT_DV  36300000

// ---------------- threefry2x32 (JAX-exact, 20 rounds) ----------------
__host__ __device__ inline void tf2x32(uint32_t k0, uint32_t k1,
                                       uint32_t x0, uint32_t x1,
                                       uint32_t& o0, uint32_t& o1) {
  uint32_t ks2 = k0 ^ k1 ^ 0x1BD11BDAu;
  x0 += k0; x1 += k1;
#define TFR(d) { x0 += x1; x1 = (x1 << d) | (x1 >> (32 - d)); x1 ^= x0; }
  TFR(13) TFR(15) TFR(26) TFR(6)
  x0 += k1; x1 += ks2 + 1u;
  TFR(17) TFR(29) TFR(16) TFR(24)
  x0 += ks2; x1 += k0 + 2u;
  TFR(13) TFR(15) TFR(26) TFR(6)
  x0 += k0; x1 += k1 + 3u;
  TFR(17) TFR(29) TFR(16) TFR(24)
  x0 += k1; x1 += ks2 + 4u;
  TFR(13) TFR(15) TFR(26) TFR(6)
  x0 += ks2; x1 += k0 + 5u;
#undef TFR
  o0 = x0; o1 = x1;
}

__device__ inline unsigned long long tf_bits64(uint32_t k0, uint32_t k1, uint32_t i) {
  uint32_t o0, o1;
  tf2x32(k0, k1, 0u, i, o0, o1);
  return ((unsigned long long)o0 << 32) | o1;
}

// ---------------- block primitives (256 threads) ----------------
__device__ inline int block_excl_scan_256(int v, int* lds /*>=5 ints*/, int& total) {
  int lane = threadIdx.x & 63, wid = threadIdx.x >> 6;
  int inc = v;
#pragma unroll
  for (int off = 1; off < 64; off <<= 1) {
    int y = __shfl_up(inc, off, 64);
    if (lane >= off) inc += y;
  }
  if (lane == 63) lds[wid] = inc;
  __syncthreads();
  if (threadIdx.x == 0) {
    int a = 0;
#pragma unroll
    for (int w = 0; w < 4; ++w) { int t = lds[w]; lds[w] = a; a += t; }
    lds[4] = a;
  }
  __syncthreads();
  total = lds[4];
  int res = inc - v + lds[wid];
  __syncthreads();           // lds reusable by caller
  return res;
}

// ---------------- BFS / enc kernels ----------------
__global__ __launch_bounds__(256) void k_seed(const int* seeds, uint8_t* frontier, uint8_t* masked) {
  int i = blockIdx.x * 256 + threadIdx.x;
  if (i < NSEED) { int v = seeds[i]; frontier[v] = 1; masked[v] = 1; }
}

__global__ __launch_bounds__(256) void k_copy_rc(const int* rows, const int* cols, float* out) {
  int e = blockIdx.x * 256 + threadIdx.x;
  out[e] = (float)rows[e];
  out[EDGES + e] = (float)cols[e];
}

__global__ __launch_bounds__(256) void k_bfs0(const int* rows, const int* cols,
                                              const uint8_t* frontier, uint8_t* alive, uint8_t* nxt) {
  int e = blockIdx.x * 256 + threadIdx.x;
  int r = rows[e], c = cols[e];
  if (frontier[r] | frontier[c]) { alive[e] = 0; nxt[r] = 1; nxt[c] = 1; }
}

__global__ __launch_bounds__(256) void k_masked_or(uint8_t* masked, const uint8_t* nxt) {
  int v = blockIdx.x * 256 + threadIdx.x;
  if (v < NNODE) masked[v] |= nxt[v];
}

__global__ __launch_bounds__(256) void k_bfs1(const int* rows, const int* cols,
                                              const uint8_t* nxt, uint8_t* alive) {
  int e = blockIdx.x * 256 + threadIdx.x;
  if (alive[e] && (nxt[rows[e]] | nxt[cols[e]])) alive[e] = 0;
}

// masked_nodes.at[randint(ks,(15000,),0,N)].set(True)
__global__ __launch_bounds__(256) void k_sample(uint8_t* masked,
                                                uint32_t a0, uint32_t a1, uint32_t b0, uint32_t b1) {
  int i = blockIdx.x * 256 + threadIdx.x;
  if (i >= NSAMP) return;
  unsigned long long hi = tf_bits64(a0, a1, (uint32_t)i);
  unsigned long long lo = tf_bits64(b0, b1, (uint32_t)i);
  unsigned long long off = ((hi % SPAN) * MULTK + (lo % SPAN)) % SPAN;
  masked[off] = 1;
}

__global__ __launch_bounds__(256) void k_deg(const int* rows, const uint8_t* alive, float* deg) {
  int e = blockIdx.x * 256 + threadIdx.x;
  if (alive[e]) atomicAdd(&deg[rows[e]], 1.0f);
}

__global__ __launch_bounds__(256) void k_dnorm(const float* deg, float* dnorm) {
  int v = blockIdx.x * 256 + threadIdx.x;
  if (v < NNODE) {
    float x = deg[v] + 1e-12f;                  // f32 add like jnp
    dnorm[v] = (float)(1.0 / sqrt((double)x));  // (x)^-0.5, high-precision
  }
}

__global__ __launch_bounds__(256) void k_enc(const int* rows, const int* cols,
                                             const uint8_t* alive, const float* dnorm, float* out) {
  int e = blockIdx.x * 256 + threadIdx.x;
  out[2 * EDGES + e] = alive[e] ? dnorm[rows[e]] * dnorm[cols[e]] : 0.0f;
}

// ---------------- masked-node compaction (= argsort(~masked) prefix) ----------------
__global__ __launch_bounds__(256) void k_mreduce(const uint8_t* masked, int* mPart) {
  __shared__ int lds[4];
  int base = blockIdx.x * SORT_TILE;
  int s = 0;
  for (int i = threadIdx.x; i < SORT_TILE; i += 256) {
    int idx = base + i;
    if (idx < NNODE) s += masked[idx];
  }
#pragma unroll
  for (int off = 32; off; off >>= 1) s += __shfl_down(s, off, 64);
  if ((threadIdx.x & 63) == 0) lds[threadIdx.x >> 6] = s;
  __syncthreads();
  if (threadIdx.x == 0) mPart[blockIdx.x] = lds[0] + lds[1] + lds[2] + lds[3];
}

// single-block exclusive scan, m <= 2048 (1024 threads)
__global__ __launch_bounds__(1024) void k_scan_small(int* part, int m, int* totalOut) {
  __shared__ int a[2048];
  int tid = threadIdx.x;
  a[tid] = (tid < m) ? part[tid] : 0;
  a[tid + 1024] = (tid + 1024 < m) ? part[tid + 1024] : 0;
  __syncthreads();
  for (int off = 1; off < 2048; off <<= 1) {
    int v1 = 0, v2;
    if (tid >= off) v1 = a[tid - off];
    v2 = a[tid + 1024 - off];
    __syncthreads();
    if (tid >= off) a[tid] += v1;
    a[tid + 1024] += v2;
    __syncthreads();
  }
  if (tid < m) part[tid] = (tid == 0) ? 0 : a[tid - 1];
  if (tid + 1024 < m) part[tid + 1024] = a[tid + 1023];
  if (tid == 0 && totalOut) *totalOut = a[2047];
}

__global__ __launch_bounds__(256) void k_mscatter(const uint8_t* masked, const int* mPart, int* mlist) {
  __shared__ int lds[8];
  int t0 = blockIdx.x * SORT_TILE + threadIdx.x * 8;
  int c = 0;
#pragma unroll
  for (int k = 0; k < 8; ++k) { int idx = t0 + k; c += (idx < NNODE) ? masked[idx] : 0; }
  int total;
  int ex = block_excl_scan_256(c, lds, total);
  int run = mPart[blockIdx.x] + ex;
#pragma unroll
  for (int k = 0; k < 8; ++k) {
    int idx = t0 + k;
    if (idx < NNODE && masked[idx]) mlist[run++] = idx;
  }
}

// ---------------- hash building (append nonzero; 0 handled analytically) ----------------
__global__ __launch_bounds__(256) void k_build_pairs(const int* mlist, const int* counters,
                                                     unsigned long long* B, int* cnt,
                                                     uint32_t r0, uint32_t r1, uint32_t c0, uint32_t c1) {
  int e = blockIdx.x * 256 + threadIdx.x;
  long long tem = counters[1];
  unsigned long long bits = tf_bits64(r0, r1, (uint32_t)e);
  double u1 = __longlong_as_double((long long)((bits >> 12) | 0x3FF0000000000000ULL)) - 1.0;
  long long i1 = (long long)(u1 * (double)tem); if (i1 > tem - 1) i1 = tem - 1;
  bits = tf_bits64(c0, c1, (uint32_t)e);
  double u2 = __longlong_as_double((long long)((bits >> 12) | 0x3FF0000000000000ULL)) - 1.0;
  long long i2 = (long long)(u2 * (double)tem); if (i2 > tem - 1) i2 = tem - 1;
  long long tr = mlist[i1], tc = mlist[i2];
  unsigned long long v1 = (unsigned long long)(tr * 150000LL + tc);
  unsigned long long v2 = (unsigned long long)(tc * 150000LL + tr);
  int n = (v1 != 0) + (v2 != 0);
  if (n) {
    int p = atomicAdd(cnt, n);
    if (v1) B[p++] = v1;
    if (v2) B[p] = v2;
  }
}

__global__ __launch_bounds__(256) void k_build_self(unsigned long long* B, int* cnt) {
  int v = blockIdx.x * 256 + threadIdx.x;
  if (v == 0 || v >= NNODE) return;
  int p = atomicAdd(cnt, 1);
  B[p] = (unsigned long long)v * 150001ULL;
}

__global__ __launch_bounds__(256) void k_build_tail(const int* rows, const int* cols,
                                                    const uint8_t* alive, unsigned long long* B, int* cnt) {
  int e = blockIdx.x * 256 + threadIdx.x;
  if (!alive[e]) return;
  unsigned long long v = (unsigned long long)((long long)rows[e] * 150000LL + cols[e]);
  if (!v) return;
  int p = atomicAdd(cnt, 1);
  B[p] = v;
}

__global__ __launch_bounds__(256) void k_pad(unsigned long long* B, const int* cnt) {
  int i = blockIdx.x * 256 + threadIdx.x;   // grid covers MP exactly
  if (i >= *cnt) B[i] = SENTK;
}

// ---------------- LSD radix sort (35 bits: 8,8,8,8,3) ----------------
__global__ __launch_bounds__(256) void k_rhist(const unsigned long long* __restrict__ src,
                                               int* __restrict__ hist, int shift, int nbits) {
  __shared__ int h[256];
  int radix = 1 << nbits;
  h[threadIdx.x] = 0;
  __syncthreads();
  size_t base = (size_t)blockIdx.x * SORT_TILE;
  for (int i = threadIdx.x; i < SORT_TILE; i += 256) {
    int d = ((int)(src[base + i] >> shift)) & (radix - 1);
    atomicAdd(&h[d], 1);
  }
  __syncthreads();
  if (threadIdx.x < radix) hist[(size_t)threadIdx.x * NT + blockIdx.x] = h[threadIdx.x];
}

__global__ __launch_bounds__(256) void k_scan_reduce(const int* g, int* part, int n) {
  __shared__ int lds[4];
  int base = blockIdx.x * SORT_TILE;
  int s = 0;
  for (int i = threadIdx.x; i < SORT_TILE; i += 256) {
    int idx = base + i;
    if (idx < n) s += g[idx];
  }
#pragma unroll
  for (int off = 32; off; off >>= 1) s += __shfl_down(s, off, 64);
  if ((threadIdx.x & 63) == 0) lds[threadIdx.x >> 6] = s;
  __syncthreads();
  if (threadIdx.x == 0) part[blockIdx.x] = lds[0] + lds[1] + lds[2] + lds[3];
}

__global__ __launch_bounds__(256) void k_scan_apply(int* g, const int* part, int n) {
  __shared__ int lds[8];
  int t0 = blockIdx.x * SORT_TILE + threadIdx.x * 8;
  int x[8];
#pragma unroll
  for (int k = 0; k < 8; ++k) { int idx = t0 + k; x[k] = (idx < n) ? g[idx] : 0; }
  int s = 0;
#pragma unroll
  for (int k = 0; k < 8; ++k) { int t = x[k]; x[k] = s; s += t; }
  int total;
  int ex = block_excl_scan_256(s, lds, total);
  int add = part[blockIdx.x] + ex;
#pragma unroll
  for (int k = 0; k < 8; ++k) { int idx = t0 + k; if (idx < n) g[idx] = x[k] + add; }
}

// LDS bank-conflict-free swizzle for 8-elem/thread chunk layout (4B arrays)
__device__ inline int swz(int i) {
  int t = i >> 3, k = i & 7;
  return (t << 3) | ((k + (t >> 2)) & 7);
}

__global__ __launch_bounds__(256) void k_rscatter(const unsigned long long* __restrict__ src,
                                                  unsigned long long* __restrict__ dst,
                                                  const int* __restrict__ hist, int shift, int nbits) {
  __shared__ uint32_t klo[SORT_TILE], khi[SORT_TILE];
  __shared__ int dstart[256];
  __shared__ int lds[8];
  int mask = (1 << nbits) - 1;
  size_t base = (size_t)blockIdx.x * SORT_TILE;
  for (int i = threadIdx.x; i < SORT_TILE; i += 256) {
    unsigned long long v = src[base + i];
    int p = swz(i);
    klo[p] = (uint32_t)v; khi[p] = (uint32_t)(v >> 32);
  }
  __syncthreads();
  int t0 = threadIdx.x * 8;
  for (int b = 0; b < nbits; ++b) {   // stable 1-bit splits => local radix sort
    int sh = shift + b;
    unsigned long long mk[8];
    int zeros = 0;
#pragma unroll
    for (int k = 0; k < 8; ++k) {
      int p = swz(t0 + k);
      mk[k] = ((unsigned long long)khi[p] << 32) | klo[p];
      zeros += 1 - (int)((mk[k] >> sh) & 1ULL);
    }
    __syncthreads();
    int total;
    int zex = block_excl_scan_256(zeros, lds, total);
    int zpos = zex, opos = total + t0 - zex;
#pragma unroll
    for (int k = 0; k < 8; ++k) {
      unsigned long long key = mk[k];
      int pos = (((key >> sh) & 1ULL) == 0) ? zpos++ : opos++;
      int p = swz(pos);
      klo[p] = (uint32_t)key; khi[p] = (uint32_t)(key >> 32);
    }
    __syncthreads();
  }
  dstart[threadIdx.x] = 0;
  __syncthreads();
#pragma unroll
  for (int k = 0; k < 8; ++k) {
    int p = swz(t0 + k);
    unsigned long long key = ((unsigned long long)khi[p] << 32) | klo[p];
    atomicAdd(&dstart[((int)(key >> shift)) & mask], 1);
  }
  __syncthreads();
  {
    int v = dstart[threadIdx.x];
    __syncthreads();
    int tot;
    int ex = block_excl_scan_256(v, lds, tot);
    dstart[threadIdx.x] = ex;
    __syncthreads();
  }
  for (int i = threadIdx.x; i < SORT_TILE; i += 256) {
    int p = swz(i);
    unsigned long long key = ((unsigned long long)khi[p] << 32) | klo[p];
    int d = ((int)(key >> shift)) & mask;
    dst[(size_t)(hist[(size_t)d * NT + blockIdx.x] + (i - dstart[d]))] = key;
  }
}

// ---------------- unique + final decoder write ----------------
__global__ __launch_bounds__(256) void k_uniq_count(const unsigned long long* A, int* uPart) {
  __shared__ int lds[4];
  size_t base = (size_t)blockIdx.x * SORT_TILE;
  int c = 0;
  for (int i = threadIdx.x; i < SORT_TILE; i += 256) {
    size_t g = base + i;
    unsigned long long v = A[g];
    if (v != SENTK && (g == 0 || A[g - 1] != v)) c++;
  }
#pragma unroll
  for (int off = 32; off; off >>= 1) c += __shfl_down(c, off, 64);
  if ((threadIdx.x & 63) == 0) lds[threadIdx.x >> 6] = c;
  __syncthreads();
  if (threadIdx.x == 0) uPart[blockIdx.x] = lds[0] + lds[1] + lds[2] + lds[3];
}

__global__ __launch_bounds__(256) void k_final(const unsigned long long* A, const int* uPart, float* out) {
  __shared__ int lds[8];
  size_t base = (size_t)blockIdx.x * SORT_TILE + (size_t)threadIdx.x * 8;
  unsigned long long v[8];
  int f[8], c = 0;
#pragma unroll
  for (int k = 0; k < 8; ++k) {
    size_t g = base + k;
    v[k] = A[g];
    f[k] = (v[k] != SENTK && (g == 0 || A[g - 1] != v[k])) ? 1 : 0;
    c += f[k];
  }
  int total;
  int ex = block_excl_scan_256(c, lds, total);
  int j = 1 + uPart[blockIdx.x] + ex;   // +1: slot 0 is the always-present hash 0
#pragma unroll
  for (int k = 0; k < 8; ++k) {
    if (f[k]) {
      unsigned long long q = v[k] / 150000ULL, r = v[k] % 150000ULL;
      out[OUT_DR + j] = (float)q;
      out[OUT_DC + j] = (float)r;
      out[OUT_DV + j] = 1.0f;
      j++;
    }
  }
  if (blockIdx.x == 0 && threadIdx.x == 0) out[OUT_DV] = 1.0f;  // dec_vals[0]=1 (rows/cols stay 0)
}

// ---------------- host launcher ----------------
extern "C" void kernel_launch(void* const* d_in, const int* in_sizes, int n_in,
                              void* d_out, int out_size, void* d_ws, size_t ws_size,
                              hipStream_t stream) {
  const int* rows = (const int*)d_in[1];   // d_in[0]=adj_vals (unused by reference outputs)
  const int* cols = (const int*)d_in[2];
  const int* seeds = (const int*)d_in[3];
  float* out = (float*)d_out;

  // workspace layout
  char* ws = (char*)d_ws;
  size_t off = 0;
  auto alloc = [&](size_t bytes) -> char* {
    char* p = ws + off;
    off += (bytes + 255) & ~(size_t)255;
    return p;
  };
  unsigned long long* A = (unsigned long long*)alloc((size_t)MP * 8);
  uint8_t* alive = (uint8_t*)alloc(EDGES);
  char* zbase = ws + off;                       // ---- zeroed zone ----
  uint8_t* frontier = (uint8_t*)alloc(NNODE);
  uint8_t* nextf = (uint8_t*)alloc(NNODE);
  uint8_t* masked = (uint8_t*)alloc(NNODE);
  float* deg = (float*)alloc((size_t)NNODE * 4);
  int* counters = (int*)alloc(256 * 4);          // [0]=append cnt, [1]=tem_num
  size_t zsize = (size_t)((ws + off) - zbase);  // ---- end zeroed zone ----
  float* dnorm = (float*)alloc((size_t)NNODE * 4);
  int* mlist = (int*)alloc((size_t)NNODE * 4);
  int* hist = (int*)alloc((size_t)256 * NT * 4);
  int* spart = (int*)alloc(2048 * 4);
  int* uPart = (int*)alloc((size_t)NT * 4);
  int* uPart2 = (int*)alloc(2048 * 4);
  int* mPart = (int*)alloc(256 * 4);

  // radix ping-pong buffer B lives in the (later-overwritten) dec region of d_out
  unsigned long long* Bbuf = (unsigned long long*)(out + OUT_DR);

  // JAX key derivation (threefry_partitionable=True semantics):
  // key(42)=(0,42); split(key,3)[i] = tf(key,(0,i)); randint's internal split of ks likewise.
  uint32_t ks0, ks1, kr0, kr1, kc0, kc1, s10, s11, s20, s21;
  tf2x32(0u, 42u, 0u, 0u, ks0, ks1);
  tf2x32(0u, 42u, 0u, 1u, kr0, kr1);
  tf2x32(0u, 42u, 0u, 2u, kc0, kc1);
  tf2x32(ks0, ks1, 0u, 0u, s10, s11);   // randint k1 (higher bits)
  tf2x32(ks0, ks1, 0u, 1u, s20, s21);   // randint k2 (lower bits)

  hipMemsetAsync(zbase, 0, zsize, stream);
  hipMemsetAsync(alive, 1, EDGES, stream);

  const int EB = EDGES / 256;                // 15625
  const int NB = (NNODE + 255) / 256;        // 586

  k_seed<<<2, 256, 0, stream>>>(seeds, frontier, masked);
  k_copy_rc<<<EB, 256, 0, stream>>>(rows, cols, out);
  k_bfs0<<<EB, 256, 0, stream>>>(rows, cols, frontier, alive, nextf);
  k_masked_or<<<NB, 256, 0, stream>>>(masked, nextf);
  k_bfs1<<<EB, 256, 0, stream>>>(rows, cols, nextf, alive);
  k_sample<<<(NSAMP + 255) / 256, 256, 0, stream>>>(masked, s10, s11, s20, s21);
  k_deg<<<EB, 256, 0, stream>>>(rows, alive, deg);
  k_dnorm<<<NB, 256, 0, stream>>>(deg, dnorm);
  k_enc<<<EB, 256, 0, stream>>>(rows, cols, alive, dnorm, out);

  // masked node list (ascending) + tem_num
  const int MB = (NNODE + SORT_TILE - 1) / SORT_TILE;   // 74
  k_mreduce<<<MB, 256, 0, stream>>>(masked, mPart);
  k_scan_small<<<1, 1024, 0, stream>>>(mPart, MB, counters + 1);
  k_mscatter<<<MB, 256, 0, stream>>>(masked, mPart, mlist);

  // hash multiset (nonzero only) + sentinel pad to MP
  k_build_pairs<<<EB, 256, 0, stream>>>(mlist, counters, Bbuf, counters + 0, kr0, kr1, kc0, kc1);
  k_build_self<<<NB, 256, 0, stream>>>(Bbuf, counters + 0);
  k_build_tail<<<EB, 256, 0, stream>>>(rows, cols, alive, Bbuf, counters + 0);
  k_pad<<<MP / 256, 256, 0, stream>>>(Bbuf, counters + 0);

  // radix sort: B -> A -> B -> A -> B -> A (5 passes, 35 bits)
  unsigned long long* src = Bbuf;
  unsigned long long* dst = A;
  const int shifts[5] = {0, 8, 16, 24, 32};
  const int bitsp[5] = {8, 8, 8, 8, 3};
  for (int p = 0; p < 5; ++p) {
    int n = (1 << bitsp[p]) * NT;
    int scb = (n + SORT_TILE - 1) / SORT_TILE;
    k_rhist<<<NT, 256, 0, stream>>>(src, hist, shifts[p], bitsp[p]);
    k_scan_reduce<<<scb, 256, 0, stream>>>(hist, spart, n);
    k_scan_small<<<1, 1024, 0, stream>>>(spart, scb, nullptr);
    k_scan_apply<<<scb, 256, 0, stream>>>(hist, spart, n);
    k_rscatter<<<NT, 256, 0, stream>>>(src, dst, hist, shifts[p], bitsp[p]);
    unsigned long long* t = src; src = dst; dst = t;
  }
  // sorted result now in A (src == A)

  // zero dec region (padding slots must be 0,0,0), then compact uniques
  hipMemsetAsync(out + OUT_DR, 0, (size_t)3 * MOUT * 4, stream);
  k_uniq_count<<<NT, 256, 0, stream>>>(src, uPart);
  const int UB = (NT + SORT_TILE - 1) / SORT_TILE;   // 3
  k_scan_reduce<<<UB, 256, 0, stream>>>(uPart, uPart2, NT);
  k_scan_small<<<1, 1024, 0, stream>>>(uPart2, UB, nullptr);
  k_scan_apply<<<UB, 256, 0, stream>>>(uPart, uPart2, NT);
  k_final<<<NT, 256, 0, stream>>>(src, uPart, out);
}

// Round 2
// 2417.331 us; speedup vs baseline: 1.1258x; 1.1258x over previous
//
#include <hip/hip_runtime.h>
#include <stdint.h>

// ---------------- problem constants ----------------
#define NNODE   150000
#define EDGES   4000000
#define NSEED   500
#define NSAMP   15000              // int(150000 * 0.1)
#define MOUT    12150000           // 3E + N : decoder output length
#define SENTK   0xFFFFFFFFFFFFFFFFULL
#define SPAN    150000ULL
#define MULTK   51616ULL           // ((2^32 % 150000)^2) % 150000

// sort geometry
#define TILE    8192
#define TH      512
#define NT      1484               // ceil(MOUT / TILE)
#define MP      (NT * TILE)        // 12,156,928
#define PAD     (MP - MOUT)        // 6,928
#define RADIX   512
#define NHIST   (RADIX * NT)       // 759,808
#define SCB     (NHIST / 2048)     // 371 (exact)

// masked-node compaction geometry
#define MTILE   2048
#define MB      ((NNODE + MTILE - 1) / MTILE)   // 74

// out layout (float32): [rows E][cols E][enc E][dec_rows M][dec_cols M][dec_vals M]
#define OUT_DR  12000000
#define OUT_DC  24150000
#define OUT_DV  36300000

// ---------------- threefry2x32 (JAX-exact, 20 rounds) ----------------
__host__ __device__ inline void tf2x32(uint32_t k0, uint32_t k1,
                                       uint32_t x0, uint32_t x1,
                                       uint32_t& o0, uint32_t& o1) {
  uint32_t ks2 = k0 ^ k1 ^ 0x1BD11BDAu;
  x0 += k0; x1 += k1;
#define TFR(d) { x0 += x1; x1 = (x1 << d) | (x1 >> (32 - d)); x1 ^= x0; }
  TFR(13) TFR(15) TFR(26) TFR(6)
  x0 += k1; x1 += ks2 + 1u;
  TFR(17) TFR(29) TFR(16) TFR(24)
  x0 += ks2; x1 += k0 + 2u;
  TFR(13) TFR(15) TFR(26) TFR(6)
  x0 += k0; x1 += k1 + 3u;
  TFR(17) TFR(29) TFR(16) TFR(24)
  x0 += k1; x1 += ks2 + 4u;
  TFR(13) TFR(15) TFR(26) TFR(6)
  x0 += ks2; x1 += k0 + 5u;
#undef TFR
  o0 = x0; o1 = x1;
}

__device__ inline unsigned long long tf_bits64(uint32_t k0, uint32_t k1, uint32_t i) {
  uint32_t o0, o1;
  tf2x32(k0, k1, 0u, i, o0, o1);
  return ((unsigned long long)o0 << 32) | o1;
}

// ---------------- block primitives ----------------
__device__ inline int block_excl_scan_256(int v, int* lds /*>=5 ints*/, int& total) {
  int lane = threadIdx.x & 63, wid = threadIdx.x >> 6;
  int inc = v;
#pragma unroll
  for (int off = 1; off < 64; off <<= 1) {
    int y = __shfl_up(inc, off, 64);
    if (lane >= off) inc += y;
  }
  if (lane == 63) lds[wid] = inc;
  __syncthreads();
  if (threadIdx.x == 0) {
    int a = 0;
#pragma unroll
    for (int w = 0; w < 4; ++w) { int t = lds[w]; lds[w] = a; a += t; }
    lds[4] = a;
  }
  __syncthreads();
  total = lds[4];
  int res = inc - v + lds[wid];
  __syncthreads();
  return res;
}

// exclusive scan of 4 ints across 512 threads; aux >= 36 ints.
// Caller must have a barrier before aux is reused (round-end barrier).
__device__ inline void scan512_x4(const int v[4], int ex[4], int tot[4], int* aux) {
  int lane = threadIdx.x & 63, wid = threadIdx.x >> 6;
  int inc[4];
#pragma unroll
  for (int j = 0; j < 4; ++j) inc[j] = v[j];
#pragma unroll
  for (int off = 1; off < 64; off <<= 1) {
#pragma unroll
    for (int j = 0; j < 4; ++j) {
      int y = __shfl_up(inc[j], off, 64);
      if (lane >= off) inc[j] += y;
    }
  }
  if (lane == 63) {
#pragma unroll
    for (int j = 0; j < 4; ++j) aux[j * 8 + wid] = inc[j];
  }
  __syncthreads();
  if (threadIdx.x == 0) {
#pragma unroll
    for (int j = 0; j < 4; ++j) {
      int a = 0;
#pragma unroll
      for (int w = 0; w < 8; ++w) { int t = aux[j * 8 + w]; aux[j * 8 + w] = a; a += t; }
      aux[32 + j] = a;
    }
  }
  __syncthreads();
#pragma unroll
  for (int j = 0; j < 4; ++j) {
    ex[j] = inc[j] - v[j] + aux[j * 8 + wid];
    tot[j] = aux[32 + j];
  }
}

__device__ inline int scan512_1(int v, int* aux /*>=9 ints*/) {
  int lane = threadIdx.x & 63, wid = threadIdx.x >> 6;
  int inc = v;
#pragma unroll
  for (int off = 1; off < 64; off <<= 1) {
    int y = __shfl_up(inc, off, 64);
    if (lane >= off) inc += y;
  }
  if (lane == 63) aux[wid] = inc;
  __syncthreads();
  if (threadIdx.x == 0) {
    int a = 0;
#pragma unroll
    for (int w = 0; w < 8; ++w) { int t = aux[w]; aux[w] = a; a += t; }
  }
  __syncthreads();
  return inc - v + aux[wid];
}

// LDS swizzle: rotate within 16-element rows to break 16-stride bank aliasing
__device__ inline int phys16(int p) { return (p & ~15) | ((p + (p >> 4)) & 15); }

// ---------------- BFS / enc kernels ----------------
__global__ __launch_bounds__(256) void k_seed(const int* seeds, uint8_t* frontier, uint8_t* masked) {
  int i = blockIdx.x * 256 + threadIdx.x;
  if (i < NSEED) { int v = seeds[i]; frontier[v] = 1; masked[v] = 1; }
}

__global__ __launch_bounds__(256) void k_copy_rc(const int* rows, const int* cols, float* out) {
  int e = blockIdx.x * 256 + threadIdx.x;
  out[e] = (float)rows[e];
  out[EDGES + e] = (float)cols[e];
}

__global__ __launch_bounds__(256) void k_bfs0(const int* rows, const int* cols,
                                              const uint8_t* frontier, uint8_t* alive, uint8_t* nxt) {
  int e = blockIdx.x * 256 + threadIdx.x;
  int r = rows[e], c = cols[e];
  if (frontier[r] | frontier[c]) { alive[e] = 0; nxt[r] = 1; nxt[c] = 1; }
}

__global__ __launch_bounds__(256) void k_masked_or(uint8_t* masked, const uint8_t* nxt) {
  int v = blockIdx.x * 256 + threadIdx.x;
  if (v < NNODE) masked[v] |= nxt[v];
}

__global__ __launch_bounds__(256) void k_bfs1(const int* rows, const int* cols,
                                              const uint8_t* nxt, uint8_t* alive) {
  int e = blockIdx.x * 256 + threadIdx.x;
  if (alive[e] && (nxt[rows[e]] | nxt[cols[e]])) alive[e] = 0;
}

__global__ __launch_bounds__(256) void k_sample(uint8_t* masked,
                                                uint32_t a0, uint32_t a1, uint32_t b0, uint32_t b1) {
  int i = blockIdx.x * 256 + threadIdx.x;
  if (i >= NSAMP) return;
  unsigned long long hi = tf_bits64(a0, a1, (uint32_t)i);
  unsigned long long lo = tf_bits64(b0, b1, (uint32_t)i);
  unsigned long long off = ((hi % SPAN) * MULTK + (lo % SPAN)) % SPAN;
  masked[off] = 1;
}

__global__ __launch_bounds__(256) void k_deg(const int* rows, const uint8_t* alive, float* deg) {
  int e = blockIdx.x * 256 + threadIdx.x;
  if (alive[e]) atomicAdd(&deg[rows[e]], 1.0f);
}

__global__ __launch_bounds__(256) void k_dnorm(const float* deg, float* dnorm) {
  int v = blockIdx.x * 256 + threadIdx.x;
  if (v < NNODE) {
    float x = deg[v] + 1e-12f;
    dnorm[v] = (float)(1.0 / sqrt((double)x));
  }
}

__global__ __launch_bounds__(256) void k_enc(const int* rows, const int* cols,
                                             const uint8_t* alive, const float* dnorm, float* out) {
  int e = blockIdx.x * 256 + threadIdx.x;
  out[2 * EDGES + e] = alive[e] ? dnorm[rows[e]] * dnorm[cols[e]] : 0.0f;
}

// ---------------- masked-node compaction ----------------
__global__ __launch_bounds__(256) void k_mreduce(const uint8_t* masked, int* mPart) {
  __shared__ int lds[4];
  int base = blockIdx.x * MTILE;
  int s = 0;
  for (int i = threadIdx.x; i < MTILE; i += 256) {
    int idx = base + i;
    if (idx < NNODE) s += masked[idx];
  }
#pragma unroll
  for (int off = 32; off; off >>= 1) s += __shfl_down(s, off, 64);
  if ((threadIdx.x & 63) == 0) lds[threadIdx.x >> 6] = s;
  __syncthreads();
  if (threadIdx.x == 0) mPart[blockIdx.x] = lds[0] + lds[1] + lds[2] + lds[3];
}

// single-block exclusive scan, m <= 2048 (1024 threads)
__global__ __launch_bounds__(1024) void k_scan_small(int* part, int m, int* totalOut) {
  __shared__ int a[2048];
  int tid = threadIdx.x;
  a[tid] = (tid < m) ? part[tid] : 0;
  a[tid + 1024] = (tid + 1024 < m) ? part[tid + 1024] : 0;
  __syncthreads();
  for (int off = 1; off < 2048; off <<= 1) {
    int v1 = 0, v2;
    if (tid >= off) v1 = a[tid - off];
    v2 = a[tid + 1024 - off];
    __syncthreads();
    if (tid >= off) a[tid] += v1;
    a[tid + 1024] += v2;
    __syncthreads();
  }
  if (tid < m) part[tid] = (tid == 0) ? 0 : a[tid - 1];
  if (tid + 1024 < m) part[tid + 1024] = a[tid + 1023];
  if (tid == 0 && totalOut) *totalOut = a[2047];
}

__global__ __launch_bounds__(256) void k_mscatter(const uint8_t* masked, const int* mPart, int* mlist) {
  __shared__ int lds[8];
  int t0 = blockIdx.x * MTILE + threadIdx.x * 8;
  int c = 0;
#pragma unroll
  for (int k = 0; k < 8; ++k) { int idx = t0 + k; c += (idx < NNODE) ? masked[idx] : 0; }
  int total;
  int ex = block_excl_scan_256(c, lds, total);
  int run = mPart[blockIdx.x] + ex;
#pragma unroll
  for (int k = 0; k < 8; ++k) {
    int idx = t0 + k;
    if (idx < NNODE && masked[idx]) mlist[run++] = idx;
  }
}

// ---------------- hash building (deterministic slots, no atomics) ----------------
__global__ __launch_bounds__(256) void k_build_pairs(const int* mlist, const int* counters,
                                                     unsigned long long* A,
                                                     uint32_t r0, uint32_t r1, uint32_t c0, uint32_t c1) {
  int e = blockIdx.x * 256 + threadIdx.x;
  long long tem = counters[1];
  unsigned long long bits = tf_bits64(r0, r1, (uint32_t)e);
  double u1 = __longlong_as_double((long long)((bits >> 12) | 0x3FF0000000000000ULL)) - 1.0;
  long long i1 = (long long)(u1 * (double)tem); if (i1 > tem - 1) i1 = tem - 1;
  bits = tf_bits64(c0, c1, (uint32_t)e);
  double u2 = __longlong_as_double((long long)((bits >> 12) | 0x3FF0000000000000ULL)) - 1.0;
  long long i2 = (long long)(u2 * (double)tem); if (i2 > tem - 1) i2 = tem - 1;
  long long tr = mlist[i1], tc = mlist[i2];
  unsigned long long v1 = (unsigned long long)(tr * 150000LL + tc);
  unsigned long long v2 = (unsigned long long)(tc * 150000LL + tr);
  A[2 * (size_t)e]     = v1 ? v1 : SENTK;
  A[2 * (size_t)e + 1] = v2 ? v2 : SENTK;
}

__global__ __launch_bounds__(256) void k_build_self(unsigned long long* A) {
  int v = blockIdx.x * 256 + threadIdx.x;
  if (v >= NNODE) return;
  A[2 * (size_t)EDGES + v] = v ? (unsigned long long)v * 150001ULL : SENTK;
}

__global__ __launch_bounds__(256) void k_build_tail(const int* rows, const int* cols,
                                                    const uint8_t* alive, unsigned long long* A) {
  int e = blockIdx.x * 256 + threadIdx.x;
  unsigned long long v = (unsigned long long)((long long)rows[e] * 150000LL + cols[e]);
  A[2 * (size_t)EDGES + NNODE + e] = (alive[e] && v) ? v : SENTK;
}

__global__ __launch_bounds__(256) void k_pad(unsigned long long* A) {
  int i = blockIdx.x * 256 + threadIdx.x;
  if (i < PAD) A[(size_t)MOUT + i] = SENTK;
}

// ---------------- LSD radix sort: 4 passes x 9 bits (36-bit keyspace) ----------------
__global__ __launch_bounds__(TH) void k_rhist9(const unsigned long long* __restrict__ src,
                                               int* __restrict__ hist, int shift) {
  __shared__ int h[RADIX];
  h[threadIdx.x] = 0;
  __syncthreads();
  size_t base = (size_t)blockIdx.x * TILE;
#pragma unroll
  for (int r = 0; r < 16; ++r) {
    int i = threadIdx.x + r * TH;
    int d = ((int)(src[base + i] >> shift)) & (RADIX - 1);
    atomicAdd(&h[d], 1);
  }
  __syncthreads();
  hist[(size_t)threadIdx.x * NT + blockIdx.x] = h[threadIdx.x];
}

__global__ __launch_bounds__(256) void k_scan_reduce(const int* g, int* part, int n) {
  __shared__ int lds[4];
  int base = blockIdx.x * 2048;
  int s = 0;
  for (int i = threadIdx.x; i < 2048; i += 256) {
    int idx = base + i;
    if (idx < n) s += g[idx];
  }
#pragma unroll
  for (int off = 32; off; off >>= 1) s += __shfl_down(s, off, 64);
  if ((threadIdx.x & 63) == 0) lds[threadIdx.x >> 6] = s;
  __syncthreads();
  if (threadIdx.x == 0) part[blockIdx.x] = lds[0] + lds[1] + lds[2] + lds[3];
}

__global__ __launch_bounds__(256) void k_scan_apply(int* g, const int* part, int n) {
  __shared__ int lds[8];
  int t0 = blockIdx.x * 2048 + threadIdx.x * 8;
  int x[8];
#pragma unroll
  for (int k = 0; k < 8; ++k) { int idx = t0 + k; x[k] = (idx < n) ? g[idx] : 0; }
  int s = 0;
#pragma unroll
  for (int k = 0; k < 8; ++k) { int t = x[k]; x[k] = s; s += t; }
  int total;
  int ex = block_excl_scan_256(s, lds, total);
  int add = part[blockIdx.x] + ex;
#pragma unroll
  for (int k = 0; k < 8; ++k) { int idx = t0 + k; if (idx < n) g[idx] = x[k] + add; }
}

__global__ __launch_bounds__(TH, 4) void k_rscatter9(const unsigned long long* __restrict__ src,
                                                     unsigned long long* __restrict__ dst,
                                                     const int* __restrict__ hist, int shift) {
  __shared__ uint32_t klo[TILE], khi[TILE];
  __shared__ int dstart[RADIX];
  __shared__ int aux[36];
  size_t gbase = (size_t)blockIdx.x * TILE;
  // global -> LDS (coalesced)
#pragma unroll
  for (int r = 0; r < 16; ++r) {
    int i = threadIdx.x + r * TH;
    unsigned long long v = src[gbase + i];
    int p = phys16(i);
    klo[p] = (uint32_t)v; khi[p] = (uint32_t)(v >> 32);
  }
  __syncthreads();
  int t0 = threadIdx.x * 16;
  // 3 x 3-bit stable split rounds -> tile sorted by 9-bit digit
  for (int rr = 0; rr < 3; ++rr) {
    int sh = shift + 3 * rr;
    unsigned long long key[16];
    int c[8] = {0, 0, 0, 0, 0, 0, 0, 0};
#pragma unroll
    for (int k = 0; k < 16; ++k) {
      int p = phys16(t0 + k);
      key[k] = ((unsigned long long)khi[p] << 32) | klo[p];
      int d = (int)((key[k] >> sh) & 7);
#pragma unroll
      for (int q = 0; q < 8; ++q) c[q] += (d == q);   // keep c[] in VGPRs
    }
    int v4[4], ex[4], tot[4];
#pragma unroll
    for (int j = 0; j < 4; ++j) v4[j] = c[2 * j] | (c[2 * j + 1] << 16);
    scan512_x4(v4, ex, tot, aux);   // barriers inside also order reads-before-writes
    int start[8];
    {
      int a = 0;
#pragma unroll
      for (int j = 0; j < 4; ++j) {
        int tlo = tot[j] & 0xffff, thi = tot[j] >> 16;
        int elo = ex[j] & 0xffff,  ehi = ex[j] >> 16;
        start[2 * j]     = a + elo; a += tlo;
        start[2 * j + 1] = a + ehi; a += thi;
      }
    }
#pragma unroll
    for (int k = 0; k < 16; ++k) {
      int d = (int)((key[k] >> sh) & 7);
      int pos = 0;
#pragma unroll
      for (int q = 0; q < 8; ++q) { if (d == q) pos = start[q]; }
#pragma unroll
      for (int q = 0; q < 8; ++q) start[q] += (d == q);
      int p = phys16(pos);
      klo[p] = (uint32_t)key[k]; khi[p] = (uint32_t)(key[k] >> 32);
    }
    __syncthreads();
  }
  // digit boundaries within sorted tile (no atomics, no scan)
  unsigned long long kreg[16];
#pragma unroll
  for (int r = 0; r < 16; ++r) {
    int i = threadIdx.x + r * TH;
    int p = phys16(i);
    unsigned long long k1 = ((unsigned long long)khi[p] << 32) | klo[p];
    kreg[r] = k1;
    int d = (int)((k1 >> shift) & (RADIX - 1));
    int dp = -1;
    if (i > 0) {
      int q = phys16(i - 1);
      unsigned long long k0 = ((unsigned long long)khi[q] << 32) | klo[q];
      dp = (int)((k0 >> shift) & (RADIX - 1));
    }
    if (d != dp) dstart[d] = i;
  }
  __syncthreads();
  // scatter to global (stable: tile order preserved within digit)
#pragma unroll
  for (int r = 0; r < 16; ++r) {
    int i = threadIdx.x + r * TH;
    unsigned long long k1 = kreg[r];
    int d = (int)((k1 >> shift) & (RADIX - 1));
    dst[(size_t)(hist[(size_t)d * NT + blockIdx.x] + (i - dstart[d]))] = k1;
  }
}

// ---------------- unique + final decoder write ----------------
__global__ __launch_bounds__(TH) void k_uniq_count(const unsigned long long* A, int* uPart) {
  __shared__ int lds[8];
  size_t base = (size_t)blockIdx.x * TILE + (size_t)threadIdx.x * 16;
  unsigned long long prev = (base == 0) ? 0ULL : A[base - 1];
  int c = 0;
#pragma unroll
  for (int k = 0; k < 16; ++k) {
    unsigned long long v = A[base + k];
    c += (v != SENTK && v != prev) ? 1 : 0;
    prev = v;
  }
#pragma unroll
  for (int off = 32; off; off >>= 1) c += __shfl_down(c, off, 64);
  if ((threadIdx.x & 63) == 0) lds[threadIdx.x >> 6] = c;
  __syncthreads();
  if (threadIdx.x == 0) {
    int s = 0;
#pragma unroll
    for (int w = 0; w < 8; ++w) s += lds[w];
    uPart[blockIdx.x] = s;
  }
}

__global__ __launch_bounds__(TH) void k_final(const unsigned long long* A, const int* uPart, float* out) {
  __shared__ int aux[9];
  size_t base = (size_t)blockIdx.x * TILE + (size_t)threadIdx.x * 16;
  unsigned long long v[16];
  int f[16], c = 0;
  unsigned long long prev = (base == 0) ? 0ULL : A[base - 1];
#pragma unroll
  for (int k = 0; k < 16; ++k) {
    v[k] = A[base + k];
    f[k] = (v[k] != SENTK && v[k] != prev) ? 1 : 0;
    c += f[k];
    prev = v[k];
  }
  int ex = scan512_1(c, aux);
  int j = 1 + uPart[blockIdx.x] + ex;   // +1: slot 0 is the always-present hash 0
#pragma unroll
  for (int k = 0; k < 16; ++k) {
    if (f[k]) {
      unsigned long long val = v[k];
      long long q = (long long)((double)val * (1.0 / 150000.0));
      long long r = (long long)val - q * 150000LL;
      if (r < 0) { q--; r += 150000LL; }
      else if (r >= 150000LL) { q++; r -= 150000LL; }
      out[OUT_DR + j] = (float)q;
      out[OUT_DC + j] = (float)r;
      out[OUT_DV + j] = 1.0f;
      j++;
    }
  }
  if (blockIdx.x == 0 && threadIdx.x == 0) out[OUT_DV] = 1.0f;  // dec_vals[0]=1
}

// ---------------- host launcher ----------------
extern "C" void kernel_launch(void* const* d_in, const int* in_sizes, int n_in,
                              void* d_out, int out_size, void* d_ws, size_t ws_size,
                              hipStream_t stream) {
  const int* rows = (const int*)d_in[1];   // d_in[0]=adj_vals (unused by reference outputs)
  const int* cols = (const int*)d_in[2];
  const int* seeds = (const int*)d_in[3];
  float* out = (float*)d_out;

  // workspace layout
  char* ws = (char*)d_ws;
  size_t off = 0;
  auto alloc = [&](size_t bytes) -> char* {
    char* p = ws + off;
    off += (bytes + 255) & ~(size_t)255;
    return p;
  };
  unsigned long long* A = (unsigned long long*)alloc((size_t)MP * 8);
  uint8_t* alive = (uint8_t*)alloc(EDGES);
  char* zbase = ws + off;                       // ---- zeroed zone ----
  uint8_t* frontier = (uint8_t*)alloc(NNODE);
  uint8_t* nextf = (uint8_t*)alloc(NNODE);
  uint8_t* masked = (uint8_t*)alloc(NNODE);
  float* deg = (float*)alloc((size_t)NNODE * 4);
  int* counters = (int*)alloc(256 * 4);         // [1]=tem_num
  size_t zsize = (size_t)((ws + off) - zbase);  // ---- end zeroed zone ----
  float* dnorm = (float*)alloc((size_t)NNODE * 4);
  int* mlist = (int*)alloc((size_t)NNODE * 4);
  int* hist = (int*)alloc((size_t)NHIST * 4);
  int* spart = (int*)alloc(2048 * 4);
  int* uPart = (int*)alloc(2048 * 4);
  int* mPart = (int*)alloc(256 * 4);

  // radix ping-pong buffer B lives in the (later-overwritten) dec region of d_out
  unsigned long long* Bbuf = (unsigned long long*)(out + OUT_DR);

  // JAX key derivation (threefry_partitionable semantics)
  uint32_t ks0, ks1, kr0, kr1, kc0, kc1, s10, s11, s20, s21;
  tf2x32(0u, 42u, 0u, 0u, ks0, ks1);
  tf2x32(0u, 42u, 0u, 1u, kr0, kr1);
  tf2x32(0u, 42u, 0u, 2u, kc0, kc1);
  tf2x32(ks0, ks1, 0u, 0u, s10, s11);
  tf2x32(ks0, ks1, 0u, 1u, s20, s21);

  hipMemsetAsync(zbase, 0, zsize, stream);
  hipMemsetAsync(alive, 1, EDGES, stream);

  const int EB = EDGES / 256;                // 15625
  const int NB = (NNODE + 255) / 256;        // 586

  k_seed<<<2, 256, 0, stream>>>(seeds, frontier, masked);
  k_copy_rc<<<EB, 256, 0, stream>>>(rows, cols, out);
  k_bfs0<<<EB, 256, 0, stream>>>(rows, cols, frontier, alive, nextf);
  k_masked_or<<<NB, 256, 0, stream>>>(masked, nextf);
  k_bfs1<<<EB, 256, 0, stream>>>(rows, cols, nextf, alive);
  k_sample<<<(NSAMP + 255) / 256, 256, 0, stream>>>(masked, s10, s11, s20, s21);
  k_deg<<<EB, 256, 0, stream>>>(rows, alive, deg);
  k_dnorm<<<NB, 256, 0, stream>>>(deg, dnorm);
  k_enc<<<EB, 256, 0, stream>>>(rows, cols, alive, dnorm, out);

  // masked node list (ascending) + tem_num
  k_mreduce<<<MB, 256, 0, stream>>>(masked, mPart);
  k_scan_small<<<1, 1024, 0, stream>>>(mPart, MB, counters + 1);
  k_mscatter<<<MB, 256, 0, stream>>>(masked, mPart, mlist);

  // hash multiset at deterministic slots (0 / dead -> SENTK), into A
  k_build_pairs<<<EB, 256, 0, stream>>>(mlist, counters, A, kr0, kr1, kc0, kc1);
  k_build_self<<<NB, 256, 0, stream>>>(A);
  k_build_tail<<<EB, 256, 0, stream>>>(rows, cols, alive, A);
  k_pad<<<(PAD + 255) / 256, 256, 0, stream>>>(A);

  // radix sort: A -> B -> A -> B -> A (4 passes x 9 bits)
  unsigned long long* src = A;
  unsigned long long* dst = Bbuf;
  const int shifts[4] = {0, 9, 18, 27};
  for (int p = 0; p < 4; ++p) {
    k_rhist9<<<NT, TH, 0, stream>>>(src, hist, shifts[p]);
    k_scan_reduce<<<SCB, 256, 0, stream>>>(hist, spart, NHIST);
    k_scan_small<<<1, 1024, 0, stream>>>(spart, SCB, nullptr);
    k_scan_apply<<<SCB, 256, 0, stream>>>(hist, spart, NHIST);
    k_rscatter9<<<NT, TH, 0, stream>>>(src, dst, hist, shifts[p]);
    unsigned long long* t = src; src = dst; dst = t;
  }
  // sorted result now in A (src == A)

  // zero dec region (padding slots must be 0,0,0), then compact uniques
  hipMemsetAsync(out + OUT_DR, 0, (size_t)3 * MOUT * 4, stream);
  k_uniq_count<<<NT, TH, 0, stream>>>(src, uPart);
  k_scan_small<<<1, 1024, 0, stream>>>(uPart, NT, nullptr);
  k_final<<<NT, TH, 0, stream>>>(src, uPart, out);
}

// Round 3
// 1360.856 us; speedup vs baseline: 1.9999x; 1.7763x over previous
//
#include <hip/hip_runtime.h>
#include <stdint.h>

// ---------------- problem constants ----------------
#define NNODE   150000
#define EDGES   4000000
#define NSEED   500
#define NSAMP   15000              // int(150000 * 0.1)
#define MOUT    12150000           // 3E + N : decoder output length
#define SENTK   0xFFFFFFFFFFFFFFFFULL
#define SPAN    150000ULL
#define MULTK   51616ULL           // ((2^32 % 150000)^2) % 150000

// sort geometry: chunk = 16384 keys (2 sub-tiles of 8192 through one LDS)
#define STILE   8192
#define CHUNK   16384
#define TH      512
#define NC      744                // chunks; multiple of 8 for XCD swizzle
#define NCX     (NC / 8)           // 93
#define MP      ((size_t)NC * CHUNK)  // 12,189,696
#define PAD     (MP - MOUT)        // 39,696
#define RADIX   512
#define NHIST   (RADIX * NC)       // 380,928
#define SCB     (NHIST / 2048)     // 186 (exact)
#define NTILE   (NC * 2)           // 1488 sub-tiles for uniq/final

// masked-node compaction geometry
#define MTILE   2048
#define MB      ((NNODE + MTILE - 1) / MTILE)   // 74

// out layout (float32): [rows E][cols E][enc E][dec_rows M][dec_cols M][dec_vals M]
#define OUT_DR  12000000
#define OUT_DC  24150000
#define OUT_DV  36300000

// ---------------- threefry2x32 (JAX-exact, 20 rounds) ----------------
__host__ __device__ inline void tf2x32(uint32_t k0, uint32_t k1,
                                       uint32_t x0, uint32_t x1,
                                       uint32_t& o0, uint32_t& o1) {
  uint32_t ks2 = k0 ^ k1 ^ 0x1BD11BDAu;
  x0 += k0; x1 += k1;
#define TFR(d) { x0 += x1; x1 = (x1 << d) | (x1 >> (32 - d)); x1 ^= x0; }
  TFR(13) TFR(15) TFR(26) TFR(6)
  x0 += k1; x1 += ks2 + 1u;
  TFR(17) TFR(29) TFR(16) TFR(24)
  x0 += ks2; x1 += k0 + 2u;
  TFR(13) TFR(15) TFR(26) TFR(6)
  x0 += k0; x1 += k1 + 3u;
  TFR(17) TFR(29) TFR(16) TFR(24)
  x0 += k1; x1 += ks2 + 4u;
  TFR(13) TFR(15) TFR(26) TFR(6)
  x0 += ks2; x1 += k0 + 5u;
#undef TFR
  o0 = x0; o1 = x1;
}

__device__ inline unsigned long long tf_bits64(uint32_t k0, uint32_t k1, uint32_t i) {
  uint32_t o0, o1;
  tf2x32(k0, k1, 0u, i, o0, o1);
  return ((unsigned long long)o0 << 32) | o1;
}

// ---------------- block primitives ----------------
__device__ inline int block_excl_scan_256(int v, int* lds /*>=5 ints*/, int& total) {
  int lane = threadIdx.x & 63, wid = threadIdx.x >> 6;
  int inc = v;
#pragma unroll
  for (int off = 1; off < 64; off <<= 1) {
    int y = __shfl_up(inc, off, 64);
    if (lane >= off) inc += y;
  }
  if (lane == 63) lds[wid] = inc;
  __syncthreads();
  if (threadIdx.x == 0) {
    int a = 0;
#pragma unroll
    for (int w = 0; w < 4; ++w) { int t = lds[w]; lds[w] = a; a += t; }
    lds[4] = a;
  }
  __syncthreads();
  total = lds[4];
  int res = inc - v + lds[wid];
  __syncthreads();
  return res;
}

// exclusive scan of 4 packed ints across 512 threads; aux >= 36 ints.
__device__ inline void scan512_x4(const int v[4], int ex[4], int tot[4], int* aux) {
  int lane = threadIdx.x & 63, wid = threadIdx.x >> 6;
  int inc[4];
#pragma unroll
  for (int j = 0; j < 4; ++j) inc[j] = v[j];
#pragma unroll
  for (int off = 1; off < 64; off <<= 1) {
#pragma unroll
    for (int j = 0; j < 4; ++j) {
      int y = __shfl_up(inc[j], off, 64);
      if (lane >= off) inc[j] += y;
    }
  }
  if (lane == 63) {
#pragma unroll
    for (int j = 0; j < 4; ++j) aux[j * 8 + wid] = inc[j];
  }
  __syncthreads();
  if (threadIdx.x == 0) {
#pragma unroll
    for (int j = 0; j < 4; ++j) {
      int a = 0;
#pragma unroll
      for (int w = 0; w < 8; ++w) { int t = aux[j * 8 + w]; aux[j * 8 + w] = a; a += t; }
      aux[32 + j] = a;
    }
  }
  __syncthreads();
#pragma unroll
  for (int j = 0; j < 4; ++j) {
    ex[j] = inc[j] - v[j] + aux[j * 8 + wid];
    tot[j] = aux[32 + j];
  }
}

__device__ inline int scan512_1(int v, int* aux /*>=9 ints*/) {
  int lane = threadIdx.x & 63, wid = threadIdx.x >> 6;
  int inc = v;
#pragma unroll
  for (int off = 1; off < 64; off <<= 1) {
    int y = __shfl_up(inc, off, 64);
    if (lane >= off) inc += y;
  }
  if (lane == 63) aux[wid] = inc;
  __syncthreads();
  if (threadIdx.x == 0) {
    int a = 0;
#pragma unroll
    for (int w = 0; w < 8; ++w) { int t = aux[w]; aux[w] = a; a += t; }
  }
  __syncthreads();
  return inc - v + aux[wid];
}

// LDS swizzle: rotate within 16-element rows to break 16-stride bank aliasing
__device__ inline int phys16(int p) { return (p & ~15) | ((p + (p >> 4)) & 15); }

// ---------------- BFS / enc kernels (fused) ----------------
__global__ __launch_bounds__(256) void k_seed(const int* seeds, uint8_t* frontier, uint8_t* masked) {
  int i = blockIdx.x * 256 + threadIdx.x;
  if (i < NSEED) { int v = seeds[i]; frontier[v] = 1; masked[v] = 1; }
}

// bfs hop 0 + rows/cols output copy
__global__ __launch_bounds__(256) void k_bfs0(const int* rows, const int* cols,
                                              const uint8_t* frontier, uint8_t* alive, uint8_t* nxt,
                                              float* out) {
  int e = blockIdx.x * 256 + threadIdx.x;
  int r = rows[e], c = cols[e];
  out[e] = (float)r;
  out[EDGES + e] = (float)c;
  if (frontier[r] | frontier[c]) { alive[e] = 0; nxt[r] = 1; nxt[c] = 1; }
}

__global__ __launch_bounds__(256) void k_masked_or(uint8_t* masked, const uint8_t* nxt) {
  int v = blockIdx.x * 256 + threadIdx.x;
  if (v < NNODE) masked[v] |= nxt[v];
}

// bfs hop 1 + degree accumulation on the final alive set
__global__ __launch_bounds__(256) void k_bfs1deg(const int* rows, const int* cols,
                                                 const uint8_t* nxt, uint8_t* alive, float* deg) {
  int e = blockIdx.x * 256 + threadIdx.x;
  int r = rows[e];
  int a = alive[e];
  if (a && (nxt[r] | nxt[cols[e]])) { alive[e] = 0; a = 0; }
  if (a) atomicAdd(&deg[r], 1.0f);
}

__global__ __launch_bounds__(256) void k_sample(uint8_t* masked,
                                                uint32_t a0, uint32_t a1, uint32_t b0, uint32_t b1) {
  int i = blockIdx.x * 256 + threadIdx.x;
  if (i >= NSAMP) return;
  unsigned long long hi = tf_bits64(a0, a1, (uint32_t)i);
  unsigned long long lo = tf_bits64(b0, b1, (uint32_t)i);
  unsigned long long off = ((hi % SPAN) * MULTK + (lo % SPAN)) % SPAN;
  masked[off] = 1;
}

__global__ __launch_bounds__(256) void k_dnorm(const float* deg, float* dnorm) {
  int v = blockIdx.x * 256 + threadIdx.x;
  if (v < NNODE) {
    float x = deg[v] + 1e-12f;
    dnorm[v] = (float)(1.0 / sqrt((double)x));
  }
}

// encoder values + tail hash slots (fused: both read rows/cols/alive)
__global__ __launch_bounds__(256) void k_enctail(const int* rows, const int* cols,
                                                 const uint8_t* alive, const float* dnorm,
                                                 float* out, unsigned long long* A) {
  int e = blockIdx.x * 256 + threadIdx.x;
  int r = rows[e], c = cols[e];
  int a = alive[e];
  out[2 * EDGES + e] = a ? dnorm[r] * dnorm[c] : 0.0f;
  unsigned long long v = (unsigned long long)((long long)r * 150000LL + c);
  A[2 * (size_t)EDGES + NNODE + e] = (a && v) ? v : SENTK;
}

// ---------------- masked-node compaction ----------------
__global__ __launch_bounds__(256) void k_mreduce(const uint8_t* masked, int* mPart) {
  __shared__ int lds[4];
  int base = blockIdx.x * MTILE;
  int s = 0;
  for (int i = threadIdx.x; i < MTILE; i += 256) {
    int idx = base + i;
    if (idx < NNODE) s += masked[idx];
  }
#pragma unroll
  for (int off = 32; off; off >>= 1) s += __shfl_down(s, off, 64);
  if ((threadIdx.x & 63) == 0) lds[threadIdx.x >> 6] = s;
  __syncthreads();
  if (threadIdx.x == 0) mPart[blockIdx.x] = lds[0] + lds[1] + lds[2] + lds[3];
}

__global__ __launch_bounds__(1024) void k_scan_small(int* part, int m, int* totalOut) {
  __shared__ int a[2048];
  int tid = threadIdx.x;
  a[tid] = (tid < m) ? part[tid] : 0;
  a[tid + 1024] = (tid + 1024 < m) ? part[tid + 1024] : 0;
  __syncthreads();
  for (int off = 1; off < 2048; off <<= 1) {
    int v1 = 0, v2;
    if (tid >= off) v1 = a[tid - off];
    v2 = a[tid + 1024 - off];
    __syncthreads();
    if (tid >= off) a[tid] += v1;
    a[tid + 1024] += v2;
    __syncthreads();
  }
  if (tid < m) part[tid] = (tid == 0) ? 0 : a[tid - 1];
  if (tid + 1024 < m) part[tid + 1024] = a[tid + 1023];
  if (tid == 0 && totalOut) *totalOut = a[2047];
}

__global__ __launch_bounds__(256) void k_mscatter(const uint8_t* masked, const int* mPart, int* mlist) {
  __shared__ int lds[8];
  int t0 = blockIdx.x * MTILE + threadIdx.x * 8;
  int c = 0;
#pragma unroll
  for (int k = 0; k < 8; ++k) { int idx = t0 + k; c += (idx < NNODE) ? masked[idx] : 0; }
  int total;
  int ex = block_excl_scan_256(c, lds, total);
  int run = mPart[blockIdx.x] + ex;
#pragma unroll
  for (int k = 0; k < 8; ++k) {
    int idx = t0 + k;
    if (idx < NNODE && masked[idx]) mlist[run++] = idx;
  }
}

// ---------------- hash building (deterministic slots, no atomics) ----------------
__global__ __launch_bounds__(256) void k_build_pairs(const int* mlist, const int* counters,
                                                     unsigned long long* A,
                                                     uint32_t r0, uint32_t r1, uint32_t c0, uint32_t c1) {
  int e = blockIdx.x * 256 + threadIdx.x;
  long long tem = counters[1];
  unsigned long long bits = tf_bits64(r0, r1, (uint32_t)e);
  double u1 = __longlong_as_double((long long)((bits >> 12) | 0x3FF0000000000000ULL)) - 1.0;
  long long i1 = (long long)(u1 * (double)tem); if (i1 > tem - 1) i1 = tem - 1;
  bits = tf_bits64(c0, c1, (uint32_t)e);
  double u2 = __longlong_as_double((long long)((bits >> 12) | 0x3FF0000000000000ULL)) - 1.0;
  long long i2 = (long long)(u2 * (double)tem); if (i2 > tem - 1) i2 = tem - 1;
  long long tr = mlist[i1], tc = mlist[i2];
  unsigned long long v1 = (unsigned long long)(tr * 150000LL + tc);
  unsigned long long v2 = (unsigned long long)(tc * 150000LL + tr);
  A[2 * (size_t)e]     = v1 ? v1 : SENTK;
  A[2 * (size_t)e + 1] = v2 ? v2 : SENTK;
}

__global__ __launch_bounds__(256) void k_build_self(unsigned long long* A) {
  int v = blockIdx.x * 256 + threadIdx.x;
  if (v >= NNODE) return;
  A[2 * (size_t)EDGES + v] = v ? (unsigned long long)v * 150001ULL : SENTK;
}

__global__ __launch_bounds__(256) void k_pad(unsigned long long* A) {
  int i = blockIdx.x * 256 + threadIdx.x;
  if (i < (int)PAD) A[(size_t)MOUT + i] = SENTK;
}

// ---------------- LSD radix sort: 4 passes x 9 bits, 16384-key chunks ----------------
__global__ __launch_bounds__(TH) void k_rhist2(const unsigned long long* __restrict__ src,
                                               int* __restrict__ hist, int shift) {
  __shared__ int h8[RADIX * 4];
  int tid = threadIdx.x;
  for (int i = tid; i < RADIX * 4; i += TH) h8[i] = 0;
  __syncthreads();
  const ulonglong2* s2 = (const ulonglong2*)(src + (size_t)blockIdx.x * CHUNK);
  int rep = tid & 3, scnt = 0;
#pragma unroll
  for (int r = 0; r < 16; ++r) {
    ulonglong2 v = s2[tid + r * TH];
    int d0 = (int)((v.x >> shift) & (RADIX - 1));
    int d1 = (int)((v.y >> shift) & (RADIX - 1));
    if (d0 == RADIX - 1) scnt++; else atomicAdd(&h8[d0 * 4 + rep], 1);
    if (d1 == RADIX - 1) scnt++; else atomicAdd(&h8[d1 * 4 + rep], 1);
  }
  if (scnt) atomicAdd(&h8[(RADIX - 1) * 4 + rep], scnt);
  __syncthreads();
  int4 hv = *(const int4*)&h8[tid * 4];
  hist[(size_t)tid * NC + blockIdx.x] = hv.x + hv.y + hv.z + hv.w;
}

__global__ __launch_bounds__(256) void k_scan_reduce(const int* g, int* part, int n) {
  __shared__ int lds[4];
  int base = blockIdx.x * 2048;
  int s = 0;
  for (int i = threadIdx.x; i < 2048; i += 256) {
    int idx = base + i;
    if (idx < n) s += g[idx];
  }
#pragma unroll
  for (int off = 32; off; off >>= 1) s += __shfl_down(s, off, 64);
  if ((threadIdx.x & 63) == 0) lds[threadIdx.x >> 6] = s;
  __syncthreads();
  if (threadIdx.x == 0) part[blockIdx.x] = lds[0] + lds[1] + lds[2] + lds[3];
}

__global__ __launch_bounds__(256) void k_scan_apply(int* g, const int* part, int n) {
  __shared__ int lds[8];
  int t0 = blockIdx.x * 2048 + threadIdx.x * 8;
  int x[8];
#pragma unroll
  for (int k = 0; k < 8; ++k) { int idx = t0 + k; x[k] = (idx < n) ? g[idx] : 0; }
  int s = 0;
#pragma unroll
  for (int k = 0; k < 8; ++k) { int t = x[k]; x[k] = s; s += t; }
  int total;
  int ex = block_excl_scan_256(s, lds, total);
  int add = part[blockIdx.x] + ex;
#pragma unroll
  for (int k = 0; k < 8; ++k) { int idx = t0 + k; if (idx < n) g[idx] = x[k] + add; }
}

__global__ __launch_bounds__(TH) void k_rscatter2(const unsigned long long* __restrict__ src,
                                                  unsigned long long* __restrict__ dst,
                                                  const int* __restrict__ hist, int shift) {
  __shared__ uint32_t klo[STILE], khi[STILE];
  __shared__ int h8[RADIX * 4];
  __shared__ int dstart[RADIX], hcnt[RADIX], gbase[RADIX];
  __shared__ int aux[40];
  int tid = threadIdx.x;
  // XCD-contiguous chunk swizzle: adjacent chunks on the same XCD, temporally adjacent
  int chunk = (blockIdx.x & 7) * NCX + (blockIdx.x >> 3);
  size_t cbase = (size_t)chunk * CHUNK;
  // per-(digit,chunk) global base offsets (strided gather, once per block)
  gbase[tid] = hist[(size_t)tid * NC + chunk];
  for (int i = tid; i < RADIX * 4; i += TH) h8[i] = 0;
  __syncthreads();
  int rep = tid & 3;
  for (int sub = 0; sub < 2; ++sub) {
    size_t sbase = cbase + (size_t)sub * STILE;
    // ---- load sub-tile to LDS + count 9-bit digits ----
    const ulonglong2* s2 = (const ulonglong2*)(src + sbase);
    int scnt = 0;
#pragma unroll
    for (int r = 0; r < 8; ++r) {
      ulonglong2 v = s2[tid + r * TH];
      int i = 2 * (tid + r * TH);
      int p0 = phys16(i), p1 = phys16(i + 1);
      klo[p0] = (uint32_t)v.x; khi[p0] = (uint32_t)(v.x >> 32);
      klo[p1] = (uint32_t)v.y; khi[p1] = (uint32_t)(v.y >> 32);
      int d0 = (int)((v.x >> shift) & (RADIX - 1));
      int d1 = (int)((v.y >> shift) & (RADIX - 1));
      if (d0 == RADIX - 1) scnt++; else atomicAdd(&h8[d0 * 4 + rep], 1);
      if (d1 == RADIX - 1) scnt++; else atomicAdd(&h8[d1 * 4 + rep], 1);
    }
    if (scnt) atomicAdd(&h8[(RADIX - 1) * 4 + rep], scnt);
    __syncthreads();
    // ---- per-digit tile starts ----
    int4 hv = *(const int4*)&h8[tid * 4];
    int h = hv.x + hv.y + hv.z + hv.w;
    hcnt[tid] = h;
    int ex0 = scan512_1(h, aux);
    dstart[tid] = ex0;
    __syncthreads();
    // ---- 3 x 3-bit stable split rounds -> sub-tile sorted by 9-bit digit ----
    int t0 = tid * 16;
    for (int rr = 0; rr < 3; ++rr) {
      int sh = shift + 3 * rr;
      unsigned long long key[16];
      int c[8] = {0, 0, 0, 0, 0, 0, 0, 0};
#pragma unroll
      for (int k = 0; k < 16; ++k) {
        int p = phys16(t0 + k);
        key[k] = ((unsigned long long)khi[p] << 32) | klo[p];
        int d = (int)((key[k] >> sh) & 7);
#pragma unroll
        for (int q = 0; q < 8; ++q) c[q] += (d == q);
      }
      int v4[4], ex[4], tot[4];
#pragma unroll
      for (int j = 0; j < 4; ++j) v4[j] = c[2 * j] | (c[2 * j + 1] << 16);
      scan512_x4(v4, ex, tot, aux);
      int start[8];
      {
        int a = 0;
#pragma unroll
        for (int j = 0; j < 4; ++j) {
          int tlo = tot[j] & 0xffff, thi = tot[j] >> 16;
          int elo = ex[j] & 0xffff,  ehi = ex[j] >> 16;
          start[2 * j]     = a + elo; a += tlo;
          start[2 * j + 1] = a + ehi; a += thi;
        }
      }
#pragma unroll
      for (int k = 0; k < 16; ++k) {
        int d = (int)((key[k] >> sh) & 7);
        int pos = 0;
#pragma unroll
        for (int q = 0; q < 8; ++q) { if (d == q) pos = start[q]; }
#pragma unroll
        for (int q = 0; q < 8; ++q) start[q] += (d == q);
        int p = phys16(pos);
        klo[p] = (uint32_t)key[k]; khi[p] = (uint32_t)(key[k] >> 32);
      }
      __syncthreads();
    }
    // ---- direct-addressed scatter: read back in sorted order ----
#pragma unroll
    for (int r = 0; r < 16; ++r) {
      int i = tid + r * TH;
      int p = phys16(i);
      unsigned long long k1 = ((unsigned long long)khi[p] << 32) | klo[p];
      int d = (int)((k1 >> shift) & (RADIX - 1));
      dst[(size_t)(gbase[d] + (i - dstart[d]))] = k1;
    }
    __syncthreads();   // all gbase/dstart reads + LDS reads done
    if (sub == 0) {
      gbase[tid] += hcnt[tid];                        // sub1 segments follow sub0's
      for (int i = tid; i < RADIX * 4; i += TH) h8[i] = 0;
      __syncthreads();
    }
  }
}

// ---------------- unique + final decoder write ----------------
__global__ __launch_bounds__(TH) void k_uniq_count(const unsigned long long* A, int* uPart) {
  __shared__ int lds[8];
  size_t base = (size_t)blockIdx.x * STILE + (size_t)threadIdx.x * 16;
  unsigned long long prev = (base == 0) ? 0ULL : A[base - 1];
  int c = 0;
#pragma unroll
  for (int k = 0; k < 16; ++k) {
    unsigned long long v = A[base + k];
    c += (v != SENTK && v != prev) ? 1 : 0;
    prev = v;
  }
#pragma unroll
  for (int off = 32; off; off >>= 1) c += __shfl_down(c, off, 64);
  if ((threadIdx.x & 63) == 0) lds[threadIdx.x >> 6] = c;
  __syncthreads();
  if (threadIdx.x == 0) {
    int s = 0;
#pragma unroll
    for (int w = 0; w < 8; ++w) s += lds[w];
    uPart[blockIdx.x] = s;
  }
}

__global__ __launch_bounds__(TH) void k_final(const unsigned long long* A, const int* uPart, float* out) {
  __shared__ int aux[9];
  size_t base = (size_t)blockIdx.x * STILE + (size_t)threadIdx.x * 16;
  unsigned long long v[16];
  int f[16], c = 0;
  unsigned long long prev = (base == 0) ? 0ULL : A[base - 1];
#pragma unroll
  for (int k = 0; k < 16; ++k) {
    v[k] = A[base + k];
    f[k] = (v[k] != SENTK && v[k] != prev) ? 1 : 0;
    c += f[k];
    prev = v[k];
  }
  int ex = scan512_1(c, aux);
  int j = 1 + uPart[blockIdx.x] + ex;   // +1: slot 0 is the always-present hash 0
#pragma unroll
  for (int k = 0; k < 16; ++k) {
    if (f[k]) {
      unsigned long long val = v[k];
      long long q = (long long)((double)val * (1.0 / 150000.0));
      long long r = (long long)val - q * 150000LL;
      if (r < 0) { q--; r += 150000LL; }
      else if (r >= 150000LL) { q++; r -= 150000LL; }
      out[OUT_DR + j] = (float)q;
      out[OUT_DC + j] = (float)r;
      out[OUT_DV + j] = 1.0f;
      j++;
    }
  }
  if (blockIdx.x == 0 && threadIdx.x == 0) out[OUT_DV] = 1.0f;  // dec_vals[0]=1
}

// ---------------- host launcher ----------------
extern "C" void kernel_launch(void* const* d_in, const int* in_sizes, int n_in,
                              void* d_out, int out_size, void* d_ws, size_t ws_size,
                              hipStream_t stream) {
  const int* rows = (const int*)d_in[1];   // d_in[0]=adj_vals (unused by reference outputs)
  const int* cols = (const int*)d_in[2];
  const int* seeds = (const int*)d_in[3];
  float* out = (float*)d_out;

  // workspace layout
  char* ws = (char*)d_ws;
  size_t off = 0;
  auto alloc = [&](size_t bytes) -> char* {
    char* p = ws + off;
    off += (bytes + 255) & ~(size_t)255;
    return p;
  };
  unsigned long long* A = (unsigned long long*)alloc(MP * 8);
  uint8_t* alive = (uint8_t*)alloc(EDGES);
  char* zbase = ws + off;                       // ---- zeroed zone ----
  uint8_t* frontier = (uint8_t*)alloc(NNODE);
  uint8_t* nextf = (uint8_t*)alloc(NNODE);
  uint8_t* masked = (uint8_t*)alloc(NNODE);
  float* deg = (float*)alloc((size_t)NNODE * 4);
  int* counters = (int*)alloc(256 * 4);         // [1]=tem_num
  size_t zsize = (size_t)((ws + off) - zbase);  // ---- end zeroed zone ----
  float* dnorm = (float*)alloc((size_t)NNODE * 4);
  int* mlist = (int*)alloc((size_t)NNODE * 4);
  int* hist = (int*)alloc((size_t)NHIST * 4);
  int* spart = (int*)alloc(2048 * 4);
  int* uPart = (int*)alloc(2048 * 4);
  int* mPart = (int*)alloc(256 * 4);

  // radix ping-pong buffer B lives in the (later-overwritten) dec region of d_out
  unsigned long long* Bbuf = (unsigned long long*)(out + OUT_DR);

  // JAX key derivation (threefry_partitionable semantics)
  uint32_t ks0, ks1, kr0, kr1, kc0, kc1, s10, s11, s20, s21;
  tf2x32(0u, 42u, 0u, 0u, ks0, ks1);
  tf2x32(0u, 42u, 0u, 1u, kr0, kr1);
  tf2x32(0u, 42u, 0u, 2u, kc0, kc1);
  tf2x32(ks0, ks1, 0u, 0u, s10, s11);
  tf2x32(ks0, ks1, 0u, 1u, s20, s21);

  hipMemsetAsync(zbase, 0, zsize, stream);
  hipMemsetAsync(alive, 1, EDGES, stream);

  const int EB = EDGES / 256;                // 15625
  const int NB = (NNODE + 255) / 256;        // 586

  k_seed<<<2, 256, 0, stream>>>(seeds, frontier, masked);
  k_bfs0<<<EB, 256, 0, stream>>>(rows, cols, frontier, alive, nextf, out);
  k_masked_or<<<NB, 256, 0, stream>>>(masked, nextf);
  k_bfs1deg<<<EB, 256, 0, stream>>>(rows, cols, nextf, alive, deg);
  k_sample<<<(NSAMP + 255) / 256, 256, 0, stream>>>(masked, s10, s11, s20, s21);
  k_dnorm<<<NB, 256, 0, stream>>>(deg, dnorm);
  k_enctail<<<EB, 256, 0, stream>>>(rows, cols, alive, dnorm, out, A);

  // masked node list (ascending) + tem_num
  k_mreduce<<<MB, 256, 0, stream>>>(masked, mPart);
  k_scan_small<<<1, 1024, 0, stream>>>(mPart, MB, counters + 1);
  k_mscatter<<<MB, 256, 0, stream>>>(masked, mPart, mlist);

  // hash multiset at deterministic slots (0 / dead -> SENTK), into A
  k_build_pairs<<<EB, 256, 0, stream>>>(mlist, counters, A, kr0, kr1, kc0, kc1);
  k_build_self<<<NB, 256, 0, stream>>>(A);
  k_pad<<<((int)PAD + 255) / 256, 256, 0, stream>>>(A);

  // radix sort: A -> B -> A -> B -> A (4 passes x 9 bits over 16384-key chunks)
  unsigned long long* src = A;
  unsigned long long* dst = Bbuf;
  const int shifts[4] = {0, 9, 18, 27};
  for (int p = 0; p < 4; ++p) {
    k_rhist2<<<NC, TH, 0, stream>>>(src, hist, shifts[p]);
    k_scan_reduce<<<SCB, 256, 0, stream>>>(hist, spart, NHIST);
    k_scan_small<<<1, 1024, 0, stream>>>(spart, SCB, nullptr);
    k_scan_apply<<<SCB, 256, 0, stream>>>(hist, spart, NHIST);
    k_rscatter2<<<NC, TH, 0, stream>>>(src, dst, hist, shifts[p]);
    unsigned long long* t = src; src = dst; dst = t;
  }
  // sorted result now in A (src == A)

  // zero dec region (padding slots must be 0,0,0), then compact uniques
  hipMemsetAsync(out + OUT_DR, 0, (size_t)3 * MOUT * 4, stream);
  k_uniq_count<<<NTILE, TH, 0, stream>>>(src, uPart);
  k_scan_small<<<1, 1024, 0, stream>>>(uPart, NTILE, nullptr);
  k_final<<<NTILE, TH, 0, stream>>>(src, uPart, out);
}

// Round 4
// 1359.265 us; speedup vs baseline: 2.0022x; 1.0012x over previous
//
#include <hip/hip_runtime.h>
#include <stdint.h>

// ---------------- problem constants ----------------
#define NNODE   150000
#define EDGES   4000000
#define NSEED   500
#define NSAMP   15000              // int(150000 * 0.1)
#define MOUT    12150000           // 3E + N : decoder output length
#define SENTK   0xFFFFFFFFFFFFFFFFULL
#define SPAN    150000ULL
#define MULTK   51616ULL           // ((2^32 % 150000)^2) % 150000
#define FIXED   8150000            // pairs (8M) + self loops (150k) fixed slots

// sort geometry: chunk = 16384 keys (2 sub-tiles of 8192 through one LDS)
#define STILE   8192
#define CHUNK   16384
#define TH      512
#define NC      744                // max chunks; multiple of 8 for XCD swizzle
#define NCX     (NC / 8)           // 93
#define MP      ((size_t)NC * CHUNK)
#define RADIX   512
#define NHIST   (RADIX * NC)       // 380,928
#define SCB     (NHIST / 2048)     // 186 (exact)
#define NTILE   (NC * 2)           // 1488 max sub-tiles for uniq/final

// masked-node compaction geometry
#define MTILE   2048
#define MB      ((NNODE + MTILE - 1) / MTILE)   // 74

// out layout (float32): [rows E][cols E][enc E][dec_rows M][dec_cols M][dec_vals M]
#define OUT_DR  12000000
#define OUT_DC  24150000
#define OUT_DV  36300000

// ---------------- threefry2x32 (JAX-exact, 20 rounds) ----------------
__host__ __device__ inline void tf2x32(uint32_t k0, uint32_t k1,
                                       uint32_t x0, uint32_t x1,
                                       uint32_t& o0, uint32_t& o1) {
  uint32_t ks2 = k0 ^ k1 ^ 0x1BD11BDAu;
  x0 += k0; x1 += k1;
#define TFR(d) { x0 += x1; x1 = (x1 << d) | (x1 >> (32 - d)); x1 ^= x0; }
  TFR(13) TFR(15) TFR(26) TFR(6)
  x0 += k1; x1 += ks2 + 1u;
  TFR(17) TFR(29) TFR(16) TFR(24)
  x0 += ks2; x1 += k0 + 2u;
  TFR(13) TFR(15) TFR(26) TFR(6)
  x0 += k0; x1 += k1 + 3u;
  TFR(17) TFR(29) TFR(16) TFR(24)
  x0 += k1; x1 += ks2 + 4u;
  TFR(13) TFR(15) TFR(26) TFR(6)
  x0 += ks2; x1 += k0 + 5u;
#undef TFR
  o0 = x0; o1 = x1;
}

__device__ inline unsigned long long tf_bits64(uint32_t k0, uint32_t k1, uint32_t i) {
  uint32_t o0, o1;
  tf2x32(k0, k1, 0u, i, o0, o1);
  return ((unsigned long long)o0 << 32) | o1;
}

// active chunk count (device, from tail append counter)
__device__ inline int activeChunks(const int* counters) {
  int m2 = FIXED + counters[2];
  return (m2 + CHUNK - 1) / CHUNK;
}

// ---------------- block primitives ----------------
__device__ inline int block_excl_scan_256(int v, int* lds /*>=5 ints*/, int& total) {
  int lane = threadIdx.x & 63, wid = threadIdx.x >> 6;
  int inc = v;
#pragma unroll
  for (int off = 1; off < 64; off <<= 1) {
    int y = __shfl_up(inc, off, 64);
    if (lane >= off) inc += y;
  }
  if (lane == 63) lds[wid] = inc;
  __syncthreads();
  if (threadIdx.x == 0) {
    int a = 0;
#pragma unroll
    for (int w = 0; w < 4; ++w) { int t = lds[w]; lds[w] = a; a += t; }
    lds[4] = a;
  }
  __syncthreads();
  total = lds[4];
  int res = inc - v + lds[wid];
  __syncthreads();
  return res;
}

// exclusive scan of 4 packed ints across 512 threads; aux >= 36 ints.
__device__ inline void scan512_x4(const int v[4], int ex[4], int tot[4], int* aux) {
  int lane = threadIdx.x & 63, wid = threadIdx.x >> 6;
  int inc[4];
#pragma unroll
  for (int j = 0; j < 4; ++j) inc[j] = v[j];
#pragma unroll
  for (int off = 1; off < 64; off <<= 1) {
#pragma unroll
    for (int j = 0; j < 4; ++j) {
      int y = __shfl_up(inc[j], off, 64);
      if (lane >= off) inc[j] += y;
    }
  }
  if (lane == 63) {
#pragma unroll
    for (int j = 0; j < 4; ++j) aux[j * 8 + wid] = inc[j];
  }
  __syncthreads();
  if (threadIdx.x == 0) {
#pragma unroll
    for (int j = 0; j < 4; ++j) {
      int a = 0;
#pragma unroll
      for (int w = 0; w < 8; ++w) { int t = aux[j * 8 + w]; aux[j * 8 + w] = a; a += t; }
      aux[32 + j] = a;
    }
  }
  __syncthreads();
#pragma unroll
  for (int j = 0; j < 4; ++j) {
    ex[j] = inc[j] - v[j] + aux[j * 8 + wid];
    tot[j] = aux[32 + j];
  }
}

__device__ inline int scan512_1(int v, int* aux /*>=9 ints*/) {
  int lane = threadIdx.x & 63, wid = threadIdx.x >> 6;
  int inc = v;
#pragma unroll
  for (int off = 1; off < 64; off <<= 1) {
    int y = __shfl_up(inc, off, 64);
    if (lane >= off) inc += y;
  }
  if (lane == 63) aux[wid] = inc;
  __syncthreads();
  if (threadIdx.x == 0) {
    int a = 0;
#pragma unroll
    for (int w = 0; w < 8; ++w) { int t = aux[w]; aux[w] = a; a += t; }
  }
  __syncthreads();
  return inc - v + aux[wid];
}

// LDS swizzle: rotate within 16-element rows to break 16-stride bank aliasing
__device__ inline int phys16(int p) { return (p & ~15) | ((p + (p >> 4)) & 15); }

// ---------------- BFS / enc kernels (fused) ----------------
__global__ __launch_bounds__(256) void k_seed(const int* seeds, uint8_t* frontier, uint8_t* masked) {
  int i = blockIdx.x * 256 + threadIdx.x;
  if (i < NSEED) { int v = seeds[i]; frontier[v] = 1; masked[v] = 1; }
}

// bfs hop 0 + rows/cols output copy
__global__ __launch_bounds__(256) void k_bfs0(const int* rows, const int* cols,
                                              const uint8_t* frontier, uint8_t* alive, uint8_t* nxt,
                                              float* out) {
  int e = blockIdx.x * 256 + threadIdx.x;
  int r = rows[e], c = cols[e];
  out[e] = (float)r;
  out[EDGES + e] = (float)c;
  if (frontier[r] | frontier[c]) { alive[e] = 0; nxt[r] = 1; nxt[c] = 1; }
}

__global__ __launch_bounds__(256) void k_masked_or(uint8_t* masked, const uint8_t* nxt) {
  int v = blockIdx.x * 256 + threadIdx.x;
  if (v < NNODE) masked[v] |= nxt[v];
}

// bfs hop 1 + degree accumulation on the final alive set
__global__ __launch_bounds__(256) void k_bfs1deg(const int* rows, const int* cols,
                                                 const uint8_t* nxt, uint8_t* alive, float* deg) {
  int e = blockIdx.x * 256 + threadIdx.x;
  int r = rows[e];
  int a = alive[e];
  if (a && (nxt[r] | nxt[cols[e]])) { alive[e] = 0; a = 0; }
  if (a) atomicAdd(&deg[r], 1.0f);
}

__global__ __launch_bounds__(256) void k_sample(uint8_t* masked,
                                                uint32_t a0, uint32_t a1, uint32_t b0, uint32_t b1) {
  int i = blockIdx.x * 256 + threadIdx.x;
  if (i >= NSAMP) return;
  unsigned long long hi = tf_bits64(a0, a1, (uint32_t)i);
  unsigned long long lo = tf_bits64(b0, b1, (uint32_t)i);
  unsigned long long off = ((hi % SPAN) * MULTK + (lo % SPAN)) % SPAN;
  masked[off] = 1;
}

__global__ __launch_bounds__(256) void k_dnorm(const float* deg, float* dnorm) {
  int v = blockIdx.x * 256 + threadIdx.x;
  if (v < NNODE) {
    float x = deg[v] + 1e-12f;
    dnorm[v] = (float)(1.0 / sqrt((double)x));
  }
}

// encoder values + compacted tail-hash append (block-aggregated atomic)
__global__ __launch_bounds__(256) void k_enctail(const int* rows, const int* cols,
                                                 const uint8_t* alive, const float* dnorm,
                                                 float* out, unsigned long long* A, int* counters) {
  __shared__ int lds[8];
  __shared__ unsigned long long stage[256];
  __shared__ int sbase;
  int e = blockIdx.x * 256 + threadIdx.x;
  int r = rows[e], c = cols[e];
  int a = alive[e];
  out[2 * EDGES + e] = a ? dnorm[r] * dnorm[c] : 0.0f;
  unsigned long long v = (unsigned long long)((long long)r * 150000LL + c);
  int emit = (a && v) ? 1 : 0;
  int total;
  int ex = block_excl_scan_256(emit, lds, total);
  if (emit) stage[ex] = v;
  if (threadIdx.x == 0 && total) sbase = atomicAdd(&counters[2], total);
  __syncthreads();
  if (threadIdx.x < total) A[(size_t)FIXED + sbase + threadIdx.x] = stage[threadIdx.x];
}

// ---------------- masked-node compaction ----------------
__global__ __launch_bounds__(256) void k_mreduce(const uint8_t* masked, int* mPart) {
  __shared__ int lds[4];
  int base = blockIdx.x * MTILE;
  int s = 0;
  for (int i = threadIdx.x; i < MTILE; i += 256) {
    int idx = base + i;
    if (idx < NNODE) s += masked[idx];
  }
#pragma unroll
  for (int off = 32; off; off >>= 1) s += __shfl_down(s, off, 64);
  if ((threadIdx.x & 63) == 0) lds[threadIdx.x >> 6] = s;
  __syncthreads();
  if (threadIdx.x == 0) mPart[blockIdx.x] = lds[0] + lds[1] + lds[2] + lds[3];
}

__global__ __launch_bounds__(1024) void k_scan_small(int* part, int m, int* totalOut) {
  __shared__ int a[2048];
  int tid = threadIdx.x;
  a[tid] = (tid < m) ? part[tid] : 0;
  a[tid + 1024] = (tid + 1024 < m) ? part[tid + 1024] : 0;
  __syncthreads();
  for (int off = 1; off < 2048; off <<= 1) {
    int v1 = 0, v2;
    if (tid >= off) v1 = a[tid - off];
    v2 = a[tid + 1024 - off];
    __syncthreads();
    if (tid >= off) a[tid] += v1;
    a[tid + 1024] += v2;
    __syncthreads();
  }
  if (tid < m) part[tid] = (tid == 0) ? 0 : a[tid - 1];
  if (tid + 1024 < m) part[tid + 1024] = a[tid + 1023];
  if (tid == 0 && totalOut) *totalOut = a[2047];
}

__global__ __launch_bounds__(256) void k_mscatter(const uint8_t* masked, const int* mPart, int* mlist) {
  __shared__ int lds[8];
  int t0 = blockIdx.x * MTILE + threadIdx.x * 8;
  int c = 0;
#pragma unroll
  for (int k = 0; k < 8; ++k) { int idx = t0 + k; c += (idx < NNODE) ? masked[idx] : 0; }
  int total;
  int ex = block_excl_scan_256(c, lds, total);
  int run = mPart[blockIdx.x] + ex;
#pragma unroll
  for (int k = 0; k < 8; ++k) {
    int idx = t0 + k;
    if (idx < NNODE && masked[idx]) mlist[run++] = idx;
  }
}

// ---------------- hash building ----------------
__global__ __launch_bounds__(256) void k_build_pairs(const int* mlist, const int* counters,
                                                     unsigned long long* A,
                                                     uint32_t r0, uint32_t r1, uint32_t c0, uint32_t c1) {
  int e = blockIdx.x * 256 + threadIdx.x;
  long long tem = counters[1];
  unsigned long long bits = tf_bits64(r0, r1, (uint32_t)e);
  double u1 = __longlong_as_double((long long)((bits >> 12) | 0x3FF0000000000000ULL)) - 1.0;
  long long i1 = (long long)(u1 * (double)tem); if (i1 > tem - 1) i1 = tem - 1;
  bits = tf_bits64(c0, c1, (uint32_t)e);
  double u2 = __longlong_as_double((long long)((bits >> 12) | 0x3FF0000000000000ULL)) - 1.0;
  long long i2 = (long long)(u2 * (double)tem); if (i2 > tem - 1) i2 = tem - 1;
  long long tr = mlist[i1], tc = mlist[i2];
  unsigned long long v1 = (unsigned long long)(tr * 150000LL + tc);
  unsigned long long v2 = (unsigned long long)(tc * 150000LL + tr);
  A[2 * (size_t)e]     = v1 ? v1 : SENTK;
  A[2 * (size_t)e + 1] = v2 ? v2 : SENTK;
}

__global__ __launch_bounds__(256) void k_build_self(unsigned long long* A) {
  int v = blockIdx.x * 256 + threadIdx.x;
  if (v >= NNODE) return;
  A[2 * (size_t)EDGES + v] = v ? (unsigned long long)v * 150001ULL : SENTK;
}

// pad [m2, AC*CHUNK) with sentinels (< CHUNK elements)
__global__ __launch_bounds__(256) void k_pad(unsigned long long* A, const int* counters) {
  int m2 = FIXED + counters[2];
  int ac = (m2 + CHUNK - 1) / CHUNK;
  size_t idx = (size_t)m2 + blockIdx.x * 256 + threadIdx.x;
  if (idx < (size_t)ac * CHUNK) A[idx] = SENTK;
}

// ---------------- LSD radix sort: 4 passes x 9 bits, 16384-key chunks ----------------
__global__ __launch_bounds__(TH) void k_rhist2(const unsigned long long* __restrict__ src,
                                               int* __restrict__ hist, int shift,
                                               const int* counters) {
  __shared__ int h8[RADIX * 4];
  int tid = threadIdx.x;
  int ac = activeChunks(counters);
  if ((int)blockIdx.x >= ac) { hist[(size_t)tid * NC + blockIdx.x] = 0; return; }
  for (int i = tid; i < RADIX * 4; i += TH) h8[i] = 0;
  __syncthreads();
  const ulonglong2* s2 = (const ulonglong2*)(src + (size_t)blockIdx.x * CHUNK);
  int rep = tid & 3, scnt = 0;
#pragma unroll
  for (int r = 0; r < 16; ++r) {
    ulonglong2 v = s2[tid + r * TH];
    int d0 = (int)((v.x >> shift) & (RADIX - 1));
    int d1 = (int)((v.y >> shift) & (RADIX - 1));
    if (d0 == RADIX - 1) scnt++; else atomicAdd(&h8[d0 * 4 + rep], 1);
    if (d1 == RADIX - 1) scnt++; else atomicAdd(&h8[d1 * 4 + rep], 1);
  }
  if (scnt) atomicAdd(&h8[(RADIX - 1) * 4 + rep], scnt);
  __syncthreads();
  int4 hv = *(const int4*)&h8[tid * 4];
  hist[(size_t)tid * NC + blockIdx.x] = hv.x + hv.y + hv.z + hv.w;
}

__global__ __launch_bounds__(256) void k_scan_reduce(const int* g, int* part, int n) {
  __shared__ int lds[4];
  int base = blockIdx.x * 2048;
  int s = 0;
  for (int i = threadIdx.x; i < 2048; i += 256) {
    int idx = base + i;
    if (idx < n) s += g[idx];
  }
#pragma unroll
  for (int off = 32; off; off >>= 1) s += __shfl_down(s, off, 64);
  if ((threadIdx.x & 63) == 0) lds[threadIdx.x >> 6] = s;
  __syncthreads();
  if (threadIdx.x == 0) part[blockIdx.x] = lds[0] + lds[1] + lds[2] + lds[3];
}

__global__ __launch_bounds__(256) void k_scan_apply(int* g, const int* part, int n) {
  __shared__ int lds[8];
  int t0 = blockIdx.x * 2048 + threadIdx.x * 8;
  int x[8];
#pragma unroll
  for (int k = 0; k < 8; ++k) { int idx = t0 + k; x[k] = (idx < n) ? g[idx] : 0; }
  int s = 0;
#pragma unroll
  for (int k = 0; k < 8; ++k) { int t = x[k]; x[k] = s; s += t; }
  int total;
  int ex = block_excl_scan_256(s, lds, total);
  int add = part[blockIdx.x] + ex;
#pragma unroll
  for (int k = 0; k < 8; ++k) { int idx = t0 + k; if (idx < n) g[idx] = x[k] + add; }
}

__global__ __launch_bounds__(TH) void k_rscatter2(const unsigned long long* __restrict__ src,
                                                  unsigned long long* __restrict__ dst,
                                                  const int* __restrict__ hist, int shift,
                                                  const int* counters) {
  __shared__ uint32_t klo[STILE], khi[STILE];
  __shared__ int h8[RADIX * 4];
  __shared__ int dstart[RADIX], hcnt[RADIX], gbase[RADIX];
  __shared__ int aux[40];
  int tid = threadIdx.x;
  // XCD-contiguous chunk swizzle: adjacent chunks on the same XCD, temporally adjacent
  int chunk = (blockIdx.x & 7) * NCX + (blockIdx.x >> 3);
  int ac = activeChunks(counters);
  if (chunk >= ac) return;
  size_t cbase = (size_t)chunk * CHUNK;
  gbase[tid] = hist[(size_t)tid * NC + chunk];
  for (int i = tid; i < RADIX * 4; i += TH) h8[i] = 0;
  __syncthreads();
  int rep = tid & 3;
  for (int sub = 0; sub < 2; ++sub) {
    size_t sbase = cbase + (size_t)sub * STILE;
    const ulonglong2* s2 = (const ulonglong2*)(src + sbase);
    int scnt = 0;
#pragma unroll
    for (int r = 0; r < 8; ++r) {
      ulonglong2 v = s2[tid + r * TH];
      int i = 2 * (tid + r * TH);
      int p0 = phys16(i), p1 = phys16(i + 1);
      klo[p0] = (uint32_t)v.x; khi[p0] = (uint32_t)(v.x >> 32);
      klo[p1] = (uint32_t)v.y; khi[p1] = (uint32_t)(v.y >> 32);
      int d0 = (int)((v.x >> shift) & (RADIX - 1));
      int d1 = (int)((v.y >> shift) & (RADIX - 1));
      if (d0 == RADIX - 1) scnt++; else atomicAdd(&h8[d0 * 4 + rep], 1);
      if (d1 == RADIX - 1) scnt++; else atomicAdd(&h8[d1 * 4 + rep], 1);
    }
    if (scnt) atomicAdd(&h8[(RADIX - 1) * 4 + rep], scnt);
    __syncthreads();
    int4 hv = *(const int4*)&h8[tid * 4];
    int h = hv.x + hv.y + hv.z + hv.w;
    hcnt[tid] = h;
    int ex0 = scan512_1(h, aux);
    dstart[tid] = ex0;
    __syncthreads();
    // 3 x 3-bit stable split rounds -> sub-tile sorted by 9-bit digit
    int t0 = tid * 16;
    for (int rr = 0; rr < 3; ++rr) {
      int sh = shift + 3 * rr;
      unsigned long long key[16];
      int c[8] = {0, 0, 0, 0, 0, 0, 0, 0};
#pragma unroll
      for (int k = 0; k < 16; ++k) {
        int p = phys16(t0 + k);
        key[k] = ((unsigned long long)khi[p] << 32) | klo[p];
        int d = (int)((key[k] >> sh) & 7);
#pragma unroll
        for (int q = 0; q < 8; ++q) c[q] += (d == q);
      }
      int v4[4], ex[4], tot[4];
#pragma unroll
      for (int j = 0; j < 4; ++j) v4[j] = c[2 * j] | (c[2 * j + 1] << 16);
      scan512_x4(v4, ex, tot, aux);
      int start[8];
      {
        int a = 0;
#pragma unroll
        for (int j = 0; j < 4; ++j) {
          int tlo = tot[j] & 0xffff, thi = tot[j] >> 16;
          int elo = ex[j] & 0xffff,  ehi = ex[j] >> 16;
          start[2 * j]     = a + elo; a += tlo;
          start[2 * j + 1] = a + ehi; a += thi;
        }
      }
#pragma unroll
      for (int k = 0; k < 16; ++k) {
        int d = (int)((key[k] >> sh) & 7);
        int pos = 0;
#pragma unroll
        for (int q = 0; q < 8; ++q) { if (d == q) pos = start[q]; }
#pragma unroll
        for (int q = 0; q < 8; ++q) start[q] += (d == q);
        int p = phys16(pos);
        klo[p] = (uint32_t)key[k]; khi[p] = (uint32_t)(key[k] >> 32);
      }
      __syncthreads();
    }
    // direct-addressed scatter: read back in sorted order
#pragma unroll
    for (int r = 0; r < 16; ++r) {
      int i = tid + r * TH;
      int p = phys16(i);
      unsigned long long k1 = ((unsigned long long)khi[p] << 32) | klo[p];
      int d = (int)((k1 >> shift) & (RADIX - 1));
      dst[(size_t)(gbase[d] + (i - dstart[d]))] = k1;
    }
    __syncthreads();
    if (sub == 0) {
      gbase[tid] += hcnt[tid];
      for (int i = tid; i < RADIX * 4; i += TH) h8[i] = 0;
      __syncthreads();
    }
  }
}

// ---------------- unique + final decoder write ----------------
__global__ __launch_bounds__(TH) void k_uniq_count(const unsigned long long* A, int* uPart,
                                                   const int* counters) {
  __shared__ int lds[8];
  int ac = activeChunks(counters);
  if ((int)blockIdx.x >= 2 * ac) { if (threadIdx.x == 0) uPart[blockIdx.x] = 0; return; }
  size_t base = (size_t)blockIdx.x * STILE + (size_t)threadIdx.x * 16;
  unsigned long long prev = (base == 0) ? 0ULL : A[base - 1];
  int c = 0;
#pragma unroll
  for (int k = 0; k < 16; ++k) {
    unsigned long long v = A[base + k];
    c += (v != SENTK && v != prev) ? 1 : 0;
    prev = v;
  }
#pragma unroll
  for (int off = 32; off; off >>= 1) c += __shfl_down(c, off, 64);
  if ((threadIdx.x & 63) == 0) lds[threadIdx.x >> 6] = c;
  __syncthreads();
  if (threadIdx.x == 0) {
    int s = 0;
#pragma unroll
    for (int w = 0; w < 8; ++w) s += lds[w];
    uPart[blockIdx.x] = s;
  }
}

// compact uniques via LDS staging, then dense coalesced writes (no RMW thrash)
__global__ __launch_bounds__(TH) void k_final(const unsigned long long* A, const int* uPart,
                                              const int* counters, float* out) {
  __shared__ int aux[9];
  __shared__ float sq[STILE], sr[STILE];
  __shared__ int scnt;
  int ac = activeChunks(counters);
  if ((int)blockIdx.x >= 2 * ac) return;
  size_t base = (size_t)blockIdx.x * STILE + (size_t)threadIdx.x * 16;
  unsigned long long v[16];
  int f[16], c = 0;
  unsigned long long prev = (base == 0) ? 0ULL : A[base - 1];
#pragma unroll
  for (int k = 0; k < 16; ++k) {
    v[k] = A[base + k];
    f[k] = (v[k] != SENTK && v[k] != prev) ? 1 : 0;
    c += f[k];
    prev = v[k];
  }
  int ex = scan512_1(c, aux);
  if (threadIdx.x == TH - 1) scnt = ex + c;
  int j = ex;
#pragma unroll
  for (int k = 0; k < 16; ++k) {
    if (f[k]) {
      unsigned long long val = v[k];
      long long q = (long long)((double)val * (1.0 / 150000.0));
      long long r = (long long)val - q * 150000LL;
      if (r < 0) { q--; r += 150000LL; }
      else if (r >= 150000LL) { q++; r -= 150000LL; }
      sq[j] = (float)q; sr[j] = (float)r; j++;
    }
  }
  __syncthreads();
  int cnt = scnt;
  int jb = 1 + uPart[blockIdx.x];   // +1: slot 0 is the always-present hash 0
  for (int i = (int)threadIdx.x; i < cnt; i += TH) {
    out[OUT_DR + jb + i] = sq[i];
    out[OUT_DC + jb + i] = sr[i];
  }
}

// dec_vals fill (1.0 below totU, 0 after) + zero tails of dec_rows/cols + slot 0
__global__ __launch_bounds__(256) void k_dectail(const int* counters, float* out) {
  int i = (blockIdx.x * 256 + threadIdx.x) * 4;
  if (i >= MOUT) return;
  int totU = counters[3] + 1;
  float4 dv;
  dv.x = (i + 0 < totU) ? 1.0f : 0.0f;
  dv.y = (i + 1 < totU) ? 1.0f : 0.0f;
  dv.z = (i + 2 < totU) ? 1.0f : 0.0f;
  dv.w = (i + 3 < totU) ? 1.0f : 0.0f;
  *(float4*)&out[OUT_DV + i] = dv;
  if (i + 3 >= totU) {
    float4 z = make_float4(0.0f, 0.0f, 0.0f, 0.0f);
    if (i >= totU) {
      *(float4*)&out[OUT_DR + i] = z;
      *(float4*)&out[OUT_DC + i] = z;
    } else {
#pragma unroll
      for (int k = 0; k < 4; ++k)
        if (i + k >= totU) { out[OUT_DR + i + k] = 0.0f; out[OUT_DC + i + k] = 0.0f; }
    }
  }
  if (i == 0) { out[OUT_DR] = 0.0f; out[OUT_DC] = 0.0f; }
}

// ---------------- host launcher ----------------
extern "C" void kernel_launch(void* const* d_in, const int* in_sizes, int n_in,
                              void* d_out, int out_size, void* d_ws, size_t ws_size,
                              hipStream_t stream) {
  const int* rows = (const int*)d_in[1];   // d_in[0]=adj_vals (unused by reference outputs)
  const int* cols = (const int*)d_in[2];
  const int* seeds = (const int*)d_in[3];
  float* out = (float*)d_out;

  // workspace layout
  char* ws = (char*)d_ws;
  size_t off = 0;
  auto alloc = [&](size_t bytes) -> char* {
    char* p = ws + off;
    off += (bytes + 255) & ~(size_t)255;
    return p;
  };
  unsigned long long* A = (unsigned long long*)alloc(MP * 8);
  uint8_t* alive = (uint8_t*)alloc(EDGES);
  char* zbase = ws + off;                       // ---- zeroed zone ----
  uint8_t* frontier = (uint8_t*)alloc(NNODE);
  uint8_t* nextf = (uint8_t*)alloc(NNODE);
  uint8_t* masked = (uint8_t*)alloc(NNODE);
  float* deg = (float*)alloc((size_t)NNODE * 4);
  int* counters = (int*)alloc(256 * 4);         // [1]=tem_num [2]=tailCnt [3]=uniqSum
  size_t zsize = (size_t)((ws + off) - zbase);  // ---- end zeroed zone ----
  float* dnorm = (float*)alloc((size_t)NNODE * 4);
  int* mlist = (int*)alloc((size_t)NNODE * 4);
  int* hist = (int*)alloc((size_t)NHIST * 4);
  int* spart = (int*)alloc(2048 * 4);
  int* uPart = (int*)alloc(2048 * 4);
  int* mPart = (int*)alloc(256 * 4);

  // radix ping-pong buffer B lives in the (later-overwritten) dec region of d_out
  unsigned long long* Bbuf = (unsigned long long*)(out + OUT_DR);

  // JAX key derivation (threefry_partitionable semantics)
  uint32_t ks0, ks1, kr0, kr1, kc0, kc1, s10, s11, s20, s21;
  tf2x32(0u, 42u, 0u, 0u, ks0, ks1);
  tf2x32(0u, 42u, 0u, 1u, kr0, kr1);
  tf2x32(0u, 42u, 0u, 2u, kc0, kc1);
  tf2x32(ks0, ks1, 0u, 0u, s10, s11);
  tf2x32(ks0, ks1, 0u, 1u, s20, s21);

  hipMemsetAsync(zbase, 0, zsize, stream);
  hipMemsetAsync(alive, 1, EDGES, stream);

  const int EB = EDGES / 256;                // 15625
  const int NB = (NNODE + 255) / 256;        // 586

  k_seed<<<2, 256, 0, stream>>>(seeds, frontier, masked);
  k_bfs0<<<EB, 256, 0, stream>>>(rows, cols, frontier, alive, nextf, out);
  k_masked_or<<<NB, 256, 0, stream>>>(masked, nextf);
  k_bfs1deg<<<EB, 256, 0, stream>>>(rows, cols, nextf, alive, deg);
  k_sample<<<(NSAMP + 255) / 256, 256, 0, stream>>>(masked, s10, s11, s20, s21);
  k_dnorm<<<NB, 256, 0, stream>>>(deg, dnorm);
  k_enctail<<<EB, 256, 0, stream>>>(rows, cols, alive, dnorm, out, A, counters);

  // masked node list (ascending) + tem_num
  k_mreduce<<<MB, 256, 0, stream>>>(masked, mPart);
  k_scan_small<<<1, 1024, 0, stream>>>(mPart, MB, counters + 1);
  k_mscatter<<<MB, 256, 0, stream>>>(masked, mPart, mlist);

  // pairs + self loops at fixed slots; tail already appended compacted
  k_build_pairs<<<EB, 256, 0, stream>>>(mlist, counters, A, kr0, kr1, kc0, kc1);
  k_build_self<<<NB, 256, 0, stream>>>(A);
  k_pad<<<CHUNK / 256, 256, 0, stream>>>(A, counters);

  // radix sort: A -> B -> A -> B -> A (4 passes x 9 bits over active chunks)
  unsigned long long* src = A;
  unsigned long long* dst = Bbuf;
  const int shifts[4] = {0, 9, 18, 27};
  for (int p = 0; p < 4; ++p) {
    k_rhist2<<<NC, TH, 0, stream>>>(src, hist, shifts[p], counters);
    k_scan_reduce<<<SCB, 256, 0, stream>>>(hist, spart, NHIST);
    k_scan_small<<<1, 1024, 0, stream>>>(spart, SCB, nullptr);
    k_scan_apply<<<SCB, 256, 0, stream>>>(hist, spart, NHIST);
    k_rscatter2<<<NC, TH, 0, stream>>>(src, dst, hist, shifts[p], counters);
    unsigned long long* t = src; src = dst; dst = t;
  }
  // sorted result now in A (src == A)

  k_uniq_count<<<NTILE, TH, 0, stream>>>(src, uPart, counters);
  k_scan_small<<<1, 1024, 0, stream>>>(uPart, NTILE, counters + 3);
  k_final<<<NTILE, TH, 0, stream>>>(src, uPart, counters, out);
  k_dectail<<<(MOUT / 4 + 255) / 256, 256, 0, stream>>>(counters, out);
}

// Round 6
// 1220.716 us; speedup vs baseline: 2.2295x; 1.1135x over previous
//
#include <hip/hip_runtime.h>
#include <stdint.h>

// ---------------- problem constants ----------------
#define NNODE   150000
#define EDGES   4000000
#define NSEED   500
#define NSAMP   15000              // int(150000 * 0.1)
#define MOUT    12150000           // 3E + N : decoder output length
#define SENTK   0xFFFFFFFFFFFFFFFFULL
#define SPAN    150000ULL
#define MULTK   51616ULL           // ((2^32 % 150000)^2) % 150000
#define FIXED   8150000            // pairs (8M) + self loops (150k) fixed slots

// sort geometry: chunk = 16384 keys (2 sub-tiles of 8192 through one LDS)
// NOTE (R5 post-mortem): LSD radix REQUIRES a stable per-pass scatter — the
// in-LDS 3x3-bit split below is what preserves lower-digit order across
// passes. Do not replace with atomic-rank placement.
#define STILE   8192
#define CHUNK   16384
#define TH      512
#define NC      744                // max chunks; multiple of 8 for XCD swizzle
#define NCX     (NC / 8)           // 93
#define MP      ((size_t)NC * CHUNK)
#define RADIX   512
#define NHIST   (RADIX * NC)       // 380,928
#define SCB     (NHIST / 2048)     // 186 (exact)
#define NTILE   (NC * 2)           // 1488 max sub-tiles for uniq/final

// enctail geometry
#define EBLK    2048
#define ENB     ((EDGES + EBLK - 1) / EBLK)   // 1954

// masked-node compaction geometry
#define MTILE   2048
#define MB      ((NNODE + MTILE - 1) / MTILE)   // 74

// out layout (float32): [rows E][cols E][enc E][dec_rows M][dec_cols M][dec_vals M]
#define OUT_DR  12000000
#define OUT_DC  24150000
#define OUT_DV  36300000

// ---------------- threefry2x32 (JAX-exact, 20 rounds) ----------------
__host__ __device__ inline void tf2x32(uint32_t k0, uint32_t k1,
                                       uint32_t x0, uint32_t x1,
                                       uint32_t& o0, uint32_t& o1) {
  uint32_t ks2 = k0 ^ k1 ^ 0x1BD11BDAu;
  x0 += k0; x1 += k1;
#define TFR(d) { x0 += x1; x1 = (x1 << d) | (x1 >> (32 - d)); x1 ^= x0; }
  TFR(13) TFR(15) TFR(26) TFR(6)
  x0 += k1; x1 += ks2 + 1u;
  TFR(17) TFR(29) TFR(16) TFR(24)
  x0 += ks2; x1 += k0 + 2u;
  TFR(13) TFR(15) TFR(26) TFR(6)
  x0 += k0; x1 += k1 + 3u;
  TFR(17) TFR(29) TFR(16) TFR(24)
  x0 += k1; x1 += ks2 + 4u;
  TFR(13) TFR(15) TFR(26) TFR(6)
  x0 += ks2; x1 += k0 + 5u;
#undef TFR
  o0 = x0; o1 = x1;
}

__device__ inline unsigned long long tf_bits64(uint32_t k0, uint32_t k1, uint32_t i) {
  uint32_t o0, o1;
  tf2x32(k0, k1, 0u, i, o0, o1);
  return ((unsigned long long)o0 << 32) | o1;
}

// active chunk count (device, from tail append counter)
__device__ inline int activeChunks(const int* counters) {
  int m2 = FIXED + counters[2];
  return (m2 + CHUNK - 1) / CHUNK;
}

// ---------------- block primitives ----------------
__device__ inline int block_excl_scan_256(int v, int* lds /*>=5 ints*/, int& total) {
  int lane = threadIdx.x & 63, wid = threadIdx.x >> 6;
  int inc = v;
#pragma unroll
  for (int off = 1; off < 64; off <<= 1) {
    int y = __shfl_up(inc, off, 64);
    if (lane >= off) inc += y;
  }
  if (lane == 63) lds[wid] = inc;
  __syncthreads();
  if (threadIdx.x == 0) {
    int a = 0;
#pragma unroll
    for (int w = 0; w < 4; ++w) { int t = lds[w]; lds[w] = a; a += t; }
    lds[4] = a;
  }
  __syncthreads();
  total = lds[4];
  int res = inc - v + lds[wid];
  __syncthreads();
  return res;
}

// exclusive scan of 4 packed ints across 512 threads; aux >= 36 ints.
__device__ inline void scan512_x4(const int v[4], int ex[4], int tot[4], int* aux) {
  int lane = threadIdx.x & 63, wid = threadIdx.x >> 6;
  int inc[4];
#pragma unroll
  for (int j = 0; j < 4; ++j) inc[j] = v[j];
#pragma unroll
  for (int off = 1; off < 64; off <<= 1) {
#pragma unroll
    for (int j = 0; j < 4; ++j) {
      int y = __shfl_up(inc[j], off, 64);
      if (lane >= off) inc[j] += y;
    }
  }
  if (lane == 63) {
#pragma unroll
    for (int j = 0; j < 4; ++j) aux[j * 8 + wid] = inc[j];
  }
  __syncthreads();
  if (threadIdx.x == 0) {
#pragma unroll
    for (int j = 0; j < 4; ++j) {
      int a = 0;
#pragma unroll
      for (int w = 0; w < 8; ++w) { int t = aux[j * 8 + w]; aux[j * 8 + w] = a; a += t; }
      aux[32 + j] = a;
    }
  }
  __syncthreads();
#pragma unroll
  for (int j = 0; j < 4; ++j) {
    ex[j] = inc[j] - v[j] + aux[j * 8 + wid];
    tot[j] = aux[32 + j];
  }
}

__device__ inline int scan512_1(int v, int* aux /*>=9 ints*/) {
  int lane = threadIdx.x & 63, wid = threadIdx.x >> 6;
  int inc = v;
#pragma unroll
  for (int off = 1; off < 64; off <<= 1) {
    int y = __shfl_up(inc, off, 64);
    if (lane >= off) inc += y;
  }
  if (lane == 63) aux[wid] = inc;
  __syncthreads();
  if (threadIdx.x == 0) {
    int a = 0;
#pragma unroll
    for (int w = 0; w < 8; ++w) { int t = aux[w]; aux[w] = a; a += t; }
  }
  __syncthreads();
  return inc - v + aux[wid];
}

// LDS swizzle: rotate within 16-element rows to break 16-stride bank aliasing
__device__ inline int phys16(int p) { return (p & ~15) | ((p + (p >> 4)) & 15); }

// ---------------- BFS / enc kernels (fused) ----------------
__global__ __launch_bounds__(256) void k_seed(const int* seeds, uint8_t* frontier, uint8_t* masked) {
  int i = blockIdx.x * 256 + threadIdx.x;
  if (i < NSEED) { int v = seeds[i]; frontier[v] = 1; masked[v] = 1; }
}

// bfs hop 0 + rows/cols output copy
__global__ __launch_bounds__(256) void k_bfs0(const int* rows, const int* cols,
                                              const uint8_t* frontier, uint8_t* alive, uint8_t* nxt,
                                              float* out) {
  int e = blockIdx.x * 256 + threadIdx.x;
  int r = rows[e], c = cols[e];
  out[e] = (float)r;
  out[EDGES + e] = (float)c;
  if (frontier[r] | frontier[c]) { alive[e] = 0; nxt[r] = 1; nxt[c] = 1; }
}

__global__ __launch_bounds__(256) void k_masked_or(uint8_t* masked, const uint8_t* nxt) {
  int v = blockIdx.x * 256 + threadIdx.x;
  if (v < NNODE) masked[v] |= nxt[v];
}

// bfs hop 1 + degree accumulation on the final alive set
__global__ __launch_bounds__(256) void k_bfs1deg(const int* rows, const int* cols,
                                                 const uint8_t* nxt, uint8_t* alive, float* deg) {
  int e = blockIdx.x * 256 + threadIdx.x;
  int r = rows[e];
  int a = alive[e];
  if (a && (nxt[r] | nxt[cols[e]])) { alive[e] = 0; a = 0; }
  if (a) atomicAdd(&deg[r], 1.0f);
}

__global__ __launch_bounds__(256) void k_sample(uint8_t* masked,
                                                uint32_t a0, uint32_t a1, uint32_t b0, uint32_t b1) {
  int i = blockIdx.x * 256 + threadIdx.x;
  if (i >= NSAMP) return;
  unsigned long long hi = tf_bits64(a0, a1, (uint32_t)i);
  unsigned long long lo = tf_bits64(b0, b1, (uint32_t)i);
  unsigned long long off = ((hi % SPAN) * MULTK + (lo % SPAN)) % SPAN;
  masked[off] = 1;
}

__global__ __launch_bounds__(256) void k_dnorm(const float* deg, float* dnorm) {
  int v = blockIdx.x * 256 + threadIdx.x;
  if (v < NNODE) {
    float x = deg[v] + 1e-12f;
    dnorm[v] = (float)(1.0 / sqrt((double)x));
  }
}

// encoder values + compacted tail-hash append.
// 2048 edges/block -> 1954 block-level atomics (same-address atomic service
// rate ~12ns was R4's 187us bottleneck at 15625 atomics).
__global__ __launch_bounds__(256) void k_enctail(const int* rows, const int* cols,
                                                 const uint8_t* alive, const float* dnorm,
                                                 float* out, unsigned long long* A, int* counters) {
  __shared__ int lds[8];
  __shared__ unsigned long long stage[EBLK];
  __shared__ int sbase;
  int base = blockIdx.x * EBLK;
  unsigned long long vv[8];
  int emit[8], c = 0;
#pragma unroll
  for (int k = 0; k < 8; ++k) {
    int e = base + k * 256 + threadIdx.x;
    emit[k] = 0;
    if (e < EDGES) {
      int r = rows[e], cc = cols[e];
      int a = alive[e];
      out[2 * EDGES + e] = a ? dnorm[r] * dnorm[cc] : 0.0f;
      unsigned long long v = (unsigned long long)((long long)r * 150000LL + cc);
      if (a && v) { emit[k] = 1; vv[k] = v; c++; }
    }
  }
  int total;
  int ex = block_excl_scan_256(c, lds, total);
#pragma unroll
  for (int k = 0; k < 8; ++k) {
    if (emit[k]) stage[ex++] = vv[k];
  }
  if (threadIdx.x == 0) sbase = total ? atomicAdd(&counters[2], total) : 0;
  __syncthreads();
  int sb = sbase;
  for (int i = threadIdx.x; i < total; i += 256)
    A[(size_t)FIXED + sb + i] = stage[i];
}

// ---------------- masked-node compaction ----------------
__global__ __launch_bounds__(256) void k_mreduce(const uint8_t* masked, int* mPart) {
  __shared__ int lds[4];
  int base = blockIdx.x * MTILE;
  int s = 0;
  for (int i = threadIdx.x; i < MTILE; i += 256) {
    int idx = base + i;
    if (idx < NNODE) s += masked[idx];
  }
#pragma unroll
  for (int off = 32; off; off >>= 1) s += __shfl_down(s, off, 64);
  if ((threadIdx.x & 63) == 0) lds[threadIdx.x >> 6] = s;
  __syncthreads();
  if (threadIdx.x == 0) mPart[blockIdx.x] = lds[0] + lds[1] + lds[2] + lds[3];
}

__global__ __launch_bounds__(1024) void k_scan_small(int* part, int m, int* totalOut) {
  __shared__ int a[2048];
  int tid = threadIdx.x;
  a[tid] = (tid < m) ? part[tid] : 0;
  a[tid + 1024] = (tid + 1024 < m) ? part[tid + 1024] : 0;
  __syncthreads();
  for (int off = 1; off < 2048; off <<= 1) {
    int v1 = 0, v2;
    if (tid >= off) v1 = a[tid - off];
    v2 = a[tid + 1024 - off];
    __syncthreads();
    if (tid >= off) a[tid] += v1;
    a[tid + 1024] += v2;
    __syncthreads();
  }
  if (tid < m) part[tid] = (tid == 0) ? 0 : a[tid - 1];
  if (tid + 1024 < m) part[tid + 1024] = a[tid + 1023];
  if (tid == 0 && totalOut) *totalOut = a[2047];
}

__global__ __launch_bounds__(256) void k_mscatter(const uint8_t* masked, const int* mPart, int* mlist) {
  __shared__ int lds[8];
  int t0 = blockIdx.x * MTILE + threadIdx.x * 8;
  int c = 0;
#pragma unroll
  for (int k = 0; k < 8; ++k) { int idx = t0 + k; c += (idx < NNODE) ? masked[idx] : 0; }
  int total;
  int ex = block_excl_scan_256(c, lds, total);
  int run = mPart[blockIdx.x] + ex;
#pragma unroll
  for (int k = 0; k < 8; ++k) {
    int idx = t0 + k;
    if (idx < NNODE && masked[idx]) mlist[run++] = idx;
  }
}

// ---------------- hash building ----------------
// dead / zero hashes are written as 0 (not SENTK): zeros sort to the front,
// are never counted as uniques (prev inits to 0; hash 0 is handled by the +1).
__global__ __launch_bounds__(256) void k_build_pairs(const int* mlist, const int* counters,
                                                     unsigned long long* A,
                                                     uint32_t r0, uint32_t r1, uint32_t c0, uint32_t c1) {
  int e = blockIdx.x * 256 + threadIdx.x;
  long long tem = counters[1];
  unsigned long long bits = tf_bits64(r0, r1, (uint32_t)e);
  double u1 = __longlong_as_double((long long)((bits >> 12) | 0x3FF0000000000000ULL)) - 1.0;
  long long i1 = (long long)(u1 * (double)tem); if (i1 > tem - 1) i1 = tem - 1;
  bits = tf_bits64(c0, c1, (uint32_t)e);
  double u2 = __longlong_as_double((long long)((bits >> 12) | 0x3FF0000000000000ULL)) - 1.0;
  long long i2 = (long long)(u2 * (double)tem); if (i2 > tem - 1) i2 = tem - 1;
  long long tr = mlist[i1], tc = mlist[i2];
  A[2 * (size_t)e]     = (unsigned long long)(tr * 150000LL + tc);
  A[2 * (size_t)e + 1] = (unsigned long long)(tc * 150000LL + tr);
}

__global__ __launch_bounds__(256) void k_build_self(unsigned long long* A) {
  int v = blockIdx.x * 256 + threadIdx.x;
  if (v >= NNODE) return;
  A[2 * (size_t)EDGES + v] = (unsigned long long)v * 150001ULL;   // v=0 -> 0, fine
}

// pad [m2, AC*CHUNK) with sentinels (< CHUNK elements)
__global__ __launch_bounds__(256) void k_pad(unsigned long long* A, const int* counters) {
  int m2 = FIXED + counters[2];
  int ac = (m2 + CHUNK - 1) / CHUNK;
  size_t idx = (size_t)m2 + blockIdx.x * 256 + threadIdx.x;
  if (idx < (size_t)ac * CHUNK) A[idx] = SENTK;
}

// ---------------- LSD radix sort: 4 passes x 9 bits, 16384-key chunks ----------------
__global__ __launch_bounds__(TH) void k_rhist2(const unsigned long long* __restrict__ src,
                                               int* __restrict__ hist, int shift,
                                               const int* counters) {
  __shared__ int h8[RADIX * 4];
  int tid = threadIdx.x;
  int ac = activeChunks(counters);
  if ((int)blockIdx.x >= ac) { hist[(size_t)tid * NC + blockIdx.x] = 0; return; }
  for (int i = tid; i < RADIX * 4; i += TH) h8[i] = 0;
  __syncthreads();
  const ulonglong2* s2 = (const ulonglong2*)(src + (size_t)blockIdx.x * CHUNK);
  int rep = tid & 3, scnt = 0;
#pragma unroll
  for (int r = 0; r < 16; ++r) {
    ulonglong2 v = s2[tid + r * TH];
    int d0 = (int)((v.x >> shift) & (RADIX - 1));
    int d1 = (int)((v.y >> shift) & (RADIX - 1));
    if (d0 == RADIX - 1) scnt++; else atomicAdd(&h8[d0 * 4 + rep], 1);
    if (d1 == RADIX - 1) scnt++; else atomicAdd(&h8[d1 * 4 + rep], 1);
  }
  if (scnt) atomicAdd(&h8[(RADIX - 1) * 4 + rep], scnt);
  __syncthreads();
  int4 hv = *(const int4*)&h8[tid * 4];
  hist[(size_t)tid * NC + blockIdx.x] = hv.x + hv.y + hv.z + hv.w;
}

__global__ __launch_bounds__(256) void k_scan_reduce(const int* g, int* part, int n) {
  __shared__ int lds[4];
  int base = blockIdx.x * 2048;
  int s = 0;
  for (int i = threadIdx.x; i < 2048; i += 256) {
    int idx = base + i;
    if (idx < n) s += g[idx];
  }
#pragma unroll
  for (int off = 32; off; off >>= 1) s += __shfl_down(s, off, 64);
  if ((threadIdx.x & 63) == 0) lds[threadIdx.x >> 6] = s;
  __syncthreads();
  if (threadIdx.x == 0) part[blockIdx.x] = lds[0] + lds[1] + lds[2] + lds[3];
}

__global__ __launch_bounds__(256) void k_scan_apply(int* g, const int* part, int n) {
  __shared__ int lds[8];
  int t0 = blockIdx.x * 2048 + threadIdx.x * 8;
  int x[8];
#pragma unroll
  for (int k = 0; k < 8; ++k) { int idx = t0 + k; x[k] = (idx < n) ? g[idx] : 0; }
  int s = 0;
#pragma unroll
  for (int k = 0; k < 8; ++k) { int t = x[k]; x[k] = s; s += t; }
  int total;
  int ex = block_excl_scan_256(s, lds, total);
  int add = part[blockIdx.x] + ex;
#pragma unroll
  for (int k = 0; k < 8; ++k) { int idx = t0 + k; if (idx < n) g[idx] = x[k] + add; }
}

// STABLE scatter (required for LSD): 3x3-bit in-LDS split rounds sort the
// sub-tile by the 9-bit digit while preserving intra-digit (= prior-pass)
// order, then a direct-addressed coalesced write per digit segment.
__global__ __launch_bounds__(TH) void k_rscatter2(const unsigned long long* __restrict__ src,
                                                  unsigned long long* __restrict__ dst,
                                                  const int* __restrict__ hist, int shift,
                                                  const int* counters) {
  __shared__ uint32_t klo[STILE], khi[STILE];
  __shared__ int h8[RADIX * 4];
  __shared__ int dstart[RADIX], hcnt[RADIX], gbase[RADIX];
  __shared__ int aux[40];
  int tid = threadIdx.x;
  // XCD-contiguous chunk swizzle: adjacent chunks on the same XCD, temporally adjacent
  int chunk = (blockIdx.x & 7) * NCX + (blockIdx.x >> 3);
  int ac = activeChunks(counters);
  if (chunk >= ac) return;
  size_t cbase = (size_t)chunk * CHUNK;
  gbase[tid] = hist[(size_t)tid * NC + chunk];
  for (int i = tid; i < RADIX * 4; i += TH) h8[i] = 0;
  __syncthreads();
  int rep = tid & 3;
  for (int sub = 0; sub < 2; ++sub) {
    size_t sbase = cbase + (size_t)sub * STILE;
    const ulonglong2* s2 = (const ulonglong2*)(src + sbase);
    int scnt = 0;
#pragma unroll
    for (int r = 0; r < 8; ++r) {
      ulonglong2 v = s2[tid + r * TH];
      int i = 2 * (tid + r * TH);
      int p0 = phys16(i), p1 = phys16(i + 1);
      klo[p0] = (uint32_t)v.x; khi[p0] = (uint32_t)(v.x >> 32);
      klo[p1] = (uint32_t)v.y; khi[p1] = (uint32_t)(v.y >> 32);
      int d0 = (int)((v.x >> shift) & (RADIX - 1));
      int d1 = (int)((v.y >> shift) & (RADIX - 1));
      if (d0 == RADIX - 1) scnt++; else atomicAdd(&h8[d0 * 4 + rep], 1);
      if (d1 == RADIX - 1) scnt++; else atomicAdd(&h8[d1 * 4 + rep], 1);
    }
    if (scnt) atomicAdd(&h8[(RADIX - 1) * 4 + rep], scnt);
    __syncthreads();
    int4 hv = *(const int4*)&h8[tid * 4];
    int h = hv.x + hv.y + hv.z + hv.w;
    hcnt[tid] = h;
    int ex0 = scan512_1(h, aux);
    dstart[tid] = ex0;
    __syncthreads();
    // 3 x 3-bit stable split rounds -> sub-tile sorted by 9-bit digit
    int t0 = tid * 16;
    for (int rr = 0; rr < 3; ++rr) {
      int sh = shift + 3 * rr;
      unsigned long long key[16];
      int c[8] = {0, 0, 0, 0, 0, 0, 0, 0};
#pragma unroll
      for (int k = 0; k < 16; ++k) {
        int p = phys16(t0 + k);
        key[k] = ((unsigned long long)khi[p] << 32) | klo[p];
        int d = (int)((key[k] >> sh) & 7);
#pragma unroll
        for (int q = 0; q < 8; ++q) c[q] += (d == q);
      }
      int v4[4], ex[4], tot[4];
#pragma unroll
      for (int j = 0; j < 4; ++j) v4[j] = c[2 * j] | (c[2 * j + 1] << 16);
      scan512_x4(v4, ex, tot, aux);
      int start[8];
      {
        int a = 0;
#pragma unroll
        for (int j = 0; j < 4; ++j) {
          int tlo = tot[j] & 0xffff, thi = tot[j] >> 16;
          int elo = ex[j] & 0xffff,  ehi = ex[j] >> 16;
          start[2 * j]     = a + elo; a += tlo;
          start[2 * j + 1] = a + ehi; a += thi;
        }
      }
#pragma unroll
      for (int k = 0; k < 16; ++k) {
        int d = (int)((key[k] >> sh) & 7);
        int pos = 0;
#pragma unroll
        for (int q = 0; q < 8; ++q) { if (d == q) pos = start[q]; }
#pragma unroll
        for (int q = 0; q < 8; ++q) start[q] += (d == q);
        int p = phys16(pos);
        klo[p] = (uint32_t)key[k]; khi[p] = (uint32_t)(key[k] >> 32);
      }
      __syncthreads();
    }
    // direct-addressed scatter: read back in sorted order
#pragma unroll
    for (int r = 0; r < 16; ++r) {
      int i = tid + r * TH;
      int p = phys16(i);
      unsigned long long k1 = ((unsigned long long)khi[p] << 32) | klo[p];
      int d = (int)((k1 >> shift) & (RADIX - 1));
      dst[(size_t)(gbase[d] + (i - dstart[d]))] = k1;
    }
    __syncthreads();
    if (sub == 0) {
      gbase[tid] += hcnt[tid];
      for (int i = tid; i < RADIX * 4; i += TH) h8[i] = 0;
      __syncthreads();
    }
  }
}

// ---------------- unique + final decoder write ----------------
__global__ __launch_bounds__(TH) void k_uniq_count(const unsigned long long* A, int* uPart,
                                                   const int* counters) {
  __shared__ int lds[8];
  int ac = activeChunks(counters);
  if ((int)blockIdx.x >= 2 * ac) { if (threadIdx.x == 0) uPart[blockIdx.x] = 0; return; }
  size_t base = (size_t)blockIdx.x * STILE + (size_t)threadIdx.x * 16;
  unsigned long long prev = (base == 0) ? 0ULL : A[base - 1];
  int c = 0;
#pragma unroll
  for (int k = 0; k < 16; ++k) {
    unsigned long long v = A[base + k];
    c += (v != SENTK && v != prev) ? 1 : 0;
    prev = v;
  }
#pragma unroll
  for (int off = 32; off; off >>= 1) c += __shfl_down(c, off, 64);
  if ((threadIdx.x & 63) == 0) lds[threadIdx.x >> 6] = c;
  __syncthreads();
  if (threadIdx.x == 0) {
    int s = 0;
#pragma unroll
    for (int w = 0; w < 8; ++w) s += lds[w];
    uPart[blockIdx.x] = s;
  }
}

// compact uniques via LDS staging, then dense coalesced writes (no RMW thrash)
__global__ __launch_bounds__(TH) void k_final(const unsigned long long* A, const int* uPart,
                                              const int* counters, float* out) {
  __shared__ int aux[9];
  __shared__ float sq[STILE], sr[STILE];
  __shared__ int scnt;
  int ac = activeChunks(counters);
  if ((int)blockIdx.x >= 2 * ac) return;
  size_t base = (size_t)blockIdx.x * STILE + (size_t)threadIdx.x * 16;
  unsigned long long v[16];
  int f[16], c = 0;
  unsigned long long prev = (base == 0) ? 0ULL : A[base - 1];
#pragma unroll
  for (int k = 0; k < 16; ++k) {
    v[k] = A[base + k];
    f[k] = (v[k] != SENTK && v[k] != prev) ? 1 : 0;
    c += f[k];
    prev = v[k];
  }
  int ex = scan512_1(c, aux);
  if (threadIdx.x == TH - 1) scnt = ex + c;
  int j = ex;
#pragma unroll
  for (int k = 0; k < 16; ++k) {
    if (f[k]) {
      unsigned long long val = v[k];
      long long q = (long long)((double)val * (1.0 / 150000.0));
      long long r = (long long)val - q * 150000LL;
      if (r < 0) { q--; r += 150000LL; }
      else if (r >= 150000LL) { q++; r -= 150000LL; }
      sq[j] = (float)q; sr[j] = (float)r; j++;
    }
  }
  __syncthreads();
  int cnt = scnt;
  int jb = 1 + uPart[blockIdx.x];   // +1: slot 0 is the always-present hash 0
  for (int i = (int)threadIdx.x; i < cnt; i += TH) {
    out[OUT_DR + jb + i] = sq[i];
    out[OUT_DC + jb + i] = sr[i];
  }
}

// dec_vals fill (1.0 below totU, 0 after) + zero tails of dec_rows/cols + slot 0
__global__ __launch_bounds__(256) void k_dectail(const int* counters, float* out) {
  int i = (blockIdx.x * 256 + threadIdx.x) * 4;
  if (i >= MOUT) return;
  int totU = counters[3] + 1;
  float4 dv;
  dv.x = (i + 0 < totU) ? 1.0f : 0.0f;
  dv.y = (i + 1 < totU) ? 1.0f : 0.0f;
  dv.z = (i + 2 < totU) ? 1.0f : 0.0f;
  dv.w = (i + 3 < totU) ? 1.0f : 0.0f;
  *(float4*)&out[OUT_DV + i] = dv;
  if (i + 3 >= totU) {
    float4 z = make_float4(0.0f, 0.0f, 0.0f, 0.0f);
    if (i >= totU) {
      *(float4*)&out[OUT_DR + i] = z;
      *(float4*)&out[OUT_DC + i] = z;
    } else {
#pragma unroll
      for (int k = 0; k < 4; ++k)
        if (i + k >= totU) { out[OUT_DR + i + k] = 0.0f; out[OUT_DC + i + k] = 0.0f; }
    }
  }
  if (i == 0) { out[OUT_DR] = 0.0f; out[OUT_DC] = 0.0f; }
}

// ---------------- host launcher ----------------
extern "C" void kernel_launch(void* const* d_in, const int* in_sizes, int n_in,
                              void* d_out, int out_size, void* d_ws, size_t ws_size,
                              hipStream_t stream) {
  const int* rows = (const int*)d_in[1];   // d_in[0]=adj_vals (unused by reference outputs)
  const int* cols = (const int*)d_in[2];
  const int* seeds = (const int*)d_in[3];
  float* out = (float*)d_out;

  // workspace layout
  char* ws = (char*)d_ws;
  size_t off = 0;
  auto alloc = [&](size_t bytes) -> char* {
    char* p = ws + off;
    off += (bytes + 255) & ~(size_t)255;
    return p;
  };
  unsigned long long* A = (unsigned long long*)alloc(MP * 8);
  uint8_t* alive = (uint8_t*)alloc(EDGES);
  char* zbase = ws + off;                       // ---- zeroed zone ----
  uint8_t* frontier = (uint8_t*)alloc(NNODE);
  uint8_t* nextf = (uint8_t*)alloc(NNODE);
  uint8_t* masked = (uint8_t*)alloc(NNODE);
  float* deg = (float*)alloc((size_t)NNODE * 4);
  int* counters = (int*)alloc(256 * 4);         // [1]=tem_num [2]=tailCnt [3]=uniqSum
  size_t zsize = (size_t)((ws + off) - zbase);  // ---- end zeroed zone ----
  float* dnorm = (float*)alloc((size_t)NNODE * 4);
  int* mlist = (int*)alloc((size_t)NNODE * 4);
  int* hist = (int*)alloc((size_t)NHIST * 4);
  int* spart = (int*)alloc(2048 * 4);
  int* uPart = (int*)alloc(2048 * 4);
  int* mPart = (int*)alloc(256 * 4);

  // radix ping-pong buffer B lives in the (later-overwritten) dec region of d_out
  unsigned long long* Bbuf = (unsigned long long*)(out + OUT_DR);

  // JAX key derivation (threefry_partitionable semantics)
  uint32_t ks0, ks1, kr0, kr1, kc0, kc1, s10, s11, s20, s21;
  tf2x32(0u, 42u, 0u, 0u, ks0, ks1);
  tf2x32(0u, 42u, 0u, 1u, kr0, kr1);
  tf2x32(0u, 42u, 0u, 2u, kc0, kc1);
  tf2x32(ks0, ks1, 0u, 0u, s10, s11);
  tf2x32(ks0, ks1, 0u, 1u, s20, s21);

  hipMemsetAsync(zbase, 0, zsize, stream);
  hipMemsetAsync(alive, 1, EDGES, stream);

  const int EB = EDGES / 256;                // 15625
  const int NB = (NNODE + 255) / 256;        // 586

  k_seed<<<2, 256, 0, stream>>>(seeds, frontier, masked);
  k_bfs0<<<EB, 256, 0, stream>>>(rows, cols, frontier, alive, nextf, out);
  k_masked_or<<<NB, 256, 0, stream>>>(masked, nextf);
  k_bfs1deg<<<EB, 256, 0, stream>>>(rows, cols, nextf, alive, deg);
  k_sample<<<(NSAMP + 255) / 256, 256, 0, stream>>>(masked, s10, s11, s20, s21);
  k_dnorm<<<NB, 256, 0, stream>>>(deg, dnorm);
  k_enctail<<<ENB, 256, 0, stream>>>(rows, cols, alive, dnorm, out, A, counters);

  // masked node list (ascending) + tem_num
  k_mreduce<<<MB, 256, 0, stream>>>(masked, mPart);
  k_scan_small<<<1, 1024, 0, stream>>>(mPart, MB, counters + 1);
  k_mscatter<<<MB, 256, 0, stream>>>(masked, mPart, mlist);

  // pairs + self loops at fixed slots; tail already appended compacted
  k_build_pairs<<<EB, 256, 0, stream>>>(mlist, counters, A, kr0, kr1, kc0, kc1);
  k_build_self<<<NB, 256, 0, stream>>>(A);
  k_pad<<<CHUNK / 256, 256, 0, stream>>>(A, counters);

  // radix sort: A -> B -> A -> B -> A (4 passes x 9 bits over active chunks)
  unsigned long long* src = A;
  unsigned long long* dst = Bbuf;
  const int shifts[4] = {0, 9, 18, 27};
  for (int p = 0; p < 4; ++p) {
    k_rhist2<<<NC, TH, 0, stream>>>(src, hist, shifts[p], counters);
    k_scan_reduce<<<SCB, 256, 0, stream>>>(hist, spart, NHIST);
    k_scan_small<<<1, 1024, 0, stream>>>(spart, SCB, nullptr);
    k_scan_apply<<<SCB, 256, 0, stream>>>(hist, spart, NHIST);
    k_rscatter2<<<NC, TH, 0, stream>>>(src, dst, hist, shifts[p], counters);
    unsigned long long* t = src; src = dst; dst = t;
  }
  // sorted result now in A (src == A)

  k_uniq_count<<<NTILE, TH, 0, stream>>>(src, uPart, counters);
  k_scan_small<<<1, 1024, 0, stream>>>(uPart, NTILE, counters + 3);
  k_final<<<NTILE, TH, 0, stream>>>(src, uPart, counters, out);
  k_dectail<<<(MOUT / 4 + 255) / 256, 256, 0, stream>>>(counters, out);
}

// Round 7
// 1048.696 us; speedup vs baseline: 2.5952x; 1.1640x over previous
//
#include <hip/hip_runtime.h>
#include <stdint.h>

// ---------------- problem constants ----------------
#define NNODE   150000
#define EDGES   4000000
#define NSEED   500
#define NSAMP   15000              // int(150000 * 0.1)
#define MOUT    12150000           // 3E + N : decoder output length
#define SENTK   0xFFFFFFFFFFFFFFFFULL
#define SPAN    150000ULL
#define MULTK   51616ULL           // ((2^32 % 150000)^2) % 150000
#define FIXED   8150000            // pairs (8M) + self loops (150k) fixed slots

// sort geometry: 8192-key chunks, one tile per block (tail smoothing vs 16k).
// NOTE (R5 post-mortem): LSD radix REQUIRES a stable per-pass scatter — the
// in-LDS 3x3-bit split below is what preserves lower-digit order across
// passes. Do not replace with atomic-rank placement.
#define CHUNK   8192
#define TH      512
#define NC      1488               // max chunks; multiple of 8 for XCD swizzle
#define NCX     (NC / 8)           // 186
#define MP      ((size_t)NC * CHUNK)
#define RADIX   512
#define NHIST   (RADIX * NC)       // 761,856
#define SCB     (NHIST / 2048)     // 372 (exact)
#define NTILE   NC                 // uniq/final tiles == chunks

// enctail geometry
#define EBLK    2048
#define ENB     ((EDGES + EBLK - 1) / EBLK)   // 1954

// masked-node compaction geometry
#define MTILE   2048
#define MB      ((NNODE + MTILE - 1) / MTILE)   // 74

// out layout (float32): [rows E][cols E][enc E][dec_rows M][dec_cols M][dec_vals M]
#define OUT_DR  12000000
#define OUT_DC  24150000
#define OUT_DV  36300000

// ---------------- threefry2x32 (JAX-exact, 20 rounds) ----------------
__host__ __device__ inline void tf2x32(uint32_t k0, uint32_t k1,
                                       uint32_t x0, uint32_t x1,
                                       uint32_t& o0, uint32_t& o1) {
  uint32_t ks2 = k0 ^ k1 ^ 0x1BD11BDAu;
  x0 += k0; x1 += k1;
#define TFR(d) { x0 += x1; x1 = (x1 << d) | (x1 >> (32 - d)); x1 ^= x0; }
  TFR(13) TFR(15) TFR(26) TFR(6)
  x0 += k1; x1 += ks2 + 1u;
  TFR(17) TFR(29) TFR(16) TFR(24)
  x0 += ks2; x1 += k0 + 2u;
  TFR(13) TFR(15) TFR(26) TFR(6)
  x0 += k0; x1 += k1 + 3u;
  TFR(17) TFR(29) TFR(16) TFR(24)
  x0 += k1; x1 += ks2 + 4u;
  TFR(13) TFR(15) TFR(26) TFR(6)
  x0 += ks2; x1 += k0 + 5u;
#undef TFR
  o0 = x0; o1 = x1;
}

__device__ inline unsigned long long tf_bits64(uint32_t k0, uint32_t k1, uint32_t i) {
  uint32_t o0, o1;
  tf2x32(k0, k1, 0u, i, o0, o1);
  return ((unsigned long long)o0 << 32) | o1;
}

// active chunk count (device, from tail append counter)
__device__ inline int activeChunks(const int* counters) {
  int m2 = FIXED + counters[2];
  return (m2 + CHUNK - 1) / CHUNK;
}

// ---------------- block primitives ----------------
__device__ inline int block_excl_scan_256(int v, int* lds /*>=5 ints*/, int& total) {
  int lane = threadIdx.x & 63, wid = threadIdx.x >> 6;
  int inc = v;
#pragma unroll
  for (int off = 1; off < 64; off <<= 1) {
    int y = __shfl_up(inc, off, 64);
    if (lane >= off) inc += y;
  }
  if (lane == 63) lds[wid] = inc;
  __syncthreads();
  if (threadIdx.x == 0) {
    int a = 0;
#pragma unroll
    for (int w = 0; w < 4; ++w) { int t = lds[w]; lds[w] = a; a += t; }
    lds[4] = a;
  }
  __syncthreads();
  total = lds[4];
  int res = inc - v + lds[wid];
  __syncthreads();
  return res;
}

// exclusive scan of 4 packed ints across 512 threads; aux >= 36 ints.
__device__ inline void scan512_x4(const int v[4], int ex[4], int tot[4], int* aux) {
  int lane = threadIdx.x & 63, wid = threadIdx.x >> 6;
  int inc[4];
#pragma unroll
  for (int j = 0; j < 4; ++j) inc[j] = v[j];
#pragma unroll
  for (int off = 1; off < 64; off <<= 1) {
#pragma unroll
    for (int j = 0; j < 4; ++j) {
      int y = __shfl_up(inc[j], off, 64);
      if (lane >= off) inc[j] += y;
    }
  }
  if (lane == 63) {
#pragma unroll
    for (int j = 0; j < 4; ++j) aux[j * 8 + wid] = inc[j];
  }
  __syncthreads();
  if (threadIdx.x == 0) {
#pragma unroll
    for (int j = 0; j < 4; ++j) {
      int a = 0;
#pragma unroll
      for (int w = 0; w < 8; ++w) { int t = aux[j * 8 + w]; aux[j * 8 + w] = a; a += t; }
      aux[32 + j] = a;
    }
  }
  __syncthreads();
#pragma unroll
  for (int j = 0; j < 4; ++j) {
    ex[j] = inc[j] - v[j] + aux[j * 8 + wid];
    tot[j] = aux[32 + j];
  }
}

__device__ inline int scan512_1(int v, int* aux /*>=9 ints*/) {
  int lane = threadIdx.x & 63, wid = threadIdx.x >> 6;
  int inc = v;
#pragma unroll
  for (int off = 1; off < 64; off <<= 1) {
    int y = __shfl_up(inc, off, 64);
    if (lane >= off) inc += y;
  }
  if (lane == 63) aux[wid] = inc;
  __syncthreads();
  if (threadIdx.x == 0) {
    int a = 0;
#pragma unroll
    for (int w = 0; w < 8; ++w) { int t = aux[w]; aux[w] = a; a += t; }
  }
  __syncthreads();
  return inc - v + aux[wid];
}

// LDS swizzle: rotate within 16-element rows to break 16-stride bank aliasing
__device__ inline int phys16(int p) { return (p & ~15) | ((p + (p >> 4)) & 15); }

// ---------------- BFS / enc kernels (fused) ----------------
__global__ __launch_bounds__(256) void k_seed(const int* seeds, uint8_t* frontier, uint8_t* masked) {
  int i = blockIdx.x * 256 + threadIdx.x;
  if (i < NSEED) { int v = seeds[i]; frontier[v] = 1; masked[v] = 1; }
}

// bfs hop 0 + rows/cols output copy
__global__ __launch_bounds__(256) void k_bfs0(const int* rows, const int* cols,
                                              const uint8_t* frontier, uint8_t* alive, uint8_t* nxt,
                                              float* out) {
  int e = blockIdx.x * 256 + threadIdx.x;
  int r = rows[e], c = cols[e];
  out[e] = (float)r;
  out[EDGES + e] = (float)c;
  if (frontier[r] | frontier[c]) { alive[e] = 0; nxt[r] = 1; nxt[c] = 1; }
}

__global__ __launch_bounds__(256) void k_masked_or(uint8_t* masked, const uint8_t* nxt) {
  int v = blockIdx.x * 256 + threadIdx.x;
  if (v < NNODE) masked[v] |= nxt[v];
}

// bfs hop 1 + degree accumulation on the final alive set
__global__ __launch_bounds__(256) void k_bfs1deg(const int* rows, const int* cols,
                                                 const uint8_t* nxt, uint8_t* alive, float* deg) {
  int e = blockIdx.x * 256 + threadIdx.x;
  int r = rows[e];
  int a = alive[e];
  if (a && (nxt[r] | nxt[cols[e]])) { alive[e] = 0; a = 0; }
  if (a) atomicAdd(&deg[r], 1.0f);
}

__global__ __launch_bounds__(256) void k_sample(uint8_t* masked,
                                                uint32_t a0, uint32_t a1, uint32_t b0, uint32_t b1) {
  int i = blockIdx.x * 256 + threadIdx.x;
  if (i >= NSAMP) return;
  unsigned long long hi = tf_bits64(a0, a1, (uint32_t)i);
  unsigned long long lo = tf_bits64(b0, b1, (uint32_t)i);
  unsigned long long off = ((hi % SPAN) * MULTK + (lo % SPAN)) % SPAN;
  masked[off] = 1;
}

__global__ __launch_bounds__(256) void k_dnorm(const float* deg, float* dnorm) {
  int v = blockIdx.x * 256 + threadIdx.x;
  if (v < NNODE) {
    float x = deg[v] + 1e-12f;
    dnorm[v] = (float)(1.0 / sqrt((double)x));
  }
}

// encoder values + compacted tail-hash append.
// 2048 edges/block -> 1954 block-level atomics (same-address atomic service
// rate ~12ns was R4's 187us bottleneck at 15625 atomics).
__global__ __launch_bounds__(256) void k_enctail(const int* rows, const int* cols,
                                                 const uint8_t* alive, const float* dnorm,
                                                 float* out, unsigned long long* A, int* counters) {
  __shared__ int lds[8];
  __shared__ unsigned long long stage[EBLK];
  __shared__ int sbase;
  int base = blockIdx.x * EBLK;
  unsigned long long vv[8];
  int emit[8], c = 0;
#pragma unroll
  for (int k = 0; k < 8; ++k) {
    int e = base + k * 256 + threadIdx.x;
    emit[k] = 0;
    if (e < EDGES) {
      int r = rows[e], cc = cols[e];
      int a = alive[e];
      out[2 * EDGES + e] = a ? dnorm[r] * dnorm[cc] : 0.0f;
      unsigned long long v = (unsigned long long)((long long)r * 150000LL + cc);
      if (a && v) { emit[k] = 1; vv[k] = v; c++; }
    }
  }
  int total;
  int ex = block_excl_scan_256(c, lds, total);
#pragma unroll
  for (int k = 0; k < 8; ++k) {
    if (emit[k]) stage[ex++] = vv[k];
  }
  if (threadIdx.x == 0) sbase = total ? atomicAdd(&counters[2], total) : 0;
  __syncthreads();
  int sb = sbase;
  for (int i = threadIdx.x; i < total; i += 256)
    A[(size_t)FIXED + sb + i] = stage[i];
}

// ---------------- masked-node compaction ----------------
__global__ __launch_bounds__(256) void k_mreduce(const uint8_t* masked, int* mPart) {
  __shared__ int lds[4];
  int base = blockIdx.x * MTILE;
  int s = 0;
  for (int i = threadIdx.x; i < MTILE; i += 256) {
    int idx = base + i;
    if (idx < NNODE) s += masked[idx];
  }
#pragma unroll
  for (int off = 32; off; off >>= 1) s += __shfl_down(s, off, 64);
  if ((threadIdx.x & 63) == 0) lds[threadIdx.x >> 6] = s;
  __syncthreads();
  if (threadIdx.x == 0) mPart[blockIdx.x] = lds[0] + lds[1] + lds[2] + lds[3];
}

__global__ __launch_bounds__(1024) void k_scan_small(int* part, int m, int* totalOut) {
  __shared__ int a[2048];
  int tid = threadIdx.x;
  a[tid] = (tid < m) ? part[tid] : 0;
  a[tid + 1024] = (tid + 1024 < m) ? part[tid + 1024] : 0;
  __syncthreads();
  for (int off = 1; off < 2048; off <<= 1) {
    int v1 = 0, v2;
    if (tid >= off) v1 = a[tid - off];
    v2 = a[tid + 1024 - off];
    __syncthreads();
    if (tid >= off) a[tid] += v1;
    a[tid + 1024] += v2;
    __syncthreads();
  }
  if (tid < m) part[tid] = (tid == 0) ? 0 : a[tid - 1];
  if (tid + 1024 < m) part[tid + 1024] = a[tid + 1023];
  if (tid == 0 && totalOut) *totalOut = a[2047];
}

__global__ __launch_bounds__(256) void k_mscatter(const uint8_t* masked, const int* mPart, int* mlist) {
  __shared__ int lds[8];
  int t0 = blockIdx.x * MTILE + threadIdx.x * 8;
  int c = 0;
#pragma unroll
  for (int k = 0; k < 8; ++k) { int idx = t0 + k; c += (idx < NNODE) ? masked[idx] : 0; }
  int total;
  int ex = block_excl_scan_256(c, lds, total);
  int run = mPart[blockIdx.x] + ex;
#pragma unroll
  for (int k = 0; k < 8; ++k) {
    int idx = t0 + k;
    if (idx < NNODE && masked[idx]) mlist[run++] = idx;
  }
}

// ---------------- hash building ----------------
// dead / zero hashes are written as 0 (not SENTK): zeros sort to the front,
// are never counted as uniques (prev inits to 0; hash 0 is handled by the +1).
__global__ __launch_bounds__(256) void k_build_pairs(const int* mlist, const int* counters,
                                                     unsigned long long* A,
                                                     uint32_t r0, uint32_t r1, uint32_t c0, uint32_t c1) {
  int e = blockIdx.x * 256 + threadIdx.x;
  long long tem = counters[1];
  unsigned long long bits = tf_bits64(r0, r1, (uint32_t)e);
  double u1 = __longlong_as_double((long long)((bits >> 12) | 0x3FF0000000000000ULL)) - 1.0;
  long long i1 = (long long)(u1 * (double)tem); if (i1 > tem - 1) i1 = tem - 1;
  bits = tf_bits64(c0, c1, (uint32_t)e);
  double u2 = __longlong_as_double((long long)((bits >> 12) | 0x3FF0000000000000ULL)) - 1.0;
  long long i2 = (long long)(u2 * (double)tem); if (i2 > tem - 1) i2 = tem - 1;
  long long tr = mlist[i1], tc = mlist[i2];
  A[2 * (size_t)e]     = (unsigned long long)(tr * 150000LL + tc);
  A[2 * (size_t)e + 1] = (unsigned long long)(tc * 150000LL + tr);
}

__global__ __launch_bounds__(256) void k_build_self(unsigned long long* A) {
  int v = blockIdx.x * 256 + threadIdx.x;
  if (v >= NNODE) return;
  A[2 * (size_t)EDGES + v] = (unsigned long long)v * 150001ULL;   // v=0 -> 0, fine
}

// pad [m2, AC*CHUNK) with sentinels (< CHUNK elements)
__global__ __launch_bounds__(256) void k_pad(unsigned long long* A, const int* counters) {
  int m2 = FIXED + counters[2];
  int ac = (m2 + CHUNK - 1) / CHUNK;
  size_t idx = (size_t)m2 + blockIdx.x * 256 + threadIdx.x;
  if (idx < (size_t)ac * CHUNK) A[idx] = SENTK;
}

// ---------------- LSD radix sort: 4 passes x 9 bits, 8192-key chunks ----------------
__global__ __launch_bounds__(TH) void k_rhist2(const unsigned long long* __restrict__ src,
                                               int* __restrict__ hist, int shift,
                                               const int* counters) {
  __shared__ int h8[RADIX * 4];
  int tid = threadIdx.x;
  int ac = activeChunks(counters);
  if ((int)blockIdx.x >= ac) { hist[(size_t)tid * NC + blockIdx.x] = 0; return; }
  for (int i = tid; i < RADIX * 4; i += TH) h8[i] = 0;
  __syncthreads();
  const ulonglong2* s2 = (const ulonglong2*)(src + (size_t)blockIdx.x * CHUNK);
  int rep = tid & 3, scnt = 0;
#pragma unroll
  for (int r = 0; r < 8; ++r) {
    ulonglong2 v = s2[tid + r * TH];
    int d0 = (int)((v.x >> shift) & (RADIX - 1));
    int d1 = (int)((v.y >> shift) & (RADIX - 1));
    if (d0 == RADIX - 1) scnt++; else atomicAdd(&h8[d0 * 4 + rep], 1);
    if (d1 == RADIX - 1) scnt++; else atomicAdd(&h8[d1 * 4 + rep], 1);
  }
  if (scnt) atomicAdd(&h8[(RADIX - 1) * 4 + rep], scnt);
  __syncthreads();
  int4 hv = *(const int4*)&h8[tid * 4];
  hist[(size_t)tid * NC + blockIdx.x] = hv.x + hv.y + hv.z + hv.w;
}

__global__ __launch_bounds__(256) void k_scan_reduce(const int* g, int* part, int n) {
  __shared__ int lds[4];
  int base = blockIdx.x * 2048;
  int s = 0;
  for (int i = threadIdx.x; i < 2048; i += 256) {
    int idx = base + i;
    if (idx < n) s += g[idx];
  }
#pragma unroll
  for (int off = 32; off; off >>= 1) s += __shfl_down(s, off, 64);
  if ((threadIdx.x & 63) == 0) lds[threadIdx.x >> 6] = s;
  __syncthreads();
  if (threadIdx.x == 0) part[blockIdx.x] = lds[0] + lds[1] + lds[2] + lds[3];
}

__global__ __launch_bounds__(256) void k_scan_apply(int* g, const int* part, int n) {
  __shared__ int lds[8];
  int t0 = blockIdx.x * 2048 + threadIdx.x * 8;
  int x[8];
#pragma unroll
  for (int k = 0; k < 8; ++k) { int idx = t0 + k; x[k] = (idx < n) ? g[idx] : 0; }
  int s = 0;
#pragma unroll
  for (int k = 0; k < 8; ++k) { int t = x[k]; x[k] = s; s += t; }
  int total;
  int ex = block_excl_scan_256(s, lds, total);
  int add = part[blockIdx.x] + ex;
#pragma unroll
  for (int k = 0; k < 8; ++k) { int idx = t0 + k; if (idx < n) g[idx] = x[k] + add; }
}

// STABLE scatter (required for LSD): 3x3-bit in-LDS split rounds sort the
// tile by the 9-bit digit while preserving intra-digit (= prior-pass) order,
// then a direct-addressed coalesced write per digit segment.
// R7: per-key ranking uses packed bit-field counters (8x8-bit u64) and packed
// start positions (2x u64, 4x16-bit fields) instead of 8-way compare chains.
__global__ __launch_bounds__(TH) void k_rscatter2(const unsigned long long* __restrict__ src,
                                                  unsigned long long* __restrict__ dst,
                                                  const int* __restrict__ hist, int shift,
                                                  const int* counters) {
  __shared__ uint32_t klo[CHUNK], khi[CHUNK];
  __shared__ int h8[RADIX * 4];
  __shared__ int dstart[RADIX], gbase[RADIX];
  __shared__ int aux[40];
  int tid = threadIdx.x;
  // XCD-contiguous chunk swizzle: adjacent chunks on the same XCD, temporally adjacent
  int chunk = (blockIdx.x & 7) * NCX + (blockIdx.x >> 3);
  int ac = activeChunks(counters);
  if (chunk >= ac) return;
  size_t cbase = (size_t)chunk * CHUNK;
  gbase[tid] = hist[(size_t)tid * NC + chunk];
  for (int i = tid; i < RADIX * 4; i += TH) h8[i] = 0;
  __syncthreads();
  int rep = tid & 3;
  const ulonglong2* s2 = (const ulonglong2*)(src + cbase);
  int scnt = 0;
#pragma unroll
  for (int r = 0; r < 8; ++r) {
    ulonglong2 v = s2[tid + r * TH];
    int i = 2 * (tid + r * TH);
    int p0 = phys16(i), p1 = phys16(i + 1);
    klo[p0] = (uint32_t)v.x; khi[p0] = (uint32_t)(v.x >> 32);
    klo[p1] = (uint32_t)v.y; khi[p1] = (uint32_t)(v.y >> 32);
    int d0 = (int)((v.x >> shift) & (RADIX - 1));
    int d1 = (int)((v.y >> shift) & (RADIX - 1));
    if (d0 == RADIX - 1) scnt++; else atomicAdd(&h8[d0 * 4 + rep], 1);
    if (d1 == RADIX - 1) scnt++; else atomicAdd(&h8[d1 * 4 + rep], 1);
  }
  if (scnt) atomicAdd(&h8[(RADIX - 1) * 4 + rep], scnt);
  __syncthreads();
  int4 hv = *(const int4*)&h8[tid * 4];
  int h = hv.x + hv.y + hv.z + hv.w;
  int ex0 = scan512_1(h, aux);
  dstart[tid] = ex0;
  __syncthreads();
  // 3 x 3-bit stable split rounds -> tile sorted by 9-bit digit
  int t0 = tid * 16;
  for (int rr = 0; rr < 3; ++rr) {
    int sh = shift + 3 * rr;
    unsigned long long key[16];
    unsigned long long cpack = 0;               // 8 x 8-bit digit counters
#pragma unroll
    for (int k = 0; k < 16; ++k) {
      int p = phys16(t0 + k);
      key[k] = ((unsigned long long)khi[p] << 32) | klo[p];
      cpack += 1ULL << (((int)(key[k] >> sh) & 7) << 3);
    }
    int v4[4], ex[4], tot[4];
#pragma unroll
    for (int j = 0; j < 4; ++j) {
      unsigned pair = (unsigned)(cpack >> (16 * j));
      v4[j] = (int)((pair & 0xffu) | ((pair & 0xff00u) << 8));
    }
    scan512_x4(v4, ex, tot, aux);   // internal barriers also order reads-before-writes
    unsigned long long startq0, startq1;        // 8 start positions, 4x16-bit each
    {
      int a = 0, s8[8];
#pragma unroll
      for (int j = 0; j < 4; ++j) {
        int tlo = tot[j] & 0xffff, thi = tot[j] >> 16;
        int elo = ex[j] & 0xffff,  ehi = ex[j] >> 16;
        s8[2 * j]     = a + elo; a += tlo;
        s8[2 * j + 1] = a + ehi; a += thi;
      }
      startq0 = (unsigned long long)(unsigned)s8[0]
              | ((unsigned long long)(unsigned)s8[1] << 16)
              | ((unsigned long long)(unsigned)s8[2] << 32)
              | ((unsigned long long)(unsigned)s8[3] << 48);
      startq1 = (unsigned long long)(unsigned)s8[4]
              | ((unsigned long long)(unsigned)s8[5] << 16)
              | ((unsigned long long)(unsigned)s8[6] << 32)
              | ((unsigned long long)(unsigned)s8[7] << 48);
    }
#pragma unroll
    for (int k = 0; k < 16; ++k) {
      int d = (int)(key[k] >> sh) & 7;
      int fs = (d & 3) << 4;
      unsigned long long inc = 1ULL << fs;
      int pos;
      if (d < 4) { pos = (int)((startq0 >> fs) & 0xffffu); startq0 += inc; }
      else       { pos = (int)((startq1 >> fs) & 0xffffu); startq1 += inc; }
      int p = phys16(pos);
      klo[p] = (uint32_t)key[k]; khi[p] = (uint32_t)(key[k] >> 32);
    }
    __syncthreads();
  }
  // direct-addressed scatter: read back in sorted order
#pragma unroll
  for (int r = 0; r < 16; ++r) {
    int i = tid + r * TH;
    int p = phys16(i);
    unsigned long long k1 = ((unsigned long long)khi[p] << 32) | klo[p];
    int d = (int)((k1 >> shift) & (RADIX - 1));
    dst[(size_t)(gbase[d] + (i - dstart[d]))] = k1;
  }
}

// ---------------- unique + final decoder write ----------------
__global__ __launch_bounds__(TH) void k_uniq_count(const unsigned long long* A, int* uPart,
                                                   const int* counters) {
  __shared__ int lds[8];
  int ac = activeChunks(counters);
  if ((int)blockIdx.x >= ac) { if (threadIdx.x == 0) uPart[blockIdx.x] = 0; return; }
  size_t base = (size_t)blockIdx.x * CHUNK + (size_t)threadIdx.x * 16;
  unsigned long long prev = (base == 0) ? 0ULL : A[base - 1];
  int c = 0;
#pragma unroll
  for (int k = 0; k < 16; ++k) {
    unsigned long long v = A[base + k];
    c += (v != SENTK && v != prev) ? 1 : 0;
    prev = v;
  }
#pragma unroll
  for (int off = 32; off; off >>= 1) c += __shfl_down(c, off, 64);
  if ((threadIdx.x & 63) == 0) lds[threadIdx.x >> 6] = c;
  __syncthreads();
  if (threadIdx.x == 0) {
    int s = 0;
#pragma unroll
    for (int w = 0; w < 8; ++w) s += lds[w];
    uPart[blockIdx.x] = s;
  }
}

// compact uniques via LDS staging, then dense coalesced writes (no RMW thrash)
__global__ __launch_bounds__(TH) void k_final(const unsigned long long* A, const int* uPart,
                                              const int* counters, float* out) {
  __shared__ int aux[9];
  __shared__ float sq[CHUNK], sr[CHUNK];
  __shared__ int scnt;
  int ac = activeChunks(counters);
  if ((int)blockIdx.x >= ac) return;
  size_t base = (size_t)blockIdx.x * CHUNK + (size_t)threadIdx.x * 16;
  unsigned long long v[16];
  int f[16], c = 0;
  unsigned long long prev = (base == 0) ? 0ULL : A[base - 1];
#pragma unroll
  for (int k = 0; k < 16; ++k) {
    v[k] = A[base + k];
    f[k] = (v[k] != SENTK && v[k] != prev) ? 1 : 0;
    c += f[k];
    prev = v[k];
  }
  int ex = scan512_1(c, aux);
  if (threadIdx.x == TH - 1) scnt = ex + c;
  int j = ex;
#pragma unroll
  for (int k = 0; k < 16; ++k) {
    if (f[k]) {
      unsigned long long val = v[k];
      long long q = (long long)((double)val * (1.0 / 150000.0));
      long long r = (long long)val - q * 150000LL;
      if (r < 0) { q--; r += 150000LL; }
      else if (r >= 150000LL) { q++; r -= 150000LL; }
      sq[j] = (float)q; sr[j] = (float)r; j++;
    }
  }
  __syncthreads();
  int cnt = scnt;
  int jb = 1 + uPart[blockIdx.x];   // +1: slot 0 is the always-present hash 0
  for (int i = (int)threadIdx.x; i < cnt; i += TH) {
    out[OUT_DR + jb + i] = sq[i];
    out[OUT_DC + jb + i] = sr[i];
  }
}

// dec_vals fill (1.0 below totU, 0 after) + zero tails of dec_rows/cols + slot 0
__global__ __launch_bounds__(256) void k_dectail(const int* counters, float* out) {
  int i = (blockIdx.x * 256 + threadIdx.x) * 4;
  if (i >= MOUT) return;
  int totU = counters[3] + 1;
  float4 dv;
  dv.x = (i + 0 < totU) ? 1.0f : 0.0f;
  dv.y = (i + 1 < totU) ? 1.0f : 0.0f;
  dv.z = (i + 2 < totU) ? 1.0f : 0.0f;
  dv.w = (i + 3 < totU) ? 1.0f : 0.0f;
  *(float4*)&out[OUT_DV + i] = dv;
  if (i + 3 >= totU) {
    float4 z = make_float4(0.0f, 0.0f, 0.0f, 0.0f);
    if (i >= totU) {
      *(float4*)&out[OUT_DR + i] = z;
      *(float4*)&out[OUT_DC + i] = z;
    } else {
#pragma unroll
      for (int k = 0; k < 4; ++k)
        if (i + k >= totU) { out[OUT_DR + i + k] = 0.0f; out[OUT_DC + i + k] = 0.0f; }
    }
  }
  if (i == 0) { out[OUT_DR] = 0.0f; out[OUT_DC] = 0.0f; }
}

// ---------------- host launcher ----------------
extern "C" void kernel_launch(void* const* d_in, const int* in_sizes, int n_in,
                              void* d_out, int out_size, void* d_ws, size_t ws_size,
                              hipStream_t stream) {
  const int* rows = (const int*)d_in[1];   // d_in[0]=adj_vals (unused by reference outputs)
  const int* cols = (const int*)d_in[2];
  const int* seeds = (const int*)d_in[3];
  float* out = (float*)d_out;

  // workspace layout
  char* ws = (char*)d_ws;
  size_t off = 0;
  auto alloc = [&](size_t bytes) -> char* {
    char* p = ws + off;
    off += (bytes + 255) & ~(size_t)255;
    return p;
  };
  unsigned long long* A = (unsigned long long*)alloc(MP * 8);
  uint8_t* alive = (uint8_t*)alloc(EDGES);
  char* zbase = ws + off;                       // ---- zeroed zone ----
  uint8_t* frontier = (uint8_t*)alloc(NNODE);
  uint8_t* nextf = (uint8_t*)alloc(NNODE);
  uint8_t* masked = (uint8_t*)alloc(NNODE);
  float* deg = (float*)alloc((size_t)NNODE * 4);
  int* counters = (int*)alloc(256 * 4);         // [1]=tem_num [2]=tailCnt [3]=uniqSum
  size_t zsize = (size_t)((ws + off) - zbase);  // ---- end zeroed zone ----
  float* dnorm = (float*)alloc((size_t)NNODE * 4);
  int* mlist = (int*)alloc((size_t)NNODE * 4);
  int* hist = (int*)alloc((size_t)NHIST * 4);
  int* spart = (int*)alloc(2048 * 4);
  int* uPart = (int*)alloc(2048 * 4);
  int* mPart = (int*)alloc(256 * 4);

  // radix ping-pong buffer B lives in the (later-overwritten) dec region of d_out
  unsigned long long* Bbuf = (unsigned long long*)(out + OUT_DR);

  // JAX key derivation (threefry_partitionable semantics)
  uint32_t ks0, ks1, kr0, kr1, kc0, kc1, s10, s11, s20, s21;
  tf2x32(0u, 42u, 0u, 0u, ks0, ks1);
  tf2x32(0u, 42u, 0u, 1u, kr0, kr1);
  tf2x32(0u, 42u, 0u, 2u, kc0, kc1);
  tf2x32(ks0, ks1, 0u, 0u, s10, s11);
  tf2x32(ks0, ks1, 0u, 1u, s20, s21);

  hipMemsetAsync(zbase, 0, zsize, stream);
  hipMemsetAsync(alive, 1, EDGES, stream);

  const int EB = EDGES / 256;                // 15625
  const int NB = (NNODE + 255) / 256;        // 586

  k_seed<<<2, 256, 0, stream>>>(seeds, frontier, masked);
  k_bfs0<<<EB, 256, 0, stream>>>(rows, cols, frontier, alive, nextf, out);
  k_masked_or<<<NB, 256, 0, stream>>>(masked, nextf);
  k_bfs1deg<<<EB, 256, 0, stream>>>(rows, cols, nextf, alive, deg);
  k_sample<<<(NSAMP + 255) / 256, 256, 0, stream>>>(masked, s10, s11, s20, s21);
  k_dnorm<<<NB, 256, 0, stream>>>(deg, dnorm);
  k_enctail<<<ENB, 256, 0, stream>>>(rows, cols, alive, dnorm, out, A, counters);

  // masked node list (ascending) + tem_num
  k_mreduce<<<MB, 256, 0, stream>>>(masked, mPart);
  k_scan_small<<<1, 1024, 0, stream>>>(mPart, MB, counters + 1);
  k_mscatter<<<MB, 256, 0, stream>>>(masked, mPart, mlist);

  // pairs + self loops at fixed slots; tail already appended compacted
  k_build_pairs<<<EB, 256, 0, stream>>>(mlist, counters, A, kr0, kr1, kc0, kc1);
  k_build_self<<<NB, 256, 0, stream>>>(A);
  k_pad<<<CHUNK / 256, 256, 0, stream>>>(A, counters);

  // radix sort: A -> B -> A -> B -> A (4 passes x 9 bits over active chunks)
  unsigned long long* src = A;
  unsigned long long* dst = Bbuf;
  const int shifts[4] = {0, 9, 18, 27};
  for (int p = 0; p < 4; ++p) {
    k_rhist2<<<NC, TH, 0, stream>>>(src, hist, shifts[p], counters);
    k_scan_reduce<<<SCB, 256, 0, stream>>>(hist, spart, NHIST);
    k_scan_small<<<1, 1024, 0, stream>>>(spart, SCB, nullptr);
    k_scan_apply<<<SCB, 256, 0, stream>>>(hist, spart, NHIST);
    k_rscatter2<<<NC, TH, 0, stream>>>(src, dst, hist, shifts[p], counters);
    unsigned long long* t = src; src = dst; dst = t;
  }
  // sorted result now in A (src == A)

  k_uniq_count<<<NTILE, TH, 0, stream>>>(src, uPart, counters);
  k_scan_small<<<1, 1024, 0, stream>>>(uPart, NTILE, counters + 3);
  k_final<<<NTILE, TH, 0, stream>>>(src, uPart, counters, out);
  k_dectail<<<(MOUT / 4 + 255) / 256, 256, 0, stream>>>(counters, out);
}

// Round 8
// 1001.300 us; speedup vs baseline: 2.7180x; 1.0473x over previous
//
#include <hip/hip_runtime.h>
#include <stdint.h>

// ---------------- problem constants ----------------
#define NNODE   150000
#define NNODE16 150016             // padded stride for deg copies
#define EDGES   4000000
#define NSEED   500
#define NSAMP   15000              // int(150000 * 0.1)
#define MOUT    12150000           // 3E + N : decoder output length
#define SENTK   0xFFFFFFFFFFFFFFFFULL
#define SPAN    150000ULL
#define MULTK   51616ULL           // ((2^32 % 150000)^2) % 150000
#define FIXED   8150000            // pairs (8M) + self loops (150k) fixed slots

// sort geometry: 8192-key chunks, one tile per block.
// NOTE (R5 post-mortem): LSD radix REQUIRES a stable per-pass scatter — the
// in-LDS 3x3-bit split below is what preserves lower-digit order across
// passes. Do not replace with atomic-rank placement.
#define CHUNK   8192
#define TH      512
#define NC      1488               // max chunks; multiple of 8 for XCD swizzle
#define NCX     (NC / 8)           // 186
#define MP      ((size_t)NC * CHUNK)
#define RADIX   512
#define NHIST   (RADIX * NC)       // 761,856
#define SCB     (NHIST / 2048)     // 372 (exact)
#define NTILE   NC                 // uniq/final tiles == chunks

// enctail geometry
#define EBLK    2048
#define ENB     ((EDGES + EBLK - 1) / EBLK)   // 1954

// vectorized edge-pass geometry (4 edges/thread)
#define VNB     ((EDGES + 1023) / 1024)       // 3907

// masked-node compaction geometry
#define MTILE   2048
#define MB      ((NNODE + MTILE - 1) / MTILE)   // 74

// out layout (float32): [rows E][cols E][enc E][dec_rows M][dec_cols M][dec_vals M]
#define OUT_DR  12000000
#define OUT_DC  24150000
#define OUT_DV  36300000

// ---------------- threefry2x32 (JAX-exact, 20 rounds) ----------------
__host__ __device__ inline void tf2x32(uint32_t k0, uint32_t k1,
                                       uint32_t x0, uint32_t x1,
                                       uint32_t& o0, uint32_t& o1) {
  uint32_t ks2 = k0 ^ k1 ^ 0x1BD11BDAu;
  x0 += k0; x1 += k1;
#define TFR(d) { x0 += x1; x1 = (x1 << d) | (x1 >> (32 - d)); x1 ^= x0; }
  TFR(13) TFR(15) TFR(26) TFR(6)
  x0 += k1; x1 += ks2 + 1u;
  TFR(17) TFR(29) TFR(16) TFR(24)
  x0 += ks2; x1 += k0 + 2u;
  TFR(13) TFR(15) TFR(26) TFR(6)
  x0 += k0; x1 += k1 + 3u;
  TFR(17) TFR(29) TFR(16) TFR(24)
  x0 += k1; x1 += ks2 + 4u;
  TFR(13) TFR(15) TFR(26) TFR(6)
  x0 += ks2; x1 += k0 + 5u;
#undef TFR
  o0 = x0; o1 = x1;
}

__device__ inline unsigned long long tf_bits64(uint32_t k0, uint32_t k1, uint32_t i) {
  uint32_t o0, o1;
  tf2x32(k0, k1, 0u, i, o0, o1);
  return ((unsigned long long)o0 << 32) | o1;
}

// active chunk count (device, from tail append counter)
__device__ inline int activeChunks(const int* counters) {
  int m2 = FIXED + counters[2];
  return (m2 + CHUNK - 1) / CHUNK;
}

// ---------------- block primitives ----------------
__device__ inline int block_excl_scan_256(int v, int* lds /*>=5 ints*/, int& total) {
  int lane = threadIdx.x & 63, wid = threadIdx.x >> 6;
  int inc = v;
#pragma unroll
  for (int off = 1; off < 64; off <<= 1) {
    int y = __shfl_up(inc, off, 64);
    if (lane >= off) inc += y;
  }
  if (lane == 63) lds[wid] = inc;
  __syncthreads();
  if (threadIdx.x == 0) {
    int a = 0;
#pragma unroll
    for (int w = 0; w < 4; ++w) { int t = lds[w]; lds[w] = a; a += t; }
    lds[4] = a;
  }
  __syncthreads();
  total = lds[4];
  int res = inc - v + lds[wid];
  __syncthreads();
  return res;
}

// exclusive scan of 4 packed ints across 512 threads; aux >= 36 ints.
__device__ inline void scan512_x4(const int v[4], int ex[4], int tot[4], int* aux) {
  int lane = threadIdx.x & 63, wid = threadIdx.x >> 6;
  int inc[4];
#pragma unroll
  for (int j = 0; j < 4; ++j) inc[j] = v[j];
#pragma unroll
  for (int off = 1; off < 64; off <<= 1) {
#pragma unroll
    for (int j = 0; j < 4; ++j) {
      int y = __shfl_up(inc[j], off, 64);
      if (lane >= off) inc[j] += y;
    }
  }
  if (lane == 63) {
#pragma unroll
    for (int j = 0; j < 4; ++j) aux[j * 8 + wid] = inc[j];
  }
  __syncthreads();
  if (threadIdx.x == 0) {
#pragma unroll
    for (int j = 0; j < 4; ++j) {
      int a = 0;
#pragma unroll
      for (int w = 0; w < 8; ++w) { int t = aux[j * 8 + w]; aux[j * 8 + w] = a; a += t; }
      aux[32 + j] = a;
    }
  }
  __syncthreads();
#pragma unroll
  for (int j = 0; j < 4; ++j) {
    ex[j] = inc[j] - v[j] + aux[j * 8 + wid];
    tot[j] = aux[32 + j];
  }
}

__device__ inline int scan512_1(int v, int* aux /*>=9 ints*/) {
  int lane = threadIdx.x & 63, wid = threadIdx.x >> 6;
  int inc = v;
#pragma unroll
  for (int off = 1; off < 64; off <<= 1) {
    int y = __shfl_up(inc, off, 64);
    if (lane >= off) inc += y;
  }
  if (lane == 63) aux[wid] = inc;
  __syncthreads();
  if (threadIdx.x == 0) {
    int a = 0;
#pragma unroll
    for (int w = 0; w < 8; ++w) { int t = aux[w]; aux[w] = a; a += t; }
  }
  __syncthreads();
  return inc - v + aux[wid];
}

// LDS swizzle: rotate within 16-element rows to break 16-stride bank aliasing
__device__ inline int phys16(int p) { return (p & ~15) | ((p + (p >> 4)) & 15); }

// ---------------- BFS / enc kernels (fused) ----------------
__global__ __launch_bounds__(256) void k_seed(const int* seeds, uint8_t* frontier, uint8_t* masked) {
  int i = blockIdx.x * 256 + threadIdx.x;
  if (i < NSEED) { int v = seeds[i]; frontier[v] = 1; masked[v] = 1; }
}

// bfs hop 0 + rows/cols output copy; 4 edges/thread (MLP for the gathers).
// Writes alive[] fully (memset removed).
__global__ __launch_bounds__(256) void k_bfs0(const int* rows, const int* cols,
                                              const uint8_t* frontier, uint8_t* alive, uint8_t* nxt,
                                              float* out) {
  int g = blockIdx.x * 1024 + threadIdx.x * 4;
  if (g >= EDGES) return;
  if (g + 4 <= EDGES) {
    int4 r4 = *(const int4*)&rows[g];
    int4 c4 = *(const int4*)&cols[g];
    int rr[4] = {r4.x, r4.y, r4.z, r4.w};
    int cc[4] = {c4.x, c4.y, c4.z, c4.w};
    *(float4*)&out[g] = make_float4((float)rr[0], (float)rr[1], (float)rr[2], (float)rr[3]);
    *(float4*)&out[EDGES + g] = make_float4((float)cc[0], (float)cc[1], (float)cc[2], (float)cc[3]);
    uint8_t al[4];
#pragma unroll
    for (int k = 0; k < 4; ++k) {
      int hit = frontier[rr[k]] | frontier[cc[k]];
      al[k] = (uint8_t)(1 - hit);
      if (hit) { nxt[rr[k]] = 1; nxt[cc[k]] = 1; }
    }
    *(uchar4*)&alive[g] = make_uchar4(al[0], al[1], al[2], al[3]);
  } else {
    for (int e = g; e < EDGES; ++e) {
      int r = rows[e], c = cols[e];
      out[e] = (float)r;
      out[EDGES + e] = (float)c;
      int hit = frontier[r] | frontier[c];
      alive[e] = (uint8_t)(1 - hit);
      if (hit) { nxt[r] = 1; nxt[c] = 1; }
    }
  }
}

__global__ __launch_bounds__(256) void k_masked_or(uint8_t* masked, const uint8_t* nxt) {
  int v = blockIdx.x * 256 + threadIdx.x;
  if (v < NNODE) masked[v] |= nxt[v];
}

// bfs hop 1 + degree accumulation; deg privatized 8x by blockIdx&7 to cut
// per-cacheline atomic serialization ~8x (R7: 148us at 1.2% VALU / 9% HBM).
__global__ __launch_bounds__(256) void k_bfs1deg(const int* rows, const int* cols,
                                                 const uint8_t* nxt, uint8_t* alive, int* deg8) {
  int g = blockIdx.x * 1024 + threadIdx.x * 4;
  if (g >= EDGES) return;
  int* dmy = deg8 + (blockIdx.x & 7) * NNODE16;
  if (g + 4 <= EDGES) {
    int4 r4 = *(const int4*)&rows[g];
    int4 c4 = *(const int4*)&cols[g];
    uchar4 a4 = *(const uchar4*)&alive[g];
    int rr[4] = {r4.x, r4.y, r4.z, r4.w};
    int cc[4] = {c4.x, c4.y, c4.z, c4.w};
    uint8_t aa[4] = {a4.x, a4.y, a4.z, a4.w};
    uint8_t na[4];
#pragma unroll
    for (int k = 0; k < 4; ++k) {
      int a = aa[k];
      if (a && (nxt[rr[k]] | nxt[cc[k]])) a = 0;
      na[k] = (uint8_t)a;
    }
    *(uchar4*)&alive[g] = make_uchar4(na[0], na[1], na[2], na[3]);
#pragma unroll
    for (int k = 0; k < 4; ++k)
      if (na[k]) atomicAdd(&dmy[rr[k]], 1);
  } else {
    for (int e = g; e < EDGES; ++e) {
      int a = alive[e];
      int r = rows[e];
      if (a && (nxt[r] | nxt[cols[e]])) { alive[e] = 0; a = 0; }
      if (a) atomicAdd(&dmy[r], 1);
    }
  }
}

__global__ __launch_bounds__(256) void k_sample(uint8_t* masked,
                                                uint32_t a0, uint32_t a1, uint32_t b0, uint32_t b1) {
  int i = blockIdx.x * 256 + threadIdx.x;
  if (i >= NSAMP) return;
  unsigned long long hi = tf_bits64(a0, a1, (uint32_t)i);
  unsigned long long lo = tf_bits64(b0, b1, (uint32_t)i);
  unsigned long long off = ((hi % SPAN) * MULTK + (lo % SPAN)) % SPAN;
  masked[off] = 1;
}

__global__ __launch_bounds__(256) void k_dnorm(const int* deg8, float* dnorm) {
  int v = blockIdx.x * 256 + threadIdx.x;
  if (v < NNODE) {
    int s = 0;
#pragma unroll
    for (int j = 0; j < 8; ++j) s += deg8[j * NNODE16 + v];
    float x = (float)s + 1e-12f;     // integer-valued sum is exact in f32
    dnorm[v] = (float)(1.0 / sqrt((double)x));
  }
}

// encoder values + compacted tail-hash append.
// 2048 edges/block -> 1954 block-level atomics (same-address atomic service
// rate ~12ns was R4's 187us bottleneck at 15625 atomics).
__global__ __launch_bounds__(256) void k_enctail(const int* rows, const int* cols,
                                                 const uint8_t* alive, const float* dnorm,
                                                 float* out, unsigned long long* A, int* counters) {
  __shared__ int lds[8];
  __shared__ unsigned long long stage[EBLK];
  __shared__ int sbase;
  int base = blockIdx.x * EBLK;
  unsigned long long vv[8];
  int emit[8], c = 0;
#pragma unroll
  for (int k = 0; k < 8; ++k) {
    int e = base + k * 256 + threadIdx.x;
    emit[k] = 0;
    if (e < EDGES) {
      int r = rows[e], cc = cols[e];
      int a = alive[e];
      out[2 * EDGES + e] = a ? dnorm[r] * dnorm[cc] : 0.0f;
      unsigned long long v = (unsigned long long)((long long)r * 150000LL + cc);
      if (a && v) { emit[k] = 1; vv[k] = v; c++; }
    }
  }
  int total;
  int ex = block_excl_scan_256(c, lds, total);
#pragma unroll
  for (int k = 0; k < 8; ++k) {
    if (emit[k]) stage[ex++] = vv[k];
  }
  if (threadIdx.x == 0) sbase = total ? atomicAdd(&counters[2], total) : 0;
  __syncthreads();
  int sb = sbase;
  for (int i = threadIdx.x; i < total; i += 256)
    A[(size_t)FIXED + sb + i] = stage[i];
}

// ---------------- masked-node compaction ----------------
__global__ __launch_bounds__(256) void k_mreduce(const uint8_t* masked, int* mPart) {
  __shared__ int lds[4];
  int base = blockIdx.x * MTILE;
  int s = 0;
  for (int i = threadIdx.x; i < MTILE; i += 256) {
    int idx = base + i;
    if (idx < NNODE) s += masked[idx];
  }
#pragma unroll
  for (int off = 32; off; off >>= 1) s += __shfl_down(s, off, 64);
  if ((threadIdx.x & 63) == 0) lds[threadIdx.x >> 6] = s;
  __syncthreads();
  if (threadIdx.x == 0) mPart[blockIdx.x] = lds[0] + lds[1] + lds[2] + lds[3];
}

__global__ __launch_bounds__(1024) void k_scan_small(int* part, int m, int* totalOut) {
  __shared__ int a[2048];
  int tid = threadIdx.x;
  a[tid] = (tid < m) ? part[tid] : 0;
  a[tid + 1024] = (tid + 1024 < m) ? part[tid + 1024] : 0;
  __syncthreads();
  for (int off = 1; off < 2048; off <<= 1) {
    int v1 = 0, v2;
    if (tid >= off) v1 = a[tid - off];
    v2 = a[tid + 1024 - off];
    __syncthreads();
    if (tid >= off) a[tid] += v1;
    a[tid + 1024] += v2;
    __syncthreads();
  }
  if (tid < m) part[tid] = (tid == 0) ? 0 : a[tid - 1];
  if (tid + 1024 < m) part[tid + 1024] = a[tid + 1023];
  if (tid == 0 && totalOut) *totalOut = a[2047];
}

__global__ __launch_bounds__(256) void k_mscatter(const uint8_t* masked, const int* mPart, int* mlist) {
  __shared__ int lds[8];
  int t0 = blockIdx.x * MTILE + threadIdx.x * 8;
  int c = 0;
#pragma unroll
  for (int k = 0; k < 8; ++k) { int idx = t0 + k; c += (idx < NNODE) ? masked[idx] : 0; }
  int total;
  int ex = block_excl_scan_256(c, lds, total);
  int run = mPart[blockIdx.x] + ex;
#pragma unroll
  for (int k = 0; k < 8; ++k) {
    int idx = t0 + k;
    if (idx < NNODE && masked[idx]) mlist[run++] = idx;
  }
}

// ---------------- hash building ----------------
// dead / zero hashes are written as 0 (not SENTK): zeros sort to the front,
// are never counted as uniques (prev inits to 0; hash 0 is handled by the +1).
__global__ __launch_bounds__(256) void k_build_pairs(const int* mlist, const int* counters,
                                                     unsigned long long* A,
                                                     uint32_t r0, uint32_t r1, uint32_t c0, uint32_t c1) {
  int e = blockIdx.x * 256 + threadIdx.x;
  long long tem = counters[1];
  unsigned long long bits = tf_bits64(r0, r1, (uint32_t)e);
  double u1 = __longlong_as_double((long long)((bits >> 12) | 0x3FF0000000000000ULL)) - 1.0;
  long long i1 = (long long)(u1 * (double)tem); if (i1 > tem - 1) i1 = tem - 1;
  bits = tf_bits64(c0, c1, (uint32_t)e);
  double u2 = __longlong_as_double((long long)((bits >> 12) | 0x3FF0000000000000ULL)) - 1.0;
  long long i2 = (long long)(u2 * (double)tem); if (i2 > tem - 1) i2 = tem - 1;
  long long tr = mlist[i1], tc = mlist[i2];
  A[2 * (size_t)e]     = (unsigned long long)(tr * 150000LL + tc);
  A[2 * (size_t)e + 1] = (unsigned long long)(tc * 150000LL + tr);
}

__global__ __launch_bounds__(256) void k_build_self(unsigned long long* A) {
  int v = blockIdx.x * 256 + threadIdx.x;
  if (v >= NNODE) return;
  A[2 * (size_t)EDGES + v] = (unsigned long long)v * 150001ULL;   // v=0 -> 0, fine
}

// pad [m2, AC*CHUNK) with sentinels (< CHUNK elements)
__global__ __launch_bounds__(256) void k_pad(unsigned long long* A, const int* counters) {
  int m2 = FIXED + counters[2];
  int ac = (m2 + CHUNK - 1) / CHUNK;
  size_t idx = (size_t)m2 + blockIdx.x * 256 + threadIdx.x;
  if (idx < (size_t)ac * CHUNK) A[idx] = SENTK;
}

// ---------------- LSD radix sort: 4 passes x 9 bits, 8192-key chunks ----------------
__global__ __launch_bounds__(TH) void k_rhist2(const unsigned long long* __restrict__ src,
                                               int* __restrict__ hist, int shift,
                                               const int* counters) {
  __shared__ int h8[RADIX * 4];
  int tid = threadIdx.x;
  int ac = activeChunks(counters);
  if ((int)blockIdx.x >= ac) { hist[(size_t)tid * NC + blockIdx.x] = 0; return; }
  for (int i = tid; i < RADIX * 4; i += TH) h8[i] = 0;
  __syncthreads();
  const ulonglong2* s2 = (const ulonglong2*)(src + (size_t)blockIdx.x * CHUNK);
  int rep = tid & 3, scnt = 0;
#pragma unroll
  for (int r = 0; r < 8; ++r) {
    ulonglong2 v = s2[tid + r * TH];
    int d0 = (int)((v.x >> shift) & (RADIX - 1));
    int d1 = (int)((v.y >> shift) & (RADIX - 1));
    if (d0 == RADIX - 1) scnt++; else atomicAdd(&h8[d0 * 4 + rep], 1);
    if (d1 == RADIX - 1) scnt++; else atomicAdd(&h8[d1 * 4 + rep], 1);
  }
  if (scnt) atomicAdd(&h8[(RADIX - 1) * 4 + rep], scnt);
  __syncthreads();
  int4 hv = *(const int4*)&h8[tid * 4];
  hist[(size_t)tid * NC + blockIdx.x] = hv.x + hv.y + hv.z + hv.w;
}

__global__ __launch_bounds__(256) void k_scan_reduce(const int* g, int* part, int n) {
  __shared__ int lds[4];
  int base = blockIdx.x * 2048;
  int s = 0;
  for (int i = threadIdx.x; i < 2048; i += 256) {
    int idx = base + i;
    if (idx < n) s += g[idx];
  }
#pragma unroll
  for (int off = 32; off; off >>= 1) s += __shfl_down(s, off, 64);
  if ((threadIdx.x & 63) == 0) lds[threadIdx.x >> 6] = s;
  __syncthreads();
  if (threadIdx.x == 0) part[blockIdx.x] = lds[0] + lds[1] + lds[2] + lds[3];
}

__global__ __launch_bounds__(256) void k_scan_apply(int* g, const int* part, int n) {
  __shared__ int lds[8];
  int t0 = blockIdx.x * 2048 + threadIdx.x * 8;
  int x[8];
#pragma unroll
  for (int k = 0; k < 8; ++k) { int idx = t0 + k; x[k] = (idx < n) ? g[idx] : 0; }
  int s = 0;
#pragma unroll
  for (int k = 0; k < 8; ++k) { int t = x[k]; x[k] = s; s += t; }
  int total;
  int ex = block_excl_scan_256(s, lds, total);
  int add = part[blockIdx.x] + ex;
#pragma unroll
  for (int k = 0; k < 8; ++k) { int idx = t0 + k; if (idx < n) g[idx] = x[k] + add; }
}

// STABLE scatter (required for LSD): 3x3-bit in-LDS split rounds sort the
// tile by the 9-bit digit while preserving intra-digit (= prior-pass) order,
// then a direct-addressed coalesced write per digit segment.
// R7: packed bit-field ranking. R8: keys held in a single u64 LDS array
// (halves the ds_read/ds_write instruction count vs the klo/khi split;
// phys16 on 8B elements spreads stride-16 walks over 16 bank-pairs = floor).
__global__ __launch_bounds__(TH) void k_rscatter2(const unsigned long long* __restrict__ src,
                                                  unsigned long long* __restrict__ dst,
                                                  const int* __restrict__ hist, int shift,
                                                  const int* counters) {
  __shared__ unsigned long long kk[CHUNK];
  __shared__ int h8[RADIX * 4];
  __shared__ int dstart[RADIX], gbase[RADIX];
  __shared__ int aux[40];
  int tid = threadIdx.x;
  // XCD-contiguous chunk swizzle: adjacent chunks on the same XCD, temporally adjacent
  int chunk = (blockIdx.x & 7) * NCX + (blockIdx.x >> 3);
  int ac = activeChunks(counters);
  if (chunk >= ac) return;
  size_t cbase = (size_t)chunk * CHUNK;
  gbase[tid] = hist[(size_t)tid * NC + chunk];
  for (int i = tid; i < RADIX * 4; i += TH) h8[i] = 0;
  __syncthreads();
  int rep = tid & 3;
  const ulonglong2* s2 = (const ulonglong2*)(src + cbase);
  int scnt = 0;
#pragma unroll
  for (int r = 0; r < 8; ++r) {
    ulonglong2 v = s2[tid + r * TH];
    int i = 2 * (tid + r * TH);
    kk[phys16(i)] = v.x;
    kk[phys16(i + 1)] = v.y;
    int d0 = (int)((v.x >> shift) & (RADIX - 1));
    int d1 = (int)((v.y >> shift) & (RADIX - 1));
    if (d0 == RADIX - 1) scnt++; else atomicAdd(&h8[d0 * 4 + rep], 1);
    if (d1 == RADIX - 1) scnt++; else atomicAdd(&h8[d1 * 4 + rep], 1);
  }
  if (scnt) atomicAdd(&h8[(RADIX - 1) * 4 + rep], scnt);
  __syncthreads();
  int4 hv = *(const int4*)&h8[tid * 4];
  int h = hv.x + hv.y + hv.z + hv.w;
  int ex0 = scan512_1(h, aux);
  dstart[tid] = ex0;
  __syncthreads();
  // 3 x 3-bit stable split rounds -> tile sorted by 9-bit digit
  int t0 = tid * 16;
  for (int rr = 0; rr < 3; ++rr) {
    int sh = shift + 3 * rr;
    unsigned long long key[16];
    unsigned long long cpack = 0;               // 8 x 8-bit digit counters
#pragma unroll
    for (int k = 0; k < 16; ++k) {
      key[k] = kk[phys16(t0 + k)];
      cpack += 1ULL << (((int)(key[k] >> sh) & 7) << 3);
    }
    int v4[4], ex[4], tot[4];
#pragma unroll
    for (int j = 0; j < 4; ++j) {
      unsigned pair = (unsigned)(cpack >> (16 * j));
      v4[j] = (int)((pair & 0xffu) | ((pair & 0xff00u) << 8));
    }
    scan512_x4(v4, ex, tot, aux);   // internal barriers also order reads-before-writes
    unsigned long long startq0, startq1;        // 8 start positions, 4x16-bit each
    {
      int a = 0, s8[8];
#pragma unroll
      for (int j = 0; j < 4; ++j) {
        int tlo = tot[j] & 0xffff, thi = tot[j] >> 16;
        int elo = ex[j] & 0xffff,  ehi = ex[j] >> 16;
        s8[2 * j]     = a + elo; a += tlo;
        s8[2 * j + 1] = a + ehi; a += thi;
      }
      startq0 = (unsigned long long)(unsigned)s8[0]
              | ((unsigned long long)(unsigned)s8[1] << 16)
              | ((unsigned long long)(unsigned)s8[2] << 32)
              | ((unsigned long long)(unsigned)s8[3] << 48);
      startq1 = (unsigned long long)(unsigned)s8[4]
              | ((unsigned long long)(unsigned)s8[5] << 16)
              | ((unsigned long long)(unsigned)s8[6] << 32)
              | ((unsigned long long)(unsigned)s8[7] << 48);
    }
#pragma unroll
    for (int k = 0; k < 16; ++k) {
      int d = (int)(key[k] >> sh) & 7;
      int fs = (d & 3) << 4;
      unsigned long long inc = 1ULL << fs;
      int pos;
      if (d < 4) { pos = (int)((startq0 >> fs) & 0xffffu); startq0 += inc; }
      else       { pos = (int)((startq1 >> fs) & 0xffffu); startq1 += inc; }
      kk[phys16(pos)] = key[k];
    }
    __syncthreads();
  }
  // direct-addressed scatter: read back in sorted order
#pragma unroll
  for (int r = 0; r < 16; ++r) {
    int i = tid + r * TH;
    unsigned long long k1 = kk[phys16(i)];
    int d = (int)((k1 >> shift) & (RADIX - 1));
    dst[(size_t)(gbase[d] + (i - dstart[d]))] = k1;
  }
}

// ---------------- unique + final decoder write ----------------
__global__ __launch_bounds__(TH) void k_uniq_count(const unsigned long long* A, int* uPart,
                                                   const int* counters) {
  __shared__ int lds[8];
  int ac = activeChunks(counters);
  if ((int)blockIdx.x >= ac) { if (threadIdx.x == 0) uPart[blockIdx.x] = 0; return; }
  size_t base = (size_t)blockIdx.x * CHUNK + (size_t)threadIdx.x * 16;
  unsigned long long prev = (base == 0) ? 0ULL : A[base - 1];
  int c = 0;
#pragma unroll
  for (int k = 0; k < 16; ++k) {
    unsigned long long v = A[base + k];
    c += (v != SENTK && v != prev) ? 1 : 0;
    prev = v;
  }
#pragma unroll
  for (int off = 32; off; off >>= 1) c += __shfl_down(c, off, 64);
  if ((threadIdx.x & 63) == 0) lds[threadIdx.x >> 6] = c;
  __syncthreads();
  if (threadIdx.x == 0) {
    int s = 0;
#pragma unroll
    for (int w = 0; w < 8; ++w) s += lds[w];
    uPart[blockIdx.x] = s;
  }
}

// compact uniques via LDS staging, then dense coalesced writes (no RMW thrash)
__global__ __launch_bounds__(TH) void k_final(const unsigned long long* A, const int* uPart,
                                              const int* counters, float* out) {
  __shared__ int aux[9];
  __shared__ float sq[CHUNK], sr[CHUNK];
  __shared__ int scnt;
  int ac = activeChunks(counters);
  if ((int)blockIdx.x >= ac) return;
  size_t base = (size_t)blockIdx.x * CHUNK + (size_t)threadIdx.x * 16;
  unsigned long long v[16];
  int f[16], c = 0;
  unsigned long long prev = (base == 0) ? 0ULL : A[base - 1];
#pragma unroll
  for (int k = 0; k < 16; ++k) {
    v[k] = A[base + k];
    f[k] = (v[k] != SENTK && v[k] != prev) ? 1 : 0;
    c += f[k];
    prev = v[k];
  }
  int ex = scan512_1(c, aux);
  if (threadIdx.x == TH - 1) scnt = ex + c;
  int j = ex;
#pragma unroll
  for (int k = 0; k < 16; ++k) {
    if (f[k]) {
      unsigned long long val = v[k];
      long long q = (long long)((double)val * (1.0 / 150000.0));
      long long r = (long long)val - q * 150000LL;
      if (r < 0) { q--; r += 150000LL; }
      else if (r >= 150000LL) { q++; r -= 150000LL; }
      sq[j] = (float)q; sr[j] = (float)r; j++;
    }
  }
  __syncthreads();
  int cnt = scnt;
  int jb = 1 + uPart[blockIdx.x];   // +1: slot 0 is the always-present hash 0
  for (int i = (int)threadIdx.x; i < cnt; i += TH) {
    out[OUT_DR + jb + i] = sq[i];
    out[OUT_DC + jb + i] = sr[i];
  }
}

// dec_vals fill (1.0 below totU, 0 after) + zero tails of dec_rows/cols + slot 0
__global__ __launch_bounds__(256) void k_dectail(const int* counters, float* out) {
  int i = (blockIdx.x * 256 + threadIdx.x) * 4;
  if (i >= MOUT) return;
  int totU = counters[3] + 1;
  float4 dv;
  dv.x = (i + 0 < totU) ? 1.0f : 0.0f;
  dv.y = (i + 1 < totU) ? 1.0f : 0.0f;
  dv.z = (i + 2 < totU) ? 1.0f : 0.0f;
  dv.w = (i + 3 < totU) ? 1.0f : 0.0f;
  *(float4*)&out[OUT_DV + i] = dv;
  if (i + 3 >= totU) {
    float4 z = make_float4(0.0f, 0.0f, 0.0f, 0.0f);
    if (i >= totU) {
      *(float4*)&out[OUT_DR + i] = z;
      *(float4*)&out[OUT_DC + i] = z;
    } else {
#pragma unroll
      for (int k = 0; k < 4; ++k)
        if (i + k >= totU) { out[OUT_DR + i + k] = 0.0f; out[OUT_DC + i + k] = 0.0f; }
    }
  }
  if (i == 0) { out[OUT_DR] = 0.0f; out[OUT_DC] = 0.0f; }
}

// ---------------- host launcher ----------------
extern "C" void kernel_launch(void* const* d_in, const int* in_sizes, int n_in,
                              void* d_out, int out_size, void* d_ws, size_t ws_size,
                              hipStream_t stream) {
  const int* rows = (const int*)d_in[1];   // d_in[0]=adj_vals (unused by reference outputs)
  const int* cols = (const int*)d_in[2];
  const int* seeds = (const int*)d_in[3];
  float* out = (float*)d_out;

  // workspace layout
  char* ws = (char*)d_ws;
  size_t off = 0;
  auto alloc = [&](size_t bytes) -> char* {
    char* p = ws + off;
    off += (bytes + 255) & ~(size_t)255;
    return p;
  };
  unsigned long long* A = (unsigned long long*)alloc(MP * 8);
  uint8_t* alive = (uint8_t*)alloc(EDGES);
  char* zbase = ws + off;                       // ---- zeroed zone ----
  uint8_t* frontier = (uint8_t*)alloc(NNODE);
  uint8_t* nextf = (uint8_t*)alloc(NNODE);
  uint8_t* masked = (uint8_t*)alloc(NNODE);
  int* deg8 = (int*)alloc((size_t)8 * NNODE16 * 4);
  int* counters = (int*)alloc(256 * 4);         // [1]=tem_num [2]=tailCnt [3]=uniqSum
  size_t zsize = (size_t)((ws + off) - zbase);  // ---- end zeroed zone ----
  float* dnorm = (float*)alloc((size_t)NNODE * 4);
  int* mlist = (int*)alloc((size_t)NNODE * 4);
  int* hist = (int*)alloc((size_t)NHIST * 4);
  int* spart = (int*)alloc(2048 * 4);
  int* uPart = (int*)alloc(2048 * 4);
  int* mPart = (int*)alloc(256 * 4);

  // radix ping-pong buffer B lives in the (later-overwritten) dec region of d_out
  unsigned long long* Bbuf = (unsigned long long*)(out + OUT_DR);

  // JAX key derivation (threefry_partitionable semantics)
  uint32_t ks0, ks1, kr0, kr1, kc0, kc1, s10, s11, s20, s21;
  tf2x32(0u, 42u, 0u, 0u, ks0, ks1);
  tf2x32(0u, 42u, 0u, 1u, kr0, kr1);
  tf2x32(0u, 42u, 0u, 2u, kc0, kc1);
  tf2x32(ks0, ks1, 0u, 0u, s10, s11);
  tf2x32(ks0, ks1, 0u, 1u, s20, s21);

  hipMemsetAsync(zbase, 0, zsize, stream);

  const int EB = EDGES / 256;                // 15625
  const int NB = (NNODE + 255) / 256;        // 586

  k_seed<<<2, 256, 0, stream>>>(seeds, frontier, masked);
  k_bfs0<<<VNB, 256, 0, stream>>>(rows, cols, frontier, alive, nextf, out);
  k_masked_or<<<NB, 256, 0, stream>>>(masked, nextf);
  k_bfs1deg<<<VNB, 256, 0, stream>>>(rows, cols, nextf, alive, deg8);
  k_sample<<<(NSAMP + 255) / 256, 256, 0, stream>>>(masked, s10, s11, s20, s21);
  k_dnorm<<<NB, 256, 0, stream>>>(deg8, dnorm);
  k_enctail<<<ENB, 256, 0, stream>>>(rows, cols, alive, dnorm, out, A, counters);

  // masked node list (ascending) + tem_num
  k_mreduce<<<MB, 256, 0, stream>>>(masked, mPart);
  k_scan_small<<<1, 1024, 0, stream>>>(mPart, MB, counters + 1);
  k_mscatter<<<MB, 256, 0, stream>>>(masked, mPart, mlist);

  // pairs + self loops at fixed slots; tail already appended compacted
  k_build_pairs<<<EB, 256, 0, stream>>>(mlist, counters, A, kr0, kr1, kc0, kc1);
  k_build_self<<<NB, 256, 0, stream>>>(A);
  k_pad<<<CHUNK / 256, 256, 0, stream>>>(A, counters);

  // radix sort: A -> B -> A -> B -> A (4 passes x 9 bits over active chunks)
  unsigned long long* src = A;
  unsigned long long* dst = Bbuf;
  const int shifts[4] = {0, 9, 18, 27};
  for (int p = 0; p < 4; ++p) {
    k_rhist2<<<NC, TH, 0, stream>>>(src, hist, shifts[p], counters);
    k_scan_reduce<<<SCB, 256, 0, stream>>>(hist, spart, NHIST);
    k_scan_small<<<1, 1024, 0, stream>>>(spart, SCB, nullptr);
    k_scan_apply<<<SCB, 256, 0, stream>>>(hist, spart, NHIST);
    k_rscatter2<<<NC, TH, 0, stream>>>(src, dst, hist, shifts[p], counters);
    unsigned long long* t = src; src = dst; dst = t;
  }
  // sorted result now in A (src == A)

  k_uniq_count<<<NTILE, TH, 0, stream>>>(src, uPart, counters);
  k_scan_small<<<1, 1024, 0, stream>>>(uPart, NTILE, counters + 3);
  k_final<<<NTILE, TH, 0, stream>>>(src, uPart, counters, out);
  k_dectail<<<(MOUT / 4 + 255) / 256, 256, 0, stream>>>(counters, out);
}